// Round 7
// baseline (626.580 us; speedup 1.0000x reference)
//
#include <hip/hip_runtime.h>
#include <math.h>

// ---------------- constants from the reference ----------------
constexpr int IN_F  = 64;
constexpr int HID_F = 64;
constexpr int OUT_F = 32;
constexpr int NEXP  = 8;
constexpr int EMB   = 64;   // emb_dim

// ---------------- utility kernels ----------------
__global__ void zero_f32_kernel(float* __restrict__ p, long long n) {
    long long i = (long long)blockIdx.x * blockDim.x + threadIdx.x;
    long long stride = (long long)gridDim.x * blockDim.x;
    for (; i < n; i += stride) p[i] = 0.0f;
}

__global__ void zero_i32_kernel(int* __restrict__ p, long long n) {
    long long i = (long long)blockIdx.x * blockDim.x + threadIdx.x;
    long long stride = (long long)gridDim.x * blockDim.x;
    for (; i < n; i += stride) p[i] = 0;
}

// ---------------- CSR build ----------------
__global__ void hist_kernel(const int* __restrict__ dst, int* __restrict__ counts, int E) {
    int e = blockIdx.x * blockDim.x + threadIdx.x;
    if (e >= E) return;
    atomicAdd(&counts[dst[e]], 1);
}

// two-level exclusive scan (race-free)
__global__ __launch_bounds__(1024)
void scan1_kernel(const int* __restrict__ counts, int* __restrict__ lexcl,
                  int* __restrict__ partials, int N)
{
    __shared__ int wsum[16];
    const int tid  = threadIdx.x;
    const int lane = tid & 63;
    const int wv   = tid >> 6;
    const int i    = blockIdx.x * 1024 + tid;

    int v = (i < N) ? counts[i] : 0;
    int x = v;
#pragma unroll
    for (int off = 1; off < 64; off <<= 1) {
        int t = __shfl_up(x, off);
        if (lane >= off) x += t;
    }
    if (lane == 63) wsum[wv] = x;
    __syncthreads();
    int woff = 0;
    for (int w = 0; w < wv; ++w) woff += wsum[w];
    if (i < N) lexcl[i] = woff + x - v;
    if (tid == 1023) partials[blockIdx.x] = woff + x;
}

__global__ __launch_bounds__(1024)
void scan2_kernel(int* __restrict__ partials, int NB)
{
    __shared__ int wsum[16];
    const int tid  = threadIdx.x;
    const int lane = tid & 63;
    const int wv   = tid >> 6;
    int v = (tid < NB) ? partials[tid] : 0;
    int x = v;
#pragma unroll
    for (int off = 1; off < 64; off <<= 1) {
        int t = __shfl_up(x, off);
        if (lane >= off) x += t;
    }
    if (lane == 63) wsum[wv] = x;
    __syncthreads();
    int woff = 0;
    for (int w = 0; w < wv; ++w) woff += wsum[w];
    if (tid < NB) partials[tid] = woff + x - v;
}

__global__ void scan3_kernel(const int* __restrict__ lexcl, const int* __restrict__ partials,
                             const int* __restrict__ counts,
                             int* __restrict__ offsets, int* __restrict__ cursor,
                             float* __restrict__ dinv, int N, int E)
{
    int i = blockIdx.x * blockDim.x + threadIdx.x;
    if (i >= N) return;
    int o = lexcl[i] + partials[i >> 10];
    offsets[i] = o;
    cursor[i]  = o;
    dinv[i] = rsqrtf((float)counts[i] + 1.0f);
    if (i == 0) offsets[N] = E;
}

__global__ void scatter_kernel(const int* __restrict__ src, const int* __restrict__ dst,
                               int* __restrict__ cursor, int* __restrict__ csr_src, int E)
{
    int e = blockIdx.x * blockDim.x + threadIdx.x;
    if (e >= E) return;
    int d = dst[e];
    int pos = atomicAdd(&cursor[d], 1);
    csr_src[pos] = src[e];
}

// ---------------- GEMM (x @ W) fused with dinv pre-scale + self-loop init ----------------
template<int CIN, int COUT, int ROWS>
__global__ __launch_bounds__(ROWS * COUT)
void gemm_selfloop_kernel(const float* __restrict__ x, const float* __restrict__ W,
                          const float* __restrict__ b, const float* __restrict__ dinv,
                          float* __restrict__ xws, float* __restrict__ h, int n)
{
    __shared__ float Ws[CIN * COUT];
    __shared__ float xs[ROWS * CIN];
    const int NT = ROWS * COUT;
    const int tid = threadIdx.x;

    for (int i = tid; i < CIN * COUT; i += NT) Ws[i] = W[i];
    const int row0 = blockIdx.x * ROWS;
    for (int i = tid; i < ROWS * CIN; i += NT) {
        int r = i / CIN;
        int rr = row0 + r;
        xs[i] = (rr < n) ? x[(size_t)rr * CIN + (i % CIN)] : 0.0f;
    }
    __syncthreads();

    const int r = tid / COUT;
    const int c = tid % COUT;
    const int row = row0 + r;
    if (row >= n) return;

    float acc = 0.0f;
#pragma unroll
    for (int k = 0; k < CIN; ++k) acc += xs[r * CIN + k] * Ws[k * COUT + c];

    float di = dinv[row];
    float xv = acc * di;
    xws[(size_t)row * COUT + c] = xv;
    h[(size_t)row * COUT + c] = di * xv + b[c];
}

// ---------------- CSR gather-aggregate (no atomics) ----------------
template<int F>
__global__ __launch_bounds__(256)
void csr_agg_kernel(const int* __restrict__ csr_src, const int* __restrict__ offsets,
                    const float* __restrict__ xws, const float* __restrict__ dinv,
                    float* __restrict__ h, int n)
{
    constexpr int SUB = 64 / F;           // nodes per wave
    const int lane = threadIdx.x & 63;
    const int wid  = (blockIdx.x * (blockDim.x >> 6)) + (threadIdx.x >> 6);
    const int sub  = lane / F;
    const int f    = lane % F;
    const int node = wid * SUB + sub;
    const int lbase = sub * F;

    const bool valid = (node < n);
    const int nc   = valid ? node : 0;
    const int off0 = offsets[nc];
    const int off1 = valid ? offsets[nc + 1] : off0;

    float acc0 = 0.0f, acc1 = 0.0f;
    for (int k = off0; k < off1; k += F) {
        int nk = off1 - k; if (nk > F) nk = F;
        int sj = (f < nk) ? csr_src[k + f] : 0;
        int t = 0;
        for (; t + 4 <= nk; t += 4) {
            int s0 = __shfl(sj, lbase + t);
            int s1 = __shfl(sj, lbase + t + 1);
            int s2 = __shfl(sj, lbase + t + 2);
            int s3 = __shfl(sj, lbase + t + 3);
            float v0 = xws[(size_t)s0 * F + f];
            float v1 = xws[(size_t)s1 * F + f];
            float v2 = xws[(size_t)s2 * F + f];
            float v3 = xws[(size_t)s3 * F + f];
            acc0 += v0 + v2;
            acc1 += v1 + v3;
        }
        for (; t < nk; ++t) {
            int s = __shfl(sj, lbase + t);
            acc0 += xws[(size_t)s * F + f];
        }
    }
    if (valid) h[(size_t)node * F + f] += dinv[node] * (acc0 + acc1);
}

// ---------------- mean pool ----------------
__global__ void pool_sum_kernel(const float* __restrict__ h, const int* __restrict__ batch,
                                float* __restrict__ pooled, float* __restrict__ cnt, int n)
{
    int t = blockIdx.x * blockDim.x + threadIdx.x;
    int i = t >> 5;          // node
    int f = t & 31;          // feature (OUT_F == 32)
    if (i >= n) return;
    int g = batch[i];
    atomicAdd(&pooled[(size_t)g * OUT_F + f], h[(size_t)i * OUT_F + f]);
    if (f == 0) atomicAdd(&cnt[g], 1.0f);
}

__global__ void pool_div_kernel(float* __restrict__ pooled, const float* __restrict__ cnt, int B)
{
    int t = blockIdx.x * blockDim.x + threadIdx.x;
    if (t >= B * OUT_F) return;
    int g = t >> 5;
    pooled[t] /= fmaxf(cnt[g], 1.0f);
}

// ---------------- gate: softmax([p0|p1] @ Wc + bc) ----------------
__global__ void gate_kernel(const float* __restrict__ p0, const float* __restrict__ p1,
                            const float* __restrict__ Wc, const float* __restrict__ bc,
                            float* __restrict__ gate, int B)
{
    int g = blockIdx.x * blockDim.x + threadIdx.x;
    if (g >= B) return;
    float xv[2 * OUT_F];
#pragma unroll
    for (int k = 0; k < OUT_F; ++k) xv[k] = p0[(size_t)g * OUT_F + k];
#pragma unroll
    for (int k = 0; k < OUT_F; ++k) xv[OUT_F + k] = p1[(size_t)g * OUT_F + k];

    float lg[NEXP];
    float m = -1e30f;
#pragma unroll
    for (int e = 0; e < NEXP; ++e) {
        float acc = bc[e];
#pragma unroll
        for (int k = 0; k < 2 * OUT_F; ++k) acc += xv[k] * Wc[k * NEXP + e];
        lg[e] = acc;
        m = fmaxf(m, acc);
    }
    float se = 0.0f;
#pragma unroll
    for (int e = 0; e < NEXP; ++e) { lg[e] = expf(lg[e] - m); se += lg[e]; }
    float inv = 1.0f / se;
#pragma unroll
    for (int e = 0; e < NEXP; ++e) gate[(size_t)g * NEXP + e] = lg[e] * inv;
}

__global__ void zero_scalar_kernel(float* p) { *p = 0.0f; }

// ---------------- distortion loss ----------------
// wave per 2 edges (unroll x2 for MLP). Lane l covers float4 elems [4l..4l+3]
// (expert l>>4) and [256+4l..] (expert 4+(l>>4)). 4 butterfly rounds within the
// 16-lane group give group-wide partial diffs; every lane computes the 8-wide
// softmax locally from the full gate rows; 2 more butterfly rounds (16,32)
// produce the weighted sum. 10 shuffles/edge, no gather.
__global__ __launch_bounds__(256)
void distortion_kernel(const float* __restrict__ emb, const float* __restrict__ gate,
                       const float* __restrict__ dis,
                       const int* __restrict__ s_idx, const int* __restrict__ d_idx,
                       float* __restrict__ loss, int E2)
{
    int gt = blockIdx.x * blockDim.x + threadIdx.x;
    int wid = gt >> 6;
    int lane = threadIdx.x & 63;
    int grp = lane >> 4;                 // 16-lane group = expert pair (grp, grp+4)
    int nw = (gridDim.x * blockDim.x) >> 6;

    const float4* emb4  = (const float4*)emb;
    const float4* gate4 = (const float4*)gate;

    float lsum = 0.0f;
    for (int e0 = wid * 2; e0 < E2; e0 += nw * 2) {
        const int e1v = (e0 + 1 < E2) ? (e0 + 1) : e0;
        const float wB = (e0 + 1 < E2) ? 1.0f : 0.0f;

        int sA = s_idx[e0],  dA = d_idx[e0];
        int sB = s_idx[e1v], dB = d_idx[e1v];

        const float4* esA = emb4 + (size_t)sA * 128;
        const float4* edA = emb4 + (size_t)dA * 128;
        const float4* esB = emb4 + (size_t)sB * 128;
        const float4* edB = emb4 + (size_t)dB * 128;

        // issue all 16 row loads + 8 gate loads up front (independent)
        float4 a0 = esA[lane];
        float4 b0 = edA[lane];
        float4 a1 = esA[lane + 64];
        float4 b1 = edA[lane + 64];
        float4 c0 = esB[lane];
        float4 f0 = edB[lane];
        float4 c1 = esB[lane + 64];
        float4 f1 = edB[lane + 64];
        float4 gsA0 = gate4[(size_t)sA * 2];
        float4 gsA1 = gate4[(size_t)sA * 2 + 1];
        float4 gdA0 = gate4[(size_t)dA * 2];
        float4 gdA1 = gate4[(size_t)dA * 2 + 1];
        float4 gsB0 = gate4[(size_t)sB * 2];
        float4 gsB1 = gate4[(size_t)sB * 2 + 1];
        float4 gdB0 = gate4[(size_t)dB * 2];
        float4 gdB1 = gate4[(size_t)dB * 2 + 1];
        float disA = dis[e0];
        float disB = dis[e1v];

        float dx, paA, pbA, paB, pbB;
        dx = a0.x - b0.x; paA  = dx * dx;
        dx = a0.y - b0.y; paA += dx * dx;
        dx = a0.z - b0.z; paA += dx * dx;
        dx = a0.w - b0.w; paA += dx * dx;
        dx = a1.x - b1.x; pbA  = dx * dx;
        dx = a1.y - b1.y; pbA += dx * dx;
        dx = a1.z - b1.z; pbA += dx * dx;
        dx = a1.w - b1.w; pbA += dx * dx;
        dx = c0.x - f0.x; paB  = dx * dx;
        dx = c0.y - f0.y; paB += dx * dx;
        dx = c0.z - f0.z; paB += dx * dx;
        dx = c0.w - f0.w; paB += dx * dx;
        dx = c1.x - f1.x; pbB  = dx * dx;
        dx = c1.y - f1.y; pbB += dx * dx;
        dx = c1.z - f1.z; pbB += dx * dx;
        dx = c1.w - f1.w; pbB += dx * dx;

#pragma unroll
        for (int off = 1; off < 16; off <<= 1) {
            paA += __shfl_xor(paA, off);
            pbA += __shfl_xor(pbA, off);
            paB += __shfl_xor(paB, off);
            pbB += __shfl_xor(pbB, off);
        }
        // group grp now holds: paX = diff[expert grp], pbX = diff[expert grp+4]

        // edge A softmax weights (all lanes, local)
        float gpA[NEXP] = { gsA0.x * gdA0.x, gsA0.y * gdA0.y, gsA0.z * gdA0.z, gsA0.w * gdA0.w,
                            gsA1.x * gdA1.x, gsA1.y * gdA1.y, gsA1.z * gdA1.z, gsA1.w * gdA1.w };
        float gpB[NEXP] = { gsB0.x * gdB0.x, gsB0.y * gdB0.y, gsB0.z * gdB0.z, gsB0.w * gdB0.w,
                            gsB1.x * gdB1.x, gsB1.y * gdB1.y, gsB1.z * gdB1.z, gsB1.w * gdB1.w };
        float mA = gpA[0], mB = gpB[0];
#pragma unroll
        for (int j = 1; j < NEXP; ++j) { mA = fmaxf(mA, gpA[j]); mB = fmaxf(mB, gpB[j]); }
        float seA = 0.0f, seB = 0.0f;
#pragma unroll
        for (int j = 0; j < NEXP; ++j) {
            gpA[j] = expf(gpA[j] - mA); seA += gpA[j];
            gpB[j] = expf(gpB[j] - mB); seB += gpB[j];
        }

        // group-local weighted partial, then cross-group butterfly (16, 32)
        float wA0 = gpA[grp], wA1 = gpA[grp + 4];
        float wB0 = gpB[grp], wB1 = gpB[grp + 4];
        float vA = paA * wA0 + pbA * wA1;
        float vB = paB * wB0 + pbB * wB1;
        vA += __shfl_xor(vA, 16);
        vB += __shfl_xor(vB, 16);
        vA += __shfl_xor(vA, 32);
        vB += __shfl_xor(vB, 32);

        float dsumA = vA / seA;
        float dsumB = vB / seB;
        lsum += fabsf(dsumA / disA - 1.0f) + wB * fabsf(dsumB / disB - 1.0f);
    }
    if (lane == 0) atomicAdd(loss, lsum / (float)E2);
}

// ---------------- launch ----------------
extern "C" void kernel_launch(void* const* d_in, const int* in_sizes, int n_in,
                              void* d_out, int out_size, void* d_ws, size_t ws_size,
                              hipStream_t stream)
{
    const float* x0   = (const float*)d_in[0];
    const float* x1   = (const float*)d_in[1];
    const float* W1   = (const float*)d_in[2];
    const float* b1   = (const float*)d_in[3];
    const float* W2   = (const float*)d_in[4];
    const float* b2   = (const float*)d_in[5];
    const float* Wc   = (const float*)d_in[6];
    const float* bc   = (const float*)d_in[7];
    const float* emb  = (const float*)d_in[8];
    const float* dis  = (const float*)d_in[9];
    const int*   ei0  = (const int*)d_in[10];
    const int*   ei1  = (const int*)d_in[11];
    const int*   bat0 = (const int*)d_in[12];
    const int*   bat1 = (const int*)d_in[13];
    const int*   ei2  = (const int*)d_in[14];

    const int N  = in_sizes[0] / IN_F;
    const int E  = in_sizes[10] / 2;
    const int B  = in_sizes[8] / (NEXP * EMB);
    const int E2 = in_sizes[14] / 2;

    float* gate_out = (float*)d_out;               // B*NEXP
    float* loss_out = gate_out + (size_t)B * NEXP; // 1

    // workspace layout
    float* ws      = (float*)d_ws;
    float* dinv    = ws;                           // N
    float* bufA    = dinv + N;                     // N*64  (xws1; then xws2|h2)
    float* bufB    = bufA + (size_t)N * 64;        // N*64  (h1)
    float* pooled0 = bufB + (size_t)N * 64;        // B*32
    float* pooled1 = pooled0 + (size_t)B * OUT_F;  // B*32
    float* cnt     = pooled1 + (size_t)B * OUT_F;  // B
    int*   iws     = (int*)(cnt + B);
    int*   counts  = iws;                          // N
    int*   offsets = counts + N;                   // N+1
    int*   cursor  = offsets + N + 1;              // N
    int*   csr_src = cursor + N;                   // E
    int*   lexcl   = csr_src + E;                  // N
    int*   partials= lexcl + N;                    // <=1024

    const int TB = 256;
    const int zgrid = 512;
    const int NB = (N + 1023) / 1024;              // scan blocks (<=1024)

    for (int g = 0; g < 2; ++g) {
        const float* x    = (g == 0) ? x0 : x1;
        const int* src    = (g == 0) ? ei0 : ei1;
        const int* dst    = src + E;
        const int* batch  = (g == 0) ? bat0 : bat1;
        float* pooled     = (g == 0) ? pooled0 : pooled1;

        float* xws1 = bufA;
        float* h1   = bufB;
        float* xws2 = bufA;                          // reuse (xws1 dead after agg1)
        float* h2   = bufA + (size_t)N * OUT_F;

        // CSR build (shared by both convs) + dinv
        zero_i32_kernel<<<zgrid, TB, 0, stream>>>(counts, N);
        hist_kernel<<<(E + TB - 1) / TB, TB, 0, stream>>>(dst, counts, E);
        scan1_kernel<<<NB, 1024, 0, stream>>>(counts, lexcl, partials, N);
        scan2_kernel<<<1, 1024, 0, stream>>>(partials, NB);
        scan3_kernel<<<(N + TB - 1) / TB, TB, 0, stream>>>(lexcl, partials, counts,
                                                           offsets, cursor, dinv, N, E);
        scatter_kernel<<<(E + TB - 1) / TB, TB, 0, stream>>>(src, dst, cursor, csr_src, E);

        // conv1: 64 -> 64
        gemm_selfloop_kernel<IN_F, HID_F, 4>
            <<<(N + 3) / 4, 4 * HID_F, 0, stream>>>(x, W1, b1, dinv, xws1, h1, N);
        csr_agg_kernel<HID_F>
            <<<(N + 3) / 4, TB, 0, stream>>>(csr_src, offsets, xws1, dinv, h1, N);

        // conv2: 64 -> 32
        gemm_selfloop_kernel<HID_F, OUT_F, 8>
            <<<(N + 7) / 8, 8 * OUT_F, 0, stream>>>(h1, W2, b2, dinv, xws2, h2, N);
        csr_agg_kernel<OUT_F>
            <<<(N + 7) / 8, TB, 0, stream>>>(csr_src, offsets, xws2, dinv, h2, N);

        // mean pool
        zero_f32_kernel<<<zgrid, TB, 0, stream>>>(pooled, (long long)B * OUT_F);
        zero_f32_kernel<<<zgrid, TB, 0, stream>>>(cnt, B);
        pool_sum_kernel<<<((N * 32) + TB - 1) / TB, TB, 0, stream>>>(h2, batch, pooled, cnt, N);
        pool_div_kernel<<<((B * OUT_F) + TB - 1) / TB, TB, 0, stream>>>(pooled, cnt, B);
    }

    // gate
    gate_kernel<<<(B + TB - 1) / TB, TB, 0, stream>>>(pooled0, pooled1, Wc, bc, gate_out, B);

    // distortion loss
    zero_scalar_kernel<<<1, 1, 0, stream>>>(loss_out);
    distortion_kernel<<<2048, TB, 0, stream>>>(emb, gate_out, dis,
                                               ei2, ei2 + E2, loss_out, E2);
}

// Round 8
// 618.981 us; speedup vs baseline: 1.0123x; 1.0123x over previous
//
#include <hip/hip_runtime.h>
#include <math.h>

// ---------------- constants from the reference ----------------
constexpr int IN_F  = 64;
constexpr int HID_F = 64;
constexpr int OUT_F = 32;
constexpr int NEXP  = 8;
constexpr int EMB   = 64;   // emb_dim

// ---------------- utility kernels ----------------
__global__ void zero_f32_kernel(float* __restrict__ p, long long n) {
    long long i = (long long)blockIdx.x * blockDim.x + threadIdx.x;
    long long stride = (long long)gridDim.x * blockDim.x;
    for (; i < n; i += stride) p[i] = 0.0f;
}

__global__ void zero_i32_kernel(int* __restrict__ p, long long n) {
    long long i = (long long)blockIdx.x * blockDim.x + threadIdx.x;
    long long stride = (long long)gridDim.x * blockDim.x;
    for (; i < n; i += stride) p[i] = 0;
}

// ---------------- CSR build ----------------
__global__ void hist_kernel(const int* __restrict__ dst, int* __restrict__ counts, int E) {
    int e = blockIdx.x * blockDim.x + threadIdx.x;
    if (e >= E) return;
    atomicAdd(&counts[dst[e]], 1);
}

// two-level exclusive scan (race-free)
__global__ __launch_bounds__(1024)
void scan1_kernel(const int* __restrict__ counts, int* __restrict__ lexcl,
                  int* __restrict__ partials, int N)
{
    __shared__ int wsum[16];
    const int tid  = threadIdx.x;
    const int lane = tid & 63;
    const int wv   = tid >> 6;
    const int i    = blockIdx.x * 1024 + tid;

    int v = (i < N) ? counts[i] : 0;
    int x = v;
#pragma unroll
    for (int off = 1; off < 64; off <<= 1) {
        int t = __shfl_up(x, off);
        if (lane >= off) x += t;
    }
    if (lane == 63) wsum[wv] = x;
    __syncthreads();
    int woff = 0;
    for (int w = 0; w < wv; ++w) woff += wsum[w];
    if (i < N) lexcl[i] = woff + x - v;
    if (tid == 1023) partials[blockIdx.x] = woff + x;
}

__global__ __launch_bounds__(1024)
void scan2_kernel(int* __restrict__ partials, int NB)
{
    __shared__ int wsum[16];
    const int tid  = threadIdx.x;
    const int lane = tid & 63;
    const int wv   = tid >> 6;
    int v = (tid < NB) ? partials[tid] : 0;
    int x = v;
#pragma unroll
    for (int off = 1; off < 64; off <<= 1) {
        int t = __shfl_up(x, off);
        if (lane >= off) x += t;
    }
    if (lane == 63) wsum[wv] = x;
    __syncthreads();
    int woff = 0;
    for (int w = 0; w < wv; ++w) woff += wsum[w];
    if (tid < NB) partials[tid] = woff + x - v;
}

__global__ void scan3_kernel(const int* __restrict__ lexcl, const int* __restrict__ partials,
                             const int* __restrict__ counts,
                             int* __restrict__ offsets, int* __restrict__ cursor,
                             float* __restrict__ dinv, int N, int E)
{
    int i = blockIdx.x * blockDim.x + threadIdx.x;
    if (i >= N) return;
    int o = lexcl[i] + partials[i >> 10];
    offsets[i] = o;
    cursor[i]  = o;
    dinv[i] = rsqrtf((float)counts[i] + 1.0f);
    if (i == 0) offsets[N] = E;
}

__global__ void scatter_kernel(const int* __restrict__ src, const int* __restrict__ dst,
                               int* __restrict__ cursor, int* __restrict__ csr_src, int E)
{
    int e = blockIdx.x * blockDim.x + threadIdx.x;
    if (e >= E) return;
    int d = dst[e];
    int pos = atomicAdd(&cursor[d], 1);
    csr_src[pos] = src[e];
}

// ---------------- GEMM (x @ W) fused with dinv pre-scale + self-loop init ----------------
template<int CIN, int COUT, int ROWS>
__global__ __launch_bounds__(ROWS * COUT)
void gemm_selfloop_kernel(const float* __restrict__ x, const float* __restrict__ W,
                          const float* __restrict__ b, const float* __restrict__ dinv,
                          float* __restrict__ xws, float* __restrict__ h, int n)
{
    __shared__ float Ws[CIN * COUT];
    __shared__ float xs[ROWS * CIN];
    const int NT = ROWS * COUT;
    const int tid = threadIdx.x;

    for (int i = tid; i < CIN * COUT; i += NT) Ws[i] = W[i];
    const int row0 = blockIdx.x * ROWS;
    for (int i = tid; i < ROWS * CIN; i += NT) {
        int r = i / CIN;
        int rr = row0 + r;
        xs[i] = (rr < n) ? x[(size_t)rr * CIN + (i % CIN)] : 0.0f;
    }
    __syncthreads();

    const int r = tid / COUT;
    const int c = tid % COUT;
    const int row = row0 + r;
    if (row >= n) return;

    float acc = 0.0f;
#pragma unroll
    for (int k = 0; k < CIN; ++k) acc += xs[r * CIN + k] * Ws[k * COUT + c];

    float di = dinv[row];
    float xv = acc * di;
    xws[(size_t)row * COUT + c] = xv;
    h[(size_t)row * COUT + c] = di * xv + b[c];
}

// ---------------- CSR gather-aggregate (no atomics) ----------------
template<int F>
__global__ __launch_bounds__(256)
void csr_agg_kernel(const int* __restrict__ csr_src, const int* __restrict__ offsets,
                    const float* __restrict__ xws, const float* __restrict__ dinv,
                    float* __restrict__ h, int n)
{
    constexpr int SUB = 64 / F;           // nodes per wave
    const int lane = threadIdx.x & 63;
    const int wid  = (blockIdx.x * (blockDim.x >> 6)) + (threadIdx.x >> 6);
    const int sub  = lane / F;
    const int f    = lane % F;
    const int node = wid * SUB + sub;
    const int lbase = sub * F;

    const bool valid = (node < n);
    const int nc   = valid ? node : 0;
    const int off0 = offsets[nc];
    const int off1 = valid ? offsets[nc + 1] : off0;

    float acc0 = 0.0f, acc1 = 0.0f;
    for (int k = off0; k < off1; k += F) {
        int nk = off1 - k; if (nk > F) nk = F;
        int sj = (f < nk) ? csr_src[k + f] : 0;
        int t = 0;
        for (; t + 4 <= nk; t += 4) {
            int s0 = __shfl(sj, lbase + t);
            int s1 = __shfl(sj, lbase + t + 1);
            int s2 = __shfl(sj, lbase + t + 2);
            int s3 = __shfl(sj, lbase + t + 3);
            float v0 = xws[(size_t)s0 * F + f];
            float v1 = xws[(size_t)s1 * F + f];
            float v2 = xws[(size_t)s2 * F + f];
            float v3 = xws[(size_t)s3 * F + f];
            acc0 += v0 + v2;
            acc1 += v1 + v3;
        }
        for (; t < nk; ++t) {
            int s = __shfl(sj, lbase + t);
            acc0 += xws[(size_t)s * F + f];
        }
    }
    if (valid) h[(size_t)node * F + f] += dinv[node] * (acc0 + acc1);
}

// ---------------- mean pool ----------------
__global__ void pool_sum_kernel(const float* __restrict__ h, const int* __restrict__ batch,
                                float* __restrict__ pooled, float* __restrict__ cnt, int n)
{
    int t = blockIdx.x * blockDim.x + threadIdx.x;
    int i = t >> 5;          // node
    int f = t & 31;          // feature (OUT_F == 32)
    if (i >= n) return;
    int g = batch[i];
    atomicAdd(&pooled[(size_t)g * OUT_F + f], h[(size_t)i * OUT_F + f]);
    if (f == 0) atomicAdd(&cnt[g], 1.0f);
}

__global__ void pool_div_kernel(float* __restrict__ pooled, const float* __restrict__ cnt, int B)
{
    int t = blockIdx.x * blockDim.x + threadIdx.x;
    if (t >= B * OUT_F) return;
    int g = t >> 5;
    pooled[t] /= fmaxf(cnt[g], 1.0f);
}

// ---------------- gate: softmax([p0|p1] @ Wc + bc) ----------------
__global__ void gate_kernel(const float* __restrict__ p0, const float* __restrict__ p1,
                            const float* __restrict__ Wc, const float* __restrict__ bc,
                            float* __restrict__ gate, int B)
{
    int g = blockIdx.x * blockDim.x + threadIdx.x;
    if (g >= B) return;
    float xv[2 * OUT_F];
#pragma unroll
    for (int k = 0; k < OUT_F; ++k) xv[k] = p0[(size_t)g * OUT_F + k];
#pragma unroll
    for (int k = 0; k < OUT_F; ++k) xv[OUT_F + k] = p1[(size_t)g * OUT_F + k];

    float lg[NEXP];
    float m = -1e30f;
#pragma unroll
    for (int e = 0; e < NEXP; ++e) {
        float acc = bc[e];
#pragma unroll
        for (int k = 0; k < 2 * OUT_F; ++k) acc += xv[k] * Wc[k * NEXP + e];
        lg[e] = acc;
        m = fmaxf(m, acc);
    }
    float se = 0.0f;
#pragma unroll
    for (int e = 0; e < NEXP; ++e) { lg[e] = expf(lg[e] - m); se += lg[e]; }
    float inv = 1.0f / se;
#pragma unroll
    for (int e = 0; e < NEXP; ++e) gate[(size_t)g * NEXP + e] = lg[e] * inv;
}

__global__ void zero_scalar_kernel(float* p) { *p = 0.0f; }

// ---------------- distortion loss ----------------
// One edge per wave per iteration, depth-2 software pipeline: edge i+1's 13
// loads live in named "next" registers across edge i's compute, forcing the
// compiler to keep ~2 edges of data in flight (ILP for the L2-miss latency).
// Lane l covers float4 elem l (expert l>>4) and l+64 (expert 4+(l>>4));
// 4 butterfly rounds in the 16-lane group, lane-local 8-wide softmax,
// 2 cross-group butterflies (16, 32).
__global__ __launch_bounds__(256, 4)
void distortion_kernel(const float* __restrict__ emb, const float* __restrict__ gate,
                       const float* __restrict__ dis,
                       const int* __restrict__ s_idx, const int* __restrict__ d_idx,
                       float* __restrict__ loss, int E2)
{
    int gt = blockIdx.x * blockDim.x + threadIdx.x;
    int wid = gt >> 6;
    int lane = threadIdx.x & 63;
    int grp = lane >> 4;                 // 16-lane group = expert pair (grp, grp+4)
    int nw = (gridDim.x * blockDim.x) >> 6;

    const float4* emb4  = (const float4*)emb;
    const float4* gate4 = (const float4*)gate;

    float lsum = 0.0f;
    int e = wid;
    if (e < E2) {
        // prologue: load edge e
        int s = s_idx[e], d = d_idx[e];
        const float4* es = emb4 + (size_t)s * 128;
        const float4* ed = emb4 + (size_t)d * 128;
        float4 a0 = es[lane];
        float4 b0 = ed[lane];
        float4 a1 = es[lane + 64];
        float4 b1 = ed[lane + 64];
        float4 gs0 = gate4[(size_t)s * 2];
        float4 gs1 = gate4[(size_t)s * 2 + 1];
        float4 gd0 = gate4[(size_t)d * 2];
        float4 gd1 = gate4[(size_t)d * 2 + 1];
        float dv = dis[e];

        for (;;) {
            // ---- issue next edge's loads (held live across this compute) ----
            int en = e + nw;
            bool has_next = (en < E2);
            int enc = has_next ? en : e;
            int sn = s_idx[enc], dn = d_idx[enc];
            const float4* esn = emb4 + (size_t)sn * 128;
            const float4* edn = emb4 + (size_t)dn * 128;
            float4 na0 = esn[lane];
            float4 nb0 = edn[lane];
            float4 na1 = esn[lane + 64];
            float4 nb1 = edn[lane + 64];
            float4 ngs0 = gate4[(size_t)sn * 2];
            float4 ngs1 = gate4[(size_t)sn * 2 + 1];
            float4 ngd0 = gate4[(size_t)dn * 2];
            float4 ngd1 = gate4[(size_t)dn * 2 + 1];
            float ndv = dis[enc];

            // ---- compute current edge ----
            float dx, pa, pb;
            dx = a0.x - b0.x; pa  = dx * dx;
            dx = a0.y - b0.y; pa += dx * dx;
            dx = a0.z - b0.z; pa += dx * dx;
            dx = a0.w - b0.w; pa += dx * dx;
            dx = a1.x - b1.x; pb  = dx * dx;
            dx = a1.y - b1.y; pb += dx * dx;
            dx = a1.z - b1.z; pb += dx * dx;
            dx = a1.w - b1.w; pb += dx * dx;

#pragma unroll
            for (int off = 1; off < 16; off <<= 1) {
                pa += __shfl_xor(pa, off);
                pb += __shfl_xor(pb, off);
            }

            float gp[NEXP] = { gs0.x * gd0.x, gs0.y * gd0.y, gs0.z * gd0.z, gs0.w * gd0.w,
                               gs1.x * gd1.x, gs1.y * gd1.y, gs1.z * gd1.z, gs1.w * gd1.w };
            float m = gp[0];
#pragma unroll
            for (int j = 1; j < NEXP; ++j) m = fmaxf(m, gp[j]);
            float se = 0.0f;
#pragma unroll
            for (int j = 0; j < NEXP; ++j) { gp[j] = expf(gp[j] - m); se += gp[j]; }

            float v = pa * gp[grp] + pb * gp[grp + 4];
            v += __shfl_xor(v, 16);
            v += __shfl_xor(v, 32);

            lsum += fabsf((v / se) / dv - 1.0f);

            if (!has_next) break;
            // ---- rotate pipeline ----
            e = en;
            a0 = na0; b0 = nb0; a1 = na1; b1 = nb1;
            gs0 = ngs0; gs1 = ngs1; gd0 = ngd0; gd1 = ngd1;
            dv = ndv;
        }
    }
    if (lane == 0) atomicAdd(loss, lsum / (float)E2);
}

// ---------------- launch ----------------
extern "C" void kernel_launch(void* const* d_in, const int* in_sizes, int n_in,
                              void* d_out, int out_size, void* d_ws, size_t ws_size,
                              hipStream_t stream)
{
    const float* x0   = (const float*)d_in[0];
    const float* x1   = (const float*)d_in[1];
    const float* W1   = (const float*)d_in[2];
    const float* b1   = (const float*)d_in[3];
    const float* W2   = (const float*)d_in[4];
    const float* b2   = (const float*)d_in[5];
    const float* Wc   = (const float*)d_in[6];
    const float* bc   = (const float*)d_in[7];
    const float* emb  = (const float*)d_in[8];
    const float* dis  = (const float*)d_in[9];
    const int*   ei0  = (const int*)d_in[10];
    const int*   ei1  = (const int*)d_in[11];
    const int*   bat0 = (const int*)d_in[12];
    const int*   bat1 = (const int*)d_in[13];
    const int*   ei2  = (const int*)d_in[14];

    const int N  = in_sizes[0] / IN_F;
    const int E  = in_sizes[10] / 2;
    const int B  = in_sizes[8] / (NEXP * EMB);
    const int E2 = in_sizes[14] / 2;

    float* gate_out = (float*)d_out;               // B*NEXP
    float* loss_out = gate_out + (size_t)B * NEXP; // 1

    // workspace layout
    float* ws      = (float*)d_ws;
    float* dinv    = ws;                           // N
    float* bufA    = dinv + N;                     // N*64  (xws1; then xws2|h2)
    float* bufB    = bufA + (size_t)N * 64;        // N*64  (h1)
    float* pooled0 = bufB + (size_t)N * 64;        // B*32
    float* pooled1 = pooled0 + (size_t)B * OUT_F;  // B*32
    float* cnt     = pooled1 + (size_t)B * OUT_F;  // B
    int*   iws     = (int*)(cnt + B);
    int*   counts  = iws;                          // N
    int*   offsets = counts + N;                   // N+1
    int*   cursor  = offsets + N + 1;              // N
    int*   csr_src = cursor + N;                   // E
    int*   lexcl   = csr_src + E;                  // N
    int*   partials= lexcl + N;                    // <=1024

    const int TB = 256;
    const int zgrid = 512;
    const int NB = (N + 1023) / 1024;              // scan blocks (<=1024)

    for (int g = 0; g < 2; ++g) {
        const float* x    = (g == 0) ? x0 : x1;
        const int* src    = (g == 0) ? ei0 : ei1;
        const int* dst    = src + E;
        const int* batch  = (g == 0) ? bat0 : bat1;
        float* pooled     = (g == 0) ? pooled0 : pooled1;

        float* xws1 = bufA;
        float* h1   = bufB;
        float* xws2 = bufA;                          // reuse (xws1 dead after agg1)
        float* h2   = bufA + (size_t)N * OUT_F;

        // CSR build (shared by both convs) + dinv
        zero_i32_kernel<<<zgrid, TB, 0, stream>>>(counts, N);
        hist_kernel<<<(E + TB - 1) / TB, TB, 0, stream>>>(dst, counts, E);
        scan1_kernel<<<NB, 1024, 0, stream>>>(counts, lexcl, partials, N);
        scan2_kernel<<<1, 1024, 0, stream>>>(partials, NB);
        scan3_kernel<<<(N + TB - 1) / TB, TB, 0, stream>>>(lexcl, partials, counts,
                                                           offsets, cursor, dinv, N, E);
        scatter_kernel<<<(E + TB - 1) / TB, TB, 0, stream>>>(src, dst, cursor, csr_src, E);

        // conv1: 64 -> 64
        gemm_selfloop_kernel<IN_F, HID_F, 4>
            <<<(N + 3) / 4, 4 * HID_F, 0, stream>>>(x, W1, b1, dinv, xws1, h1, N);
        csr_agg_kernel<HID_F>
            <<<(N + 3) / 4, TB, 0, stream>>>(csr_src, offsets, xws1, dinv, h1, N);

        // conv2: 64 -> 32
        gemm_selfloop_kernel<HID_F, OUT_F, 8>
            <<<(N + 7) / 8, 8 * OUT_F, 0, stream>>>(h1, W2, b2, dinv, xws2, h2, N);
        csr_agg_kernel<OUT_F>
            <<<(N + 7) / 8, TB, 0, stream>>>(csr_src, offsets, xws2, dinv, h2, N);

        // mean pool
        zero_f32_kernel<<<zgrid, TB, 0, stream>>>(pooled, (long long)B * OUT_F);
        zero_f32_kernel<<<zgrid, TB, 0, stream>>>(cnt, B);
        pool_sum_kernel<<<((N * 32) + TB - 1) / TB, TB, 0, stream>>>(h2, batch, pooled, cnt, N);
        pool_div_kernel<<<((B * OUT_F) + TB - 1) / TB, TB, 0, stream>>>(pooled, cnt, B);
    }

    // gate
    gate_kernel<<<(B + TB - 1) / TB, TB, 0, stream>>>(pooled0, pooled1, Wc, bc, gate_out, B);

    // distortion loss
    zero_scalar_kernel<<<1, 1, 0, stream>>>(loss_out);
    distortion_kernel<<<2048, TB, 0, stream>>>(emb, gate_out, dis,
                                               ei2, ei2 + E2, loss_out, E2);
}

// Round 9
// 575.119 us; speedup vs baseline: 1.0895x; 1.0763x over previous
//
#include <hip/hip_runtime.h>
#include <math.h>

// ---------------- constants from the reference ----------------
constexpr int IN_F  = 64;
constexpr int HID_F = 64;
constexpr int OUT_F = 32;
constexpr int NEXP  = 8;
constexpr int EMB   = 64;   // emb_dim

// ---------------- utility kernels ----------------
__global__ void zero_f32_kernel(float* __restrict__ p, long long n) {
    long long i = (long long)blockIdx.x * blockDim.x + threadIdx.x;
    long long stride = (long long)gridDim.x * blockDim.x;
    for (; i < n; i += stride) p[i] = 0.0f;
}

__global__ void zero_i32_kernel(int* __restrict__ p, long long n) {
    long long i = (long long)blockIdx.x * blockDim.x + threadIdx.x;
    long long stride = (long long)gridDim.x * blockDim.x;
    for (; i < n; i += stride) p[i] = 0;
}

// ---------------- CSR build ----------------
__global__ void hist_kernel(const int* __restrict__ dst, int* __restrict__ counts, int E) {
    int e = blockIdx.x * blockDim.x + threadIdx.x;
    if (e >= E) return;
    atomicAdd(&counts[dst[e]], 1);
}

// two-level exclusive scan (race-free)
__global__ __launch_bounds__(1024)
void scan1_kernel(const int* __restrict__ counts, int* __restrict__ lexcl,
                  int* __restrict__ partials, int N)
{
    __shared__ int wsum[16];
    const int tid  = threadIdx.x;
    const int lane = tid & 63;
    const int wv   = tid >> 6;
    const int i    = blockIdx.x * 1024 + tid;

    int v = (i < N) ? counts[i] : 0;
    int x = v;
#pragma unroll
    for (int off = 1; off < 64; off <<= 1) {
        int t = __shfl_up(x, off);
        if (lane >= off) x += t;
    }
    if (lane == 63) wsum[wv] = x;
    __syncthreads();
    int woff = 0;
    for (int w = 0; w < wv; ++w) woff += wsum[w];
    if (i < N) lexcl[i] = woff + x - v;
    if (tid == 1023) partials[blockIdx.x] = woff + x;
}

__global__ __launch_bounds__(1024)
void scan2_kernel(int* __restrict__ partials, int NB)
{
    __shared__ int wsum[16];
    const int tid  = threadIdx.x;
    const int lane = tid & 63;
    const int wv   = tid >> 6;
    int v = (tid < NB) ? partials[tid] : 0;
    int x = v;
#pragma unroll
    for (int off = 1; off < 64; off <<= 1) {
        int t = __shfl_up(x, off);
        if (lane >= off) x += t;
    }
    if (lane == 63) wsum[wv] = x;
    __syncthreads();
    int woff = 0;
    for (int w = 0; w < wv; ++w) woff += wsum[w];
    if (tid < NB) partials[tid] = woff + x - v;
}

__global__ void scan3_kernel(const int* __restrict__ lexcl, const int* __restrict__ partials,
                             const int* __restrict__ counts,
                             int* __restrict__ offsets, int* __restrict__ cursor,
                             float* __restrict__ dinv, int N, int E)
{
    int i = blockIdx.x * blockDim.x + threadIdx.x;
    if (i >= N) return;
    int o = lexcl[i] + partials[i >> 10];
    offsets[i] = o;
    cursor[i]  = o;
    dinv[i] = rsqrtf((float)counts[i] + 1.0f);
    if (i == 0) offsets[N] = E;
}

__global__ void scatter_kernel(const int* __restrict__ src, const int* __restrict__ dst,
                               int* __restrict__ cursor, int* __restrict__ csr_src, int E)
{
    int e = blockIdx.x * blockDim.x + threadIdx.x;
    if (e >= E) return;
    int d = dst[e];
    int pos = atomicAdd(&cursor[d], 1);
    csr_src[pos] = src[e];
}

// ---------------- GEMM (x @ W) fused with dinv pre-scale + self-loop init ----------------
template<int CIN, int COUT, int ROWS>
__global__ __launch_bounds__(ROWS * COUT)
void gemm_selfloop_kernel(const float* __restrict__ x, const float* __restrict__ W,
                          const float* __restrict__ b, const float* __restrict__ dinv,
                          float* __restrict__ xws, float* __restrict__ h, int n)
{
    __shared__ float Ws[CIN * COUT];
    __shared__ float xs[ROWS * CIN];
    const int NT = ROWS * COUT;
    const int tid = threadIdx.x;

    for (int i = tid; i < CIN * COUT; i += NT) Ws[i] = W[i];
    const int row0 = blockIdx.x * ROWS;
    for (int i = tid; i < ROWS * CIN; i += NT) {
        int r = i / CIN;
        int rr = row0 + r;
        xs[i] = (rr < n) ? x[(size_t)rr * CIN + (i % CIN)] : 0.0f;
    }
    __syncthreads();

    const int r = tid / COUT;
    const int c = tid % COUT;
    const int row = row0 + r;
    if (row >= n) return;

    float acc = 0.0f;
#pragma unroll
    for (int k = 0; k < CIN; ++k) acc += xs[r * CIN + k] * Ws[k * COUT + c];

    float di = dinv[row];
    float xv = acc * di;
    xws[(size_t)row * COUT + c] = xv;
    h[(size_t)row * COUT + c] = di * xv + b[c];
}

// ---------------- CSR gather-aggregate (no atomics) ----------------
// unroll 8: 8 independent gathered rows in flight per wave iteration
template<int F>
__global__ __launch_bounds__(256)
void csr_agg_kernel(const int* __restrict__ csr_src, const int* __restrict__ offsets,
                    const float* __restrict__ xws, const float* __restrict__ dinv,
                    float* __restrict__ h, int n)
{
    constexpr int SUB = 64 / F;           // nodes per wave
    const int lane = threadIdx.x & 63;
    const int wid  = (blockIdx.x * (blockDim.x >> 6)) + (threadIdx.x >> 6);
    const int sub  = lane / F;
    const int f    = lane % F;
    const int node = wid * SUB + sub;
    const int lbase = sub * F;

    const bool valid = (node < n);
    const int nc   = valid ? node : 0;
    const int off0 = offsets[nc];
    const int off1 = valid ? offsets[nc + 1] : off0;

    float acc0 = 0.0f, acc1 = 0.0f, acc2 = 0.0f, acc3 = 0.0f;
    for (int k = off0; k < off1; k += F) {
        int nk = off1 - k; if (nk > F) nk = F;
        int sj = (f < nk) ? csr_src[k + f] : 0;
        int t = 0;
        for (; t + 8 <= nk; t += 8) {
            int s0 = __shfl(sj, lbase + t);
            int s1 = __shfl(sj, lbase + t + 1);
            int s2 = __shfl(sj, lbase + t + 2);
            int s3 = __shfl(sj, lbase + t + 3);
            int s4 = __shfl(sj, lbase + t + 4);
            int s5 = __shfl(sj, lbase + t + 5);
            int s6 = __shfl(sj, lbase + t + 6);
            int s7 = __shfl(sj, lbase + t + 7);
            float v0 = xws[(size_t)s0 * F + f];
            float v1 = xws[(size_t)s1 * F + f];
            float v2 = xws[(size_t)s2 * F + f];
            float v3 = xws[(size_t)s3 * F + f];
            float v4 = xws[(size_t)s4 * F + f];
            float v5 = xws[(size_t)s5 * F + f];
            float v6 = xws[(size_t)s6 * F + f];
            float v7 = xws[(size_t)s7 * F + f];
            acc0 += v0 + v4;
            acc1 += v1 + v5;
            acc2 += v2 + v6;
            acc3 += v3 + v7;
        }
        for (; t < nk; ++t) {
            int s = __shfl(sj, lbase + t);
            acc0 += xws[(size_t)s * F + f];
        }
    }
    if (valid) h[(size_t)node * F + f] += dinv[node] * ((acc0 + acc1) + (acc2 + acc3));
}

// ---------------- mean pool ----------------
__global__ void pool_sum_kernel(const float* __restrict__ h, const int* __restrict__ batch,
                                float* __restrict__ pooled, float* __restrict__ cnt, int n)
{
    int t = blockIdx.x * blockDim.x + threadIdx.x;
    int i = t >> 5;          // node
    int f = t & 31;          // feature (OUT_F == 32)
    if (i >= n) return;
    int g = batch[i];
    atomicAdd(&pooled[(size_t)g * OUT_F + f], h[(size_t)i * OUT_F + f]);
    if (f == 0) atomicAdd(&cnt[g], 1.0f);
}

__global__ void pool_div_kernel(float* __restrict__ pooled, const float* __restrict__ cnt, int B)
{
    int t = blockIdx.x * blockDim.x + threadIdx.x;
    if (t >= B * OUT_F) return;
    int g = t >> 5;
    pooled[t] /= fmaxf(cnt[g], 1.0f);
}

// ---------------- gate: softmax([p0|p1] @ Wc + bc) ----------------
__global__ void gate_kernel(const float* __restrict__ p0, const float* __restrict__ p1,
                            const float* __restrict__ Wc, const float* __restrict__ bc,
                            float* __restrict__ gate, int B)
{
    int g = blockIdx.x * blockDim.x + threadIdx.x;
    if (g >= B) return;
    float xv[2 * OUT_F];
#pragma unroll
    for (int k = 0; k < OUT_F; ++k) xv[k] = p0[(size_t)g * OUT_F + k];
#pragma unroll
    for (int k = 0; k < OUT_F; ++k) xv[OUT_F + k] = p1[(size_t)g * OUT_F + k];

    float lg[NEXP];
    float m = -1e30f;
#pragma unroll
    for (int e = 0; e < NEXP; ++e) {
        float acc = bc[e];
#pragma unroll
        for (int k = 0; k < 2 * OUT_F; ++k) acc += xv[k] * Wc[k * NEXP + e];
        lg[e] = acc;
        m = fmaxf(m, acc);
    }
    float se = 0.0f;
#pragma unroll
    for (int e = 0; e < NEXP; ++e) { lg[e] = expf(lg[e] - m); se += lg[e]; }
    float inv = 1.0f / se;
#pragma unroll
    for (int e = 0; e < NEXP; ++e) gate[(size_t)g * NEXP + e] = lg[e] * inv;
}

__global__ void zero_scalar_kernel(float* p) { *p = 0.0f; }

// ---------------- distortion loss ----------------
// One edge per wave per iteration. Lane l covers float4 elem l (expert l>>4)
// and l+64 (expert 4+(l>>4)); 4 butterfly rounds in the 16-lane group,
// lane-local 8-wide softmax, 2 cross-group butterflies (16, 32).
// Grid 1024 blocks (A/B vs r8's 2048): fewer concurrent random-gather waves
// sustained HIGHER L3 throughput in r2 (1.33 vs 1.16 TB/s).
__global__ __launch_bounds__(256)
void distortion_kernel(const float* __restrict__ emb, const float* __restrict__ gate,
                       const float* __restrict__ dis,
                       const int* __restrict__ s_idx, const int* __restrict__ d_idx,
                       float* __restrict__ loss, int E2)
{
    int gt = blockIdx.x * blockDim.x + threadIdx.x;
    int wid = gt >> 6;
    int lane = threadIdx.x & 63;
    int grp = lane >> 4;                 // 16-lane group = expert pair (grp, grp+4)
    int nw = (gridDim.x * blockDim.x) >> 6;

    const float4* emb4  = (const float4*)emb;
    const float4* gate4 = (const float4*)gate;

    float lsum = 0.0f;
    for (int e = wid; e < E2; e += nw) {
        int s = s_idx[e], d = d_idx[e];
        const float4* es = emb4 + (size_t)s * 128;
        const float4* ed = emb4 + (size_t)d * 128;

        float4 a0 = es[lane];
        float4 b0 = ed[lane];
        float4 a1 = es[lane + 64];
        float4 b1 = ed[lane + 64];
        float4 gs0 = gate4[(size_t)s * 2];
        float4 gs1 = gate4[(size_t)s * 2 + 1];
        float4 gd0 = gate4[(size_t)d * 2];
        float4 gd1 = gate4[(size_t)d * 2 + 1];
        float dv = dis[e];

        float dx, pa, pb;
        dx = a0.x - b0.x; pa  = dx * dx;
        dx = a0.y - b0.y; pa += dx * dx;
        dx = a0.z - b0.z; pa += dx * dx;
        dx = a0.w - b0.w; pa += dx * dx;
        dx = a1.x - b1.x; pb  = dx * dx;
        dx = a1.y - b1.y; pb += dx * dx;
        dx = a1.z - b1.z; pb += dx * dx;
        dx = a1.w - b1.w; pb += dx * dx;

#pragma unroll
        for (int off = 1; off < 16; off <<= 1) {
            pa += __shfl_xor(pa, off);
            pb += __shfl_xor(pb, off);
        }

        float gp[NEXP] = { gs0.x * gd0.x, gs0.y * gd0.y, gs0.z * gd0.z, gs0.w * gd0.w,
                           gs1.x * gd1.x, gs1.y * gd1.y, gs1.z * gd1.z, gs1.w * gd1.w };
        float m = gp[0];
#pragma unroll
        for (int j = 1; j < NEXP; ++j) m = fmaxf(m, gp[j]);
        float se = 0.0f;
#pragma unroll
        for (int j = 0; j < NEXP; ++j) { gp[j] = expf(gp[j] - m); se += gp[j]; }

        float v = pa * gp[grp] + pb * gp[grp + 4];
        v += __shfl_xor(v, 16);
        v += __shfl_xor(v, 32);

        lsum += fabsf((v / se) / dv - 1.0f);
    }
    if (lane == 0) atomicAdd(loss, lsum / (float)E2);
}

// ---------------- launch ----------------
extern "C" void kernel_launch(void* const* d_in, const int* in_sizes, int n_in,
                              void* d_out, int out_size, void* d_ws, size_t ws_size,
                              hipStream_t stream)
{
    const float* x0   = (const float*)d_in[0];
    const float* x1   = (const float*)d_in[1];
    const float* W1   = (const float*)d_in[2];
    const float* b1   = (const float*)d_in[3];
    const float* W2   = (const float*)d_in[4];
    const float* b2   = (const float*)d_in[5];
    const float* Wc   = (const float*)d_in[6];
    const float* bc   = (const float*)d_in[7];
    const float* emb  = (const float*)d_in[8];
    const float* dis  = (const float*)d_in[9];
    const int*   ei0  = (const int*)d_in[10];
    const int*   ei1  = (const int*)d_in[11];
    const int*   bat0 = (const int*)d_in[12];
    const int*   bat1 = (const int*)d_in[13];
    const int*   ei2  = (const int*)d_in[14];

    const int N  = in_sizes[0] / IN_F;
    const int E  = in_sizes[10] / 2;
    const int B  = in_sizes[8] / (NEXP * EMB);
    const int E2 = in_sizes[14] / 2;

    float* gate_out = (float*)d_out;               // B*NEXP
    float* loss_out = gate_out + (size_t)B * NEXP; // 1

    // workspace layout
    float* ws      = (float*)d_ws;
    float* dinv    = ws;                           // N
    float* bufA    = dinv + N;                     // N*64  (xws1; then xws2|h2)
    float* bufB    = bufA + (size_t)N * 64;        // N*64  (h1)
    float* pooled0 = bufB + (size_t)N * 64;        // B*32
    float* pooled1 = pooled0 + (size_t)B * OUT_F;  // B*32
    float* cnt     = pooled1 + (size_t)B * OUT_F;  // B
    int*   iws     = (int*)(cnt + B);
    int*   counts  = iws;                          // N
    int*   offsets = counts + N;                   // N+1
    int*   cursor  = offsets + N + 1;              // N
    int*   csr_src = cursor + N;                   // E
    int*   lexcl   = csr_src + E;                  // N
    int*   partials= lexcl + N;                    // <=1024

    const int TB = 256;
    const int zgrid = 512;
    const int NB = (N + 1023) / 1024;              // scan blocks (<=1024)

    for (int g = 0; g < 2; ++g) {
        const float* x    = (g == 0) ? x0 : x1;
        const int* src    = (g == 0) ? ei0 : ei1;
        const int* dst    = src + E;
        const int* batch  = (g == 0) ? bat0 : bat1;
        float* pooled     = (g == 0) ? pooled0 : pooled1;

        float* xws1 = bufA;
        float* h1   = bufB;
        float* xws2 = bufA;                          // reuse (xws1 dead after agg1)
        float* h2   = bufA + (size_t)N * OUT_F;

        // CSR build (shared by both convs) + dinv
        zero_i32_kernel<<<zgrid, TB, 0, stream>>>(counts, N);
        hist_kernel<<<(E + TB - 1) / TB, TB, 0, stream>>>(dst, counts, E);
        scan1_kernel<<<NB, 1024, 0, stream>>>(counts, lexcl, partials, N);
        scan2_kernel<<<1, 1024, 0, stream>>>(partials, NB);
        scan3_kernel<<<(N + TB - 1) / TB, TB, 0, stream>>>(lexcl, partials, counts,
                                                           offsets, cursor, dinv, N, E);
        scatter_kernel<<<(E + TB - 1) / TB, TB, 0, stream>>>(src, dst, cursor, csr_src, E);

        // conv1: 64 -> 64
        gemm_selfloop_kernel<IN_F, HID_F, 4>
            <<<(N + 3) / 4, 4 * HID_F, 0, stream>>>(x, W1, b1, dinv, xws1, h1, N);
        csr_agg_kernel<HID_F>
            <<<(N + 3) / 4, TB, 0, stream>>>(csr_src, offsets, xws1, dinv, h1, N);

        // conv2: 64 -> 32
        gemm_selfloop_kernel<HID_F, OUT_F, 8>
            <<<(N + 7) / 8, 8 * OUT_F, 0, stream>>>(h1, W2, b2, dinv, xws2, h2, N);
        csr_agg_kernel<OUT_F>
            <<<(N + 7) / 8, TB, 0, stream>>>(csr_src, offsets, xws2, dinv, h2, N);

        // mean pool
        zero_f32_kernel<<<zgrid, TB, 0, stream>>>(pooled, (long long)B * OUT_F);
        zero_f32_kernel<<<zgrid, TB, 0, stream>>>(cnt, B);
        pool_sum_kernel<<<((N * 32) + TB - 1) / TB, TB, 0, stream>>>(h2, batch, pooled, cnt, N);
        pool_div_kernel<<<((B * OUT_F) + TB - 1) / TB, TB, 0, stream>>>(pooled, cnt, B);
    }

    // gate
    gate_kernel<<<(B + TB - 1) / TB, TB, 0, stream>>>(pooled0, pooled1, Wc, bc, gate_out, B);

    // distortion loss
    zero_scalar_kernel<<<1, 1, 0, stream>>>(loss_out);
    distortion_kernel<<<1024, TB, 0, stream>>>(emb, gate_out, dis,
                                               ei2, ei2 + E2, loss_out, E2);
}

// Round 10
// 543.800 us; speedup vs baseline: 1.1522x; 1.0576x over previous
//
#include <hip/hip_runtime.h>
#include <math.h>

// ---------------- constants from the reference ----------------
constexpr int IN_F  = 64;
constexpr int HID_F = 64;
constexpr int OUT_F = 32;
constexpr int NEXP  = 8;
constexpr int EMB   = 64;   // emb_dim

// Encoder is linear (no activation between the two GCNConv layers):
//   h2 = A^(A^(X W1)+b1)W2 + b2 = A^(A^(X W12)) + t*(b1 W2) + b2
// with W12 = W1@W2 (64x32), t_i = A^(1)_i = dinv_i*(dinv_i + sum_in dinv_j).
// Both aggregation passes are 32-wide (was 64+32).

// ---------------- utility kernels ----------------
__global__ void zero_f32_kernel(float* __restrict__ p, long long n) {
    long long i = (long long)blockIdx.x * blockDim.x + threadIdx.x;
    long long stride = (long long)gridDim.x * blockDim.x;
    for (; i < n; i += stride) p[i] = 0.0f;
}

__global__ void zero_i32_kernel(int* __restrict__ p, long long n) {
    long long i = (long long)blockIdx.x * blockDim.x + threadIdx.x;
    long long stride = (long long)gridDim.x * blockDim.x;
    for (; i < n; i += stride) p[i] = 0;
}

// ---------------- W12 = W1@W2, c1 = b1@W2 (once) ----------------
__global__ __launch_bounds__(1024)
void w12_kernel(const float* __restrict__ W1, const float* __restrict__ W2,
                const float* __restrict__ b1,
                float* __restrict__ W12, float* __restrict__ c1)
{
    __shared__ float sW2[HID_F * OUT_F];
    const int tid = threadIdx.x;
    for (int i = tid; i < HID_F * OUT_F; i += 1024) sW2[i] = W2[i];
    __syncthreads();
    for (int idx = tid; idx < IN_F * OUT_F; idx += 1024) {
        int i = idx >> 5, j = idx & 31;
        float acc = 0.0f;
#pragma unroll
        for (int k = 0; k < HID_F; ++k) acc += W1[i * HID_F + k] * sW2[k * OUT_F + j];
        W12[idx] = acc;
    }
    if (tid < OUT_F) {
        float acc = 0.0f;
#pragma unroll
        for (int k = 0; k < HID_F; ++k) acc += b1[k] * sW2[k * OUT_F + tid];
        c1[tid] = acc;
    }
}

// ---------------- CSR build ----------------
__global__ void hist_kernel(const int* __restrict__ dst, int* __restrict__ counts, int E) {
    int e = blockIdx.x * blockDim.x + threadIdx.x;
    if (e >= E) return;
    atomicAdd(&counts[dst[e]], 1);
}

// two-level exclusive scan (race-free)
__global__ __launch_bounds__(1024)
void scan1_kernel(const int* __restrict__ counts, int* __restrict__ lexcl,
                  int* __restrict__ partials, int N)
{
    __shared__ int wsum[16];
    const int tid  = threadIdx.x;
    const int lane = tid & 63;
    const int wv   = tid >> 6;
    const int i    = blockIdx.x * 1024 + tid;

    int v = (i < N) ? counts[i] : 0;
    int x = v;
#pragma unroll
    for (int off = 1; off < 64; off <<= 1) {
        int t = __shfl_up(x, off);
        if (lane >= off) x += t;
    }
    if (lane == 63) wsum[wv] = x;
    __syncthreads();
    int woff = 0;
    for (int w = 0; w < wv; ++w) woff += wsum[w];
    if (i < N) lexcl[i] = woff + x - v;
    if (tid == 1023) partials[blockIdx.x] = woff + x;
}

__global__ __launch_bounds__(1024)
void scan2_kernel(int* __restrict__ partials, int NB)
{
    __shared__ int wsum[16];
    const int tid  = threadIdx.x;
    const int lane = tid & 63;
    const int wv   = tid >> 6;
    int v = (tid < NB) ? partials[tid] : 0;
    int x = v;
#pragma unroll
    for (int off = 1; off < 64; off <<= 1) {
        int t = __shfl_up(x, off);
        if (lane >= off) x += t;
    }
    if (lane == 63) wsum[wv] = x;
    __syncthreads();
    int woff = 0;
    for (int w = 0; w < wv; ++w) woff += wsum[w];
    if (tid < NB) partials[tid] = woff + x - v;
}

// combine -> offsets/cursor, dinv = rsqrt(deg+1), zero sdsum
__global__ void scan3_kernel(const int* __restrict__ lexcl, const int* __restrict__ partials,
                             const int* __restrict__ counts,
                             int* __restrict__ offsets, int* __restrict__ cursor,
                             float* __restrict__ dinv, float* __restrict__ sdsum,
                             int N, int E)
{
    int i = blockIdx.x * blockDim.x + threadIdx.x;
    if (i >= N) return;
    int o = lexcl[i] + partials[i >> 10];
    offsets[i] = o;
    cursor[i]  = o;
    dinv[i] = rsqrtf((float)counts[i] + 1.0f);
    sdsum[i] = 0.0f;
    if (i == 0) offsets[N] = E;
}

// scatter edges into CSR; fused scalar aggregation sdsum[d] += dinv[s]
__global__ void scatter_kernel(const int* __restrict__ src, const int* __restrict__ dst,
                               const float* __restrict__ dinv,
                               int* __restrict__ cursor, int* __restrict__ csr_src,
                               float* __restrict__ sdsum, int E)
{
    int e = blockIdx.x * blockDim.x + threadIdx.x;
    if (e >= E) return;
    int d = dst[e];
    int s = src[e];
    int pos = atomicAdd(&cursor[d], 1);
    csr_src[pos] = s;
    atomicAdd(&sdsum[d], dinv[s]);
}

// ---------------- GEMM: Ys = (X @ W12) * dinv (pre-scaled for gather) ----------------
__global__ __launch_bounds__(256)
void gemm_ys_kernel(const float* __restrict__ x, const float* __restrict__ W12,
                    const float* __restrict__ dinv, float* __restrict__ Ys, int n)
{
    __shared__ float Ws[IN_F * OUT_F];
    __shared__ float xs[8 * IN_F];
    const int tid = threadIdx.x;

    for (int i = tid; i < IN_F * OUT_F; i += 256) Ws[i] = W12[i];
    const int row0 = blockIdx.x * 8;
    for (int i = tid; i < 8 * IN_F; i += 256) {
        int r = i >> 6;
        int rr = row0 + r;
        xs[i] = (rr < n) ? x[(size_t)rr * IN_F + (i & 63)] : 0.0f;
    }
    __syncthreads();

    const int r = tid >> 5;
    const int c = tid & 31;
    const int row = row0 + r;
    if (row >= n) return;

    float acc = 0.0f;
#pragma unroll
    for (int k = 0; k < IN_F; ++k) acc += xs[r * IN_F + k] * Ws[k * OUT_F + c];

    Ys[(size_t)row * OUT_F + c] = acc * dinv[row];
}

// ---------------- CSR gather-aggregate, 32-wide, unroll 8 ----------------
// MODE 0: out_i = dinv_i^2 * (in_i + sum_j in_j)                    (Zs pass)
// MODE 1: out_i = dinv_i   * (in_i + sum_j in_j) + t_i*c1 + b2      (P pass)
//         with t_i = dinv_i*(dinv_i + sdsum_i)
template<int MODE>
__global__ __launch_bounds__(256)
void csr_agg32_kernel(const int* __restrict__ csr_src, const int* __restrict__ offsets,
                      const float* __restrict__ in, const float* __restrict__ dinv,
                      const float* __restrict__ sdsum, const float* __restrict__ c1,
                      const float* __restrict__ b2,
                      float* __restrict__ out, int n)
{
    constexpr int F = OUT_F;              // 32
    const int lane = threadIdx.x & 63;
    const int wid  = (blockIdx.x * (blockDim.x >> 6)) + (threadIdx.x >> 6);
    const int sub  = lane >> 5;           // 2 nodes per wave
    const int f    = lane & 31;
    const int node = wid * 2 + sub;
    const int lbase = sub * F;

    const bool valid = (node < n);
    const int nc   = valid ? node : 0;
    const int off0 = offsets[nc];
    const int off1 = valid ? offsets[nc + 1] : off0;

    float acc0 = valid ? in[(size_t)nc * F + f] : 0.0f;   // self term
    float acc1 = 0.0f, acc2 = 0.0f, acc3 = 0.0f;
    for (int k = off0; k < off1; k += F) {
        int nk = off1 - k; if (nk > F) nk = F;
        int sj = (f < nk) ? csr_src[k + f] : 0;
        int t = 0;
        for (; t + 8 <= nk; t += 8) {
            int s0 = __shfl(sj, lbase + t);
            int s1 = __shfl(sj, lbase + t + 1);
            int s2 = __shfl(sj, lbase + t + 2);
            int s3 = __shfl(sj, lbase + t + 3);
            int s4 = __shfl(sj, lbase + t + 4);
            int s5 = __shfl(sj, lbase + t + 5);
            int s6 = __shfl(sj, lbase + t + 6);
            int s7 = __shfl(sj, lbase + t + 7);
            float v0 = in[(size_t)s0 * F + f];
            float v1 = in[(size_t)s1 * F + f];
            float v2 = in[(size_t)s2 * F + f];
            float v3 = in[(size_t)s3 * F + f];
            float v4 = in[(size_t)s4 * F + f];
            float v5 = in[(size_t)s5 * F + f];
            float v6 = in[(size_t)s6 * F + f];
            float v7 = in[(size_t)s7 * F + f];
            acc0 += v0 + v4;
            acc1 += v1 + v5;
            acc2 += v2 + v6;
            acc3 += v3 + v7;
        }
        for (; t < nk; ++t) {
            int s = __shfl(sj, lbase + t);
            acc0 += in[(size_t)s * F + f];
        }
    }
    if (valid) {
        float di = dinv[node];
        float s = (acc0 + acc1) + (acc2 + acc3);
        if (MODE == 0) {
            out[(size_t)node * F + f] = di * di * s;
        } else {
            float t = di * (di + sdsum[node]);
            out[(size_t)node * F + f] = di * s + t * c1[f] + b2[f];
        }
    }
}

// ---------------- mean pool ----------------
__global__ void pool_sum_kernel(const float* __restrict__ h, const int* __restrict__ batch,
                                float* __restrict__ pooled, float* __restrict__ cnt, int n)
{
    int t = blockIdx.x * blockDim.x + threadIdx.x;
    int i = t >> 5;          // node
    int f = t & 31;          // feature (OUT_F == 32)
    if (i >= n) return;
    int g = batch[i];
    atomicAdd(&pooled[(size_t)g * OUT_F + f], h[(size_t)i * OUT_F + f]);
    if (f == 0) atomicAdd(&cnt[g], 1.0f);
}

__global__ void pool_div_kernel(float* __restrict__ pooled, const float* __restrict__ cnt, int B)
{
    int t = blockIdx.x * blockDim.x + threadIdx.x;
    if (t >= B * OUT_F) return;
    int g = t >> 5;
    pooled[t] /= fmaxf(cnt[g], 1.0f);
}

// ---------------- gate: softmax([p0|p1] @ Wc + bc) ----------------
__global__ void gate_kernel(const float* __restrict__ p0, const float* __restrict__ p1,
                            const float* __restrict__ Wc, const float* __restrict__ bc,
                            float* __restrict__ gate, int B)
{
    int g = blockIdx.x * blockDim.x + threadIdx.x;
    if (g >= B) return;
    float xv[2 * OUT_F];
#pragma unroll
    for (int k = 0; k < OUT_F; ++k) xv[k] = p0[(size_t)g * OUT_F + k];
#pragma unroll
    for (int k = 0; k < OUT_F; ++k) xv[OUT_F + k] = p1[(size_t)g * OUT_F + k];

    float lg[NEXP];
    float m = -1e30f;
#pragma unroll
    for (int e = 0; e < NEXP; ++e) {
        float acc = bc[e];
#pragma unroll
        for (int k = 0; k < 2 * OUT_F; ++k) acc += xv[k] * Wc[k * NEXP + e];
        lg[e] = acc;
        m = fmaxf(m, acc);
    }
    float se = 0.0f;
#pragma unroll
    for (int e = 0; e < NEXP; ++e) { lg[e] = expf(lg[e] - m); se += lg[e]; }
    float inv = 1.0f / se;
#pragma unroll
    for (int e = 0; e < NEXP; ++e) gate[(size_t)g * NEXP + e] = lg[e] * inv;
}

__global__ void zero_scalar_kernel(float* p) { *p = 0.0f; }

// ---------------- distortion loss ----------------
// One edge per wave per iteration, grid 1024 (r9-verified: fewer random-gather
// waves = shorter TCC queues = 1.5 TB/s vs 1.16 at 2048 blocks).
__global__ __launch_bounds__(256)
void distortion_kernel(const float* __restrict__ emb, const float* __restrict__ gate,
                       const float* __restrict__ dis,
                       const int* __restrict__ s_idx, const int* __restrict__ d_idx,
                       float* __restrict__ loss, int E2)
{
    int gt = blockIdx.x * blockDim.x + threadIdx.x;
    int wid = gt >> 6;
    int lane = threadIdx.x & 63;
    int grp = lane >> 4;                 // 16-lane group = expert pair (grp, grp+4)
    int nw = (gridDim.x * blockDim.x) >> 6;

    const float4* emb4  = (const float4*)emb;
    const float4* gate4 = (const float4*)gate;

    float lsum = 0.0f;
    for (int e = wid; e < E2; e += nw) {
        int s = s_idx[e], d = d_idx[e];
        const float4* es = emb4 + (size_t)s * 128;
        const float4* ed = emb4 + (size_t)d * 128;

        float4 a0 = es[lane];
        float4 b0 = ed[lane];
        float4 a1 = es[lane + 64];
        float4 b1 = ed[lane + 64];
        float4 gs0 = gate4[(size_t)s * 2];
        float4 gs1 = gate4[(size_t)s * 2 + 1];
        float4 gd0 = gate4[(size_t)d * 2];
        float4 gd1 = gate4[(size_t)d * 2 + 1];
        float dv = dis[e];

        float dx, pa, pb;
        dx = a0.x - b0.x; pa  = dx * dx;
        dx = a0.y - b0.y; pa += dx * dx;
        dx = a0.z - b0.z; pa += dx * dx;
        dx = a0.w - b0.w; pa += dx * dx;
        dx = a1.x - b1.x; pb  = dx * dx;
        dx = a1.y - b1.y; pb += dx * dx;
        dx = a1.z - b1.z; pb += dx * dx;
        dx = a1.w - b1.w; pb += dx * dx;

#pragma unroll
        for (int off = 1; off < 16; off <<= 1) {
            pa += __shfl_xor(pa, off);
            pb += __shfl_xor(pb, off);
        }

        float gp[NEXP] = { gs0.x * gd0.x, gs0.y * gd0.y, gs0.z * gd0.z, gs0.w * gd0.w,
                           gs1.x * gd1.x, gs1.y * gd1.y, gs1.z * gd1.z, gs1.w * gd1.w };
        float m = gp[0];
#pragma unroll
        for (int j = 1; j < NEXP; ++j) m = fmaxf(m, gp[j]);
        float se = 0.0f;
#pragma unroll
        for (int j = 0; j < NEXP; ++j) { gp[j] = expf(gp[j] - m); se += gp[j]; }

        float v = pa * gp[grp] + pb * gp[grp + 4];
        v += __shfl_xor(v, 16);
        v += __shfl_xor(v, 32);

        lsum += fabsf((v / se) / dv - 1.0f);
    }
    if (lane == 0) atomicAdd(loss, lsum / (float)E2);
}

// ---------------- launch ----------------
extern "C" void kernel_launch(void* const* d_in, const int* in_sizes, int n_in,
                              void* d_out, int out_size, void* d_ws, size_t ws_size,
                              hipStream_t stream)
{
    const float* x0   = (const float*)d_in[0];
    const float* x1   = (const float*)d_in[1];
    const float* W1   = (const float*)d_in[2];
    const float* b1   = (const float*)d_in[3];
    const float* W2   = (const float*)d_in[4];
    const float* b2   = (const float*)d_in[5];
    const float* Wc   = (const float*)d_in[6];
    const float* bc   = (const float*)d_in[7];
    const float* emb  = (const float*)d_in[8];
    const float* dis  = (const float*)d_in[9];
    const int*   ei0  = (const int*)d_in[10];
    const int*   ei1  = (const int*)d_in[11];
    const int*   bat0 = (const int*)d_in[12];
    const int*   bat1 = (const int*)d_in[13];
    const int*   ei2  = (const int*)d_in[14];

    const int N  = in_sizes[0] / IN_F;
    const int E  = in_sizes[10] / 2;
    const int B  = in_sizes[8] / (NEXP * EMB);
    const int E2 = in_sizes[14] / 2;

    float* gate_out = (float*)d_out;               // B*NEXP
    float* loss_out = gate_out + (size_t)B * NEXP; // 1

    // workspace layout
    float* ws      = (float*)d_ws;
    float* dinv    = ws;                           // N
    float* Ys      = dinv + N;                     // N*32  (also P: aggB output)
    float* Zs      = Ys + (size_t)N * OUT_F;       // N*32
    float* sdsum   = Zs + (size_t)N * OUT_F;       // N
    float* pooled0 = sdsum + N;                    // B*32
    float* pooled1 = pooled0 + (size_t)B * OUT_F;  // B*32
    float* cnt     = pooled1 + (size_t)B * OUT_F;  // B
    float* W12     = cnt + B;                      // 64*32
    float* c1      = W12 + IN_F * OUT_F;           // 32
    int*   iws     = (int*)(c1 + OUT_F);
    int*   counts  = iws;                          // N
    int*   offsets = counts + N;                   // N+1
    int*   cursor  = offsets + N + 1;              // N
    int*   csr_src = cursor + N;                   // E
    int*   lexcl   = csr_src + E;                  // N
    int*   partials= lexcl + N;                    // <=1024

    const int TB = 256;
    const int zgrid = 512;
    const int NB = (N + 1023) / 1024;              // scan blocks (<=1024)

    // W12 = W1@W2, c1 = b1@W2 (once)
    w12_kernel<<<1, 1024, 0, stream>>>(W1, W2, b1, W12, c1);

    for (int g = 0; g < 2; ++g) {
        const float* x    = (g == 0) ? x0 : x1;
        const int* src    = (g == 0) ? ei0 : ei1;
        const int* dst    = src + E;
        const int* batch  = (g == 0) ? bat0 : bat1;
        float* pooled     = (g == 0) ? pooled0 : pooled1;

        // CSR build + dinv + sdsum (scalar bias aggregation fused into scatter)
        zero_i32_kernel<<<zgrid, TB, 0, stream>>>(counts, N);
        hist_kernel<<<(E + TB - 1) / TB, TB, 0, stream>>>(dst, counts, E);
        scan1_kernel<<<NB, 1024, 0, stream>>>(counts, lexcl, partials, N);
        scan2_kernel<<<1, 1024, 0, stream>>>(partials, NB);
        scan3_kernel<<<(N + TB - 1) / TB, TB, 0, stream>>>(lexcl, partials, counts,
                                                           offsets, cursor, dinv, sdsum, N, E);
        scatter_kernel<<<(E + TB - 1) / TB, TB, 0, stream>>>(src, dst, dinv, cursor,
                                                             csr_src, sdsum, E);

        // Ys = (X @ W12) * dinv
        gemm_ys_kernel<<<(N + 7) / 8, 256, 0, stream>>>(x, W12, dinv, Ys, N);

        // Zs = dinv^2 * (Ys + gather-sum(Ys))
        csr_agg32_kernel<0><<<(N + 7) / 8, TB, 0, stream>>>(csr_src, offsets, Ys, dinv,
                                                            nullptr, nullptr, nullptr, Zs, N);
        // P = dinv * (Zs + gather-sum(Zs)) + t*c1 + b2   (P overwrites Ys)
        csr_agg32_kernel<1><<<(N + 7) / 8, TB, 0, stream>>>(csr_src, offsets, Zs, dinv,
                                                            sdsum, c1, b2, Ys, N);

        // mean pool
        zero_f32_kernel<<<zgrid, TB, 0, stream>>>(pooled, (long long)B * OUT_F);
        zero_f32_kernel<<<zgrid, TB, 0, stream>>>(cnt, B);
        pool_sum_kernel<<<((N * 32) + TB - 1) / TB, TB, 0, stream>>>(Ys, batch, pooled, cnt, N);
        pool_div_kernel<<<((B * OUT_F) + TB - 1) / TB, TB, 0, stream>>>(pooled, cnt, B);
    }

    // gate
    gate_kernel<<<(B + TB - 1) / TB, TB, 0, stream>>>(pooled0, pooled1, Wc, bc, gate_out, B);

    // distortion loss
    zero_scalar_kernel<<<1, 1, 0, stream>>>(loss_out);
    distortion_kernel<<<1024, TB, 0, stream>>>(emb, gate_out, dis,
                                               ei2, ei2 + E2, loss_out, E2);
}

// Round 11
// 517.543 us; speedup vs baseline: 1.2107x; 1.0507x over previous
//
#include <hip/hip_runtime.h>
#include <math.h>

// ---------------- constants from the reference ----------------
constexpr int IN_F  = 64;
constexpr int HID_F = 64;
constexpr int OUT_F = 32;
constexpr int NEXP  = 8;
constexpr int EMB   = 64;   // emb_dim

// Encoder is linear: h2 = A^(A^(X W12)) + t*(b1 W2) + b2, W12 = W1@W2.
// Both subgraphs fused into one pipeline over 2N nodes / 2E edges
// (graph-1 nodes offset by N, graph ids offset by B).

// ---------------- utility kernels ----------------
__global__ void zero_f32_kernel(float* __restrict__ p, long long n) {
    long long i = (long long)blockIdx.x * blockDim.x + threadIdx.x;
    long long stride = (long long)gridDim.x * blockDim.x;
    for (; i < n; i += stride) p[i] = 0.0f;
}

__global__ void zero_i32_kernel(int* __restrict__ p, long long n) {
    long long i = (long long)blockIdx.x * blockDim.x + threadIdx.x;
    long long stride = (long long)gridDim.x * blockDim.x;
    for (; i < n; i += stride) p[i] = 0;
}

// ---------------- W12 = W1@W2, c1 = b1@W2 (once) ----------------
__global__ __launch_bounds__(1024)
void w12_kernel(const float* __restrict__ W1, const float* __restrict__ W2,
                const float* __restrict__ b1,
                float* __restrict__ W12, float* __restrict__ c1)
{
    __shared__ float sW2[HID_F * OUT_F];
    const int tid = threadIdx.x;
    for (int i = tid; i < HID_F * OUT_F; i += 1024) sW2[i] = W2[i];
    __syncthreads();
    for (int idx = tid; idx < IN_F * OUT_F; idx += 1024) {
        int i = idx >> 5, j = idx & 31;
        float acc = 0.0f;
#pragma unroll
        for (int k = 0; k < HID_F; ++k) acc += W1[i * HID_F + k] * sW2[k * OUT_F + j];
        W12[idx] = acc;
    }
    if (tid < OUT_F) {
        float acc = 0.0f;
#pragma unroll
        for (int k = 0; k < HID_F; ++k) acc += b1[k] * sW2[k * OUT_F + tid];
        c1[tid] = acc;
    }
}

// ---------------- fused CSR build over both graphs ----------------
__global__ void hist2_kernel(const int* __restrict__ ei0, const int* __restrict__ ei1,
                             int* __restrict__ counts, int E, int N)
{
    int e = blockIdx.x * blockDim.x + threadIdx.x;
    if (e >= 2 * E) return;
    int d = (e < E) ? ei0[E + e] : (ei1[E + (e - E)] + N);
    atomicAdd(&counts[d], 1);
}

// two-level exclusive scan (race-free)
__global__ __launch_bounds__(1024)
void scan1_kernel(const int* __restrict__ counts, int* __restrict__ lexcl,
                  int* __restrict__ partials, int N)
{
    __shared__ int wsum[16];
    const int tid  = threadIdx.x;
    const int lane = tid & 63;
    const int wv   = tid >> 6;
    const int i    = blockIdx.x * 1024 + tid;

    int v = (i < N) ? counts[i] : 0;
    int x = v;
#pragma unroll
    for (int off = 1; off < 64; off <<= 1) {
        int t = __shfl_up(x, off);
        if (lane >= off) x += t;
    }
    if (lane == 63) wsum[wv] = x;
    __syncthreads();
    int woff = 0;
    for (int w = 0; w < wv; ++w) woff += wsum[w];
    if (i < N) lexcl[i] = woff + x - v;
    if (tid == 1023) partials[blockIdx.x] = woff + x;
}

__global__ __launch_bounds__(1024)
void scan2_kernel(int* __restrict__ partials, int NB)
{
    __shared__ int wsum[16];
    const int tid  = threadIdx.x;
    const int lane = tid & 63;
    const int wv   = tid >> 6;
    int v = (tid < NB) ? partials[tid] : 0;
    int x = v;
#pragma unroll
    for (int off = 1; off < 64; off <<= 1) {
        int t = __shfl_up(x, off);
        if (lane >= off) x += t;
    }
    if (lane == 63) wsum[wv] = x;
    __syncthreads();
    int woff = 0;
    for (int w = 0; w < wv; ++w) woff += wsum[w];
    if (tid < NB) partials[tid] = woff + x - v;
}

// combine -> offsets/cursor, dinv = rsqrt(deg+1), zero sdsum  (n2 = 2N nodes)
__global__ void scan3_kernel(const int* __restrict__ lexcl, const int* __restrict__ partials,
                             const int* __restrict__ counts,
                             int* __restrict__ offsets, int* __restrict__ cursor,
                             float* __restrict__ dinv, float* __restrict__ sdsum,
                             int n2, int e2tot)
{
    int i = blockIdx.x * blockDim.x + threadIdx.x;
    if (i >= n2) return;
    int o = lexcl[i] + partials[i >> 10];
    offsets[i] = o;
    cursor[i]  = o;
    dinv[i] = rsqrtf((float)counts[i] + 1.0f);
    sdsum[i] = 0.0f;
    if (i == 0) offsets[n2] = e2tot;
}

// scatter both graphs' edges into CSR; fused sdsum[d] += dinv[s]
__global__ void scatter2_kernel(const int* __restrict__ ei0, const int* __restrict__ ei1,
                                const float* __restrict__ dinv,
                                int* __restrict__ cursor, int* __restrict__ csr_src,
                                float* __restrict__ sdsum, int E, int N)
{
    int e = blockIdx.x * blockDim.x + threadIdx.x;
    if (e >= 2 * E) return;
    int s, d;
    if (e < E) { s = ei0[e];           d = ei0[E + e]; }
    else       { s = ei1[e - E] + N;   d = ei1[E + (e - E)] + N; }
    int pos = atomicAdd(&cursor[d], 1);
    csr_src[pos] = s;
    atomicAdd(&sdsum[d], dinv[s]);
}

// ---------------- GEMM: Ys = (X @ W12) * dinv over 2N rows ----------------
__global__ __launch_bounds__(256)
void gemm_ys2_kernel(const float* __restrict__ x0, const float* __restrict__ x1,
                     const float* __restrict__ W12, const float* __restrict__ dinv,
                     float* __restrict__ Ys, int N, int n2)
{
    __shared__ float Ws[IN_F * OUT_F];
    __shared__ float xs[8 * IN_F];
    const int tid = threadIdx.x;

    for (int i = tid; i < IN_F * OUT_F; i += 256) Ws[i] = W12[i];
    const int row0 = blockIdx.x * 8;
    for (int i = tid; i < 8 * IN_F; i += 256) {
        int r = i >> 6;
        int rr = row0 + r;
        float v = 0.0f;
        if (rr < n2) {
            v = (rr < N) ? x0[(size_t)rr * IN_F + (i & 63)]
                         : x1[(size_t)(rr - N) * IN_F + (i & 63)];
        }
        xs[i] = v;
    }
    __syncthreads();

    const int r = tid >> 5;
    const int c = tid & 31;
    const int row = row0 + r;
    if (row >= n2) return;

    float acc = 0.0f;
#pragma unroll
    for (int k = 0; k < IN_F; ++k) acc += xs[r * IN_F + k] * Ws[k * OUT_F + c];

    Ys[(size_t)row * OUT_F + c] = acc * dinv[row];
}

// ---------------- CSR gather-aggregate, 32-wide, unroll 8 ----------------
// MODE 0: out_i = dinv_i^2 * (in_i + sum_j in_j)
// MODE 1: out_i = dinv_i   * (in_i + sum_j in_j) + t_i*c1 + b2,  t_i = dinv_i*(dinv_i+sdsum_i)
template<int MODE>
__global__ __launch_bounds__(256)
void csr_agg32_kernel(const int* __restrict__ csr_src, const int* __restrict__ offsets,
                      const float* __restrict__ in, const float* __restrict__ dinv,
                      const float* __restrict__ sdsum, const float* __restrict__ c1,
                      const float* __restrict__ b2,
                      float* __restrict__ out, int n)
{
    constexpr int F = OUT_F;              // 32
    const int lane = threadIdx.x & 63;
    const int wid  = (blockIdx.x * (blockDim.x >> 6)) + (threadIdx.x >> 6);
    const int sub  = lane >> 5;           // 2 nodes per wave
    const int f    = lane & 31;
    const int node = wid * 2 + sub;
    const int lbase = sub * F;

    const bool valid = (node < n);
    const int nc   = valid ? node : 0;
    const int off0 = offsets[nc];
    const int off1 = valid ? offsets[nc + 1] : off0;

    float acc0 = valid ? in[(size_t)nc * F + f] : 0.0f;   // self term
    float acc1 = 0.0f, acc2 = 0.0f, acc3 = 0.0f;
    for (int k = off0; k < off1; k += F) {
        int nk = off1 - k; if (nk > F) nk = F;
        int sj = (f < nk) ? csr_src[k + f] : 0;
        int t = 0;
        for (; t + 8 <= nk; t += 8) {
            int s0 = __shfl(sj, lbase + t);
            int s1 = __shfl(sj, lbase + t + 1);
            int s2 = __shfl(sj, lbase + t + 2);
            int s3 = __shfl(sj, lbase + t + 3);
            int s4 = __shfl(sj, lbase + t + 4);
            int s5 = __shfl(sj, lbase + t + 5);
            int s6 = __shfl(sj, lbase + t + 6);
            int s7 = __shfl(sj, lbase + t + 7);
            float v0 = in[(size_t)s0 * F + f];
            float v1 = in[(size_t)s1 * F + f];
            float v2 = in[(size_t)s2 * F + f];
            float v3 = in[(size_t)s3 * F + f];
            float v4 = in[(size_t)s4 * F + f];
            float v5 = in[(size_t)s5 * F + f];
            float v6 = in[(size_t)s6 * F + f];
            float v7 = in[(size_t)s7 * F + f];
            acc0 += v0 + v4;
            acc1 += v1 + v5;
            acc2 += v2 + v6;
            acc3 += v3 + v7;
        }
        for (; t < nk; ++t) {
            int s = __shfl(sj, lbase + t);
            acc0 += in[(size_t)s * F + f];
        }
    }
    if (valid) {
        float di = dinv[node];
        float s = (acc0 + acc1) + (acc2 + acc3);
        if (MODE == 0) {
            out[(size_t)node * F + f] = di * di * s;
        } else {
            float t = di * (di + sdsum[node]);
            out[(size_t)node * F + f] = di * s + t * c1[f] + b2[f];
        }
    }
}

// ---------------- mean pool over both graphs (2N nodes -> 2B graphs) ----------------
__global__ void pool_sum2_kernel(const float* __restrict__ h,
                                 const int* __restrict__ bat0, const int* __restrict__ bat1,
                                 float* __restrict__ pooled, float* __restrict__ cnt,
                                 int N, int n2, int B)
{
    int t = blockIdx.x * blockDim.x + threadIdx.x;
    int i = t >> 5;          // node
    int f = t & 31;          // feature
    if (i >= n2) return;
    int g = (i < N) ? bat0[i] : (bat1[i - N] + B);
    atomicAdd(&pooled[(size_t)g * OUT_F + f], h[(size_t)i * OUT_F + f]);
    if (f == 0) atomicAdd(&cnt[g], 1.0f);
}

__global__ void pool_div_kernel(float* __restrict__ pooled, const float* __restrict__ cnt, int B2)
{
    int t = blockIdx.x * blockDim.x + threadIdx.x;
    if (t >= B2 * OUT_F) return;
    int g = t >> 5;
    pooled[t] /= fmaxf(cnt[g], 1.0f);
}

// ---------------- gate: softmax([p0|p1] @ Wc + bc) ----------------
__global__ void gate_kernel(const float* __restrict__ p0, const float* __restrict__ p1,
                            const float* __restrict__ Wc, const float* __restrict__ bc,
                            float* __restrict__ gate, int B)
{
    int g = blockIdx.x * blockDim.x + threadIdx.x;
    if (g >= B) return;
    float xv[2 * OUT_F];
#pragma unroll
    for (int k = 0; k < OUT_F; ++k) xv[k] = p0[(size_t)g * OUT_F + k];
#pragma unroll
    for (int k = 0; k < OUT_F; ++k) xv[OUT_F + k] = p1[(size_t)g * OUT_F + k];

    float lg[NEXP];
    float m = -1e30f;
#pragma unroll
    for (int e = 0; e < NEXP; ++e) {
        float acc = bc[e];
#pragma unroll
        for (int k = 0; k < 2 * OUT_F; ++k) acc += xv[k] * Wc[k * NEXP + e];
        lg[e] = acc;
        m = fmaxf(m, acc);
    }
    float se = 0.0f;
#pragma unroll
    for (int e = 0; e < NEXP; ++e) { lg[e] = expf(lg[e] - m); se += lg[e]; }
    float inv = 1.0f / se;
#pragma unroll
    for (int e = 0; e < NEXP; ++e) gate[(size_t)g * NEXP + e] = lg[e] * inv;
}

__global__ void zero_scalar_kernel(float* p) { *p = 0.0f; }

// ---------------- distortion: group edges by s (counting sort over B buckets) ----------------
__global__ void histD_kernel(const int* __restrict__ s_idx, int* __restrict__ cntD, int E2) {
    int e = blockIdx.x * blockDim.x + threadIdx.x;
    if (e >= E2) return;
    atomicAdd(&cntD[s_idx[e]], 1);
}

__global__ void combineD_kernel(const int* __restrict__ lexclD, const int* __restrict__ partialsD,
                                int* __restrict__ offD, int* __restrict__ curD, int B, int E2)
{
    int i = blockIdx.x * blockDim.x + threadIdx.x;
    if (i >= B) return;
    int o = lexclD[i] + partialsD[i >> 10];
    offD[i] = o;
    curD[i] = o;
    if (i == 0) offD[B] = E2;
}

__global__ void scatterD_kernel(const int* __restrict__ s_idx, const int* __restrict__ d_idx,
                                const float* __restrict__ dis,
                                int* __restrict__ curD, int* __restrict__ dD,
                                float* __restrict__ disD, int E2)
{
    int e = blockIdx.x * blockDim.x + threadIdx.x;
    if (e >= E2) return;
    int s = s_idx[e];
    int pos = atomicAdd(&curD[s], 1);
    dD[pos] = d_idx[e];
    disD[pos] = dis[e];
}

// wave per s-group: s-row + gate[s] held in registers across the group's edges;
// per edge only the d-row + gate[d] + disD are read (halves row traffic).
__global__ __launch_bounds__(256)
void distortion2_kernel(const float* __restrict__ emb, const float* __restrict__ gate,
                        const int* __restrict__ offD, const int* __restrict__ dD,
                        const float* __restrict__ disD,
                        float* __restrict__ loss, int B, int E2)
{
    const int wid  = (blockIdx.x * (blockDim.x >> 6)) + (threadIdx.x >> 6);
    const int lane = threadIdx.x & 63;
    const int grp  = lane >> 4;          // 16-lane group = expert pair (grp, grp+4)
    if (wid >= B) return;

    const float4* emb4  = (const float4*)emb;
    const float4* gate4 = (const float4*)gate;

    const int s = wid;
    const float4* es = emb4 + (size_t)s * 128;
    float4 a0 = es[lane];
    float4 a1 = es[lane + 64];
    float4 gs0 = gate4[(size_t)s * 2];
    float4 gs1 = gate4[(size_t)s * 2 + 1];

    float lsum = 0.0f;
    const int j1 = offD[s + 1];
    for (int j = offD[s]; j < j1; ++j) {
        int d = dD[j];
        float dv = disD[j];
        const float4* ed = emb4 + (size_t)d * 128;
        float4 b0 = ed[lane];
        float4 b1 = ed[lane + 64];
        float4 gd0 = gate4[(size_t)d * 2];
        float4 gd1 = gate4[(size_t)d * 2 + 1];

        float dx, pa, pb;
        dx = a0.x - b0.x; pa  = dx * dx;
        dx = a0.y - b0.y; pa += dx * dx;
        dx = a0.z - b0.z; pa += dx * dx;
        dx = a0.w - b0.w; pa += dx * dx;
        dx = a1.x - b1.x; pb  = dx * dx;
        dx = a1.y - b1.y; pb += dx * dx;
        dx = a1.z - b1.z; pb += dx * dx;
        dx = a1.w - b1.w; pb += dx * dx;

#pragma unroll
        for (int off = 1; off < 16; off <<= 1) {
            pa += __shfl_xor(pa, off);
            pb += __shfl_xor(pb, off);
        }

        float gp[NEXP] = { gs0.x * gd0.x, gs0.y * gd0.y, gs0.z * gd0.z, gs0.w * gd0.w,
                           gs1.x * gd1.x, gs1.y * gd1.y, gs1.z * gd1.z, gs1.w * gd1.w };
        float m = gp[0];
#pragma unroll
        for (int j2 = 1; j2 < NEXP; ++j2) m = fmaxf(m, gp[j2]);
        float se = 0.0f;
#pragma unroll
        for (int j2 = 0; j2 < NEXP; ++j2) { gp[j2] = expf(gp[j2] - m); se += gp[j2]; }

        float v = pa * gp[grp] + pb * gp[grp + 4];
        v += __shfl_xor(v, 16);
        v += __shfl_xor(v, 32);

        lsum += fabsf((v / se) / dv - 1.0f);
    }
    if (lane == 0) atomicAdd(loss, lsum / (float)E2);
}

// ---------------- launch ----------------
extern "C" void kernel_launch(void* const* d_in, const int* in_sizes, int n_in,
                              void* d_out, int out_size, void* d_ws, size_t ws_size,
                              hipStream_t stream)
{
    const float* x0   = (const float*)d_in[0];
    const float* x1   = (const float*)d_in[1];
    const float* W1   = (const float*)d_in[2];
    const float* b1   = (const float*)d_in[3];
    const float* W2   = (const float*)d_in[4];
    const float* b2   = (const float*)d_in[5];
    const float* Wc   = (const float*)d_in[6];
    const float* bc   = (const float*)d_in[7];
    const float* emb  = (const float*)d_in[8];
    const float* dis  = (const float*)d_in[9];
    const int*   ei0  = (const int*)d_in[10];
    const int*   ei1  = (const int*)d_in[11];
    const int*   bat0 = (const int*)d_in[12];
    const int*   bat1 = (const int*)d_in[13];
    const int*   ei2  = (const int*)d_in[14];

    const int N  = in_sizes[0] / IN_F;
    const int E  = in_sizes[10] / 2;
    const int B  = in_sizes[8] / (NEXP * EMB);
    const int E2 = in_sizes[14] / 2;
    const int n2 = 2 * N;

    float* gate_out = (float*)d_out;               // B*NEXP
    float* loss_out = gate_out + (size_t)B * NEXP; // 1

    // workspace layout (floats)
    float* ws      = (float*)d_ws;
    float* dinv    = ws;                           // 2N
    float* Ys      = dinv + n2;                    // 2N*32
    float* Zs      = Ys + (size_t)n2 * OUT_F;      // 2N*32
    float* sdsum   = Zs + (size_t)n2 * OUT_F;      // 2N
    float* pooled  = sdsum + n2;                   // 2B*32
    float* cnt     = pooled + (size_t)2 * B * OUT_F; // 2B
    float* W12     = cnt + 2 * B;                  // 64*32
    float* c1      = W12 + IN_F * OUT_F;           // 32
    float* disD    = c1 + OUT_F;                   // E2
    int*   iws     = (int*)(disD + E2);
    int*   counts  = iws;                          // 2N
    int*   offsets = counts + n2;                  // 2N+1
    int*   cursor  = offsets + n2 + 1;             // 2N
    int*   csr_src = cursor + n2;                  // 2E
    int*   lexcl   = csr_src + 2 * E;              // 2N
    int*   partials= lexcl + n2;                   // <=1024
    int*   cntD    = partials + 1024;              // B
    int*   lexclD  = cntD + B;                     // B
    int*   partialsD = lexclD + B;                 // <=16
    int*   offD    = partialsD + 16;               // B+1
    int*   curD    = offD + B + 1;                 // B
    int*   dD      = curD + B;                     // E2

    const int TB = 256;
    const int zgrid = 512;
    const int NB2 = (n2 + 1023) / 1024;            // scan blocks over 2N
    const int NBD = (B + 1023) / 1024;             // scan blocks over B

    // W12 = W1@W2, c1 = b1@W2 (once)
    w12_kernel<<<1, 1024, 0, stream>>>(W1, W2, b1, W12, c1);

    // ---- fused CSR build over both graphs ----
    zero_i32_kernel<<<zgrid, TB, 0, stream>>>(counts, n2);
    hist2_kernel<<<(2 * E + TB - 1) / TB, TB, 0, stream>>>(ei0, ei1, counts, E, N);
    scan1_kernel<<<NB2, 1024, 0, stream>>>(counts, lexcl, partials, n2);
    scan2_kernel<<<1, 1024, 0, stream>>>(partials, NB2);
    scan3_kernel<<<(n2 + TB - 1) / TB, TB, 0, stream>>>(lexcl, partials, counts,
                                                        offsets, cursor, dinv, sdsum,
                                                        n2, 2 * E);
    scatter2_kernel<<<(2 * E + TB - 1) / TB, TB, 0, stream>>>(ei0, ei1, dinv, cursor,
                                                              csr_src, sdsum, E, N);

    // ---- distortion edge sort by s (independent of encoder) ----
    zero_i32_kernel<<<zgrid, TB, 0, stream>>>(cntD, B);
    histD_kernel<<<(E2 + TB - 1) / TB, TB, 0, stream>>>(ei2, cntD, E2);
    scan1_kernel<<<NBD, 1024, 0, stream>>>(cntD, lexclD, partialsD, B);
    scan2_kernel<<<1, 1024, 0, stream>>>(partialsD, NBD);
    combineD_kernel<<<(B + TB - 1) / TB, TB, 0, stream>>>(lexclD, partialsD, offD, curD, B, E2);
    scatterD_kernel<<<(E2 + TB - 1) / TB, TB, 0, stream>>>(ei2, ei2 + E2, dis,
                                                           curD, dD, disD, E2);

    // ---- encoder: Ys = (X@W12)*dinv ; two aggregation passes ----
    gemm_ys2_kernel<<<(n2 + 7) / 8, 256, 0, stream>>>(x0, x1, W12, dinv, Ys, N, n2);
    csr_agg32_kernel<0><<<(n2 + 7) / 8, TB, 0, stream>>>(csr_src, offsets, Ys, dinv,
                                                         nullptr, nullptr, nullptr, Zs, n2);
    csr_agg32_kernel<1><<<(n2 + 7) / 8, TB, 0, stream>>>(csr_src, offsets, Zs, dinv,
                                                         sdsum, c1, b2, Ys, n2);

    // ---- mean pool (both graphs) ----
    zero_f32_kernel<<<zgrid, TB, 0, stream>>>(pooled, (long long)2 * B * OUT_F);
    zero_f32_kernel<<<zgrid, TB, 0, stream>>>(cnt, 2 * B);
    pool_sum2_kernel<<<((n2 * 32) + TB - 1) / TB, TB, 0, stream>>>(Ys, bat0, bat1,
                                                                   pooled, cnt, N, n2, B);
    pool_div_kernel<<<((2 * B * OUT_F) + TB - 1) / TB, TB, 0, stream>>>(pooled, cnt, 2 * B);

    // ---- gate ----
    gate_kernel<<<(B + TB - 1) / TB, TB, 0, stream>>>(pooled, pooled + (size_t)B * OUT_F,
                                                      Wc, bc, gate_out, B);

    // ---- distortion loss (grouped by s) ----
    zero_scalar_kernel<<<1, 1, 0, stream>>>(loss_out);
    distortion2_kernel<<<(B + 3) / 4, TB, 0, stream>>>(emb, gate_out, offD, dD, disD,
                                                       loss_out, B, E2);
}

// Round 13
// 500.743 us; speedup vs baseline: 1.2513x; 1.0336x over previous
//
#include <hip/hip_runtime.h>
#include <math.h>

// ---------------- constants from the reference ----------------
constexpr int IN_F  = 64;
constexpr int HID_F = 64;
constexpr int OUT_F = 32;
constexpr int NEXP  = 8;
constexpr int EMB   = 64;   // emb_dim

// Encoder is linear: h2 = A^(A^(X W12)) + t*(b1 W2) + b2, W12 = W1@W2.
// Both subgraphs fused into one pipeline over 2N nodes / 2E edges.
// sdsum (= sum_in dinv[s], for the bias term t) is computed in the MODE-0
// aggregation pass (coalesced write) instead of scatter-time atomics.

// ---------------- utility kernels ----------------
__global__ void zero_f32_kernel(float* __restrict__ p, long long n) {
    long long i = (long long)blockIdx.x * blockDim.x + threadIdx.x;
    long long stride = (long long)gridDim.x * blockDim.x;
    for (; i < n; i += stride) p[i] = 0.0f;
}

__global__ void zero_i32_kernel(int* __restrict__ p, long long n) {
    long long i = (long long)blockIdx.x * blockDim.x + threadIdx.x;
    long long stride = (long long)gridDim.x * blockDim.x;
    for (; i < n; i += stride) p[i] = 0;
}

// ---------------- W12 = W1@W2, c1 = b1@W2 (once) ----------------
__global__ __launch_bounds__(1024)
void w12_kernel(const float* __restrict__ W1, const float* __restrict__ W2,
                const float* __restrict__ b1,
                float* __restrict__ W12, float* __restrict__ c1)
{
    __shared__ float sW2[HID_F * OUT_F];
    const int tid = threadIdx.x;
    for (int i = tid; i < HID_F * OUT_F; i += 1024) sW2[i] = W2[i];
    __syncthreads();
    for (int idx = tid; idx < IN_F * OUT_F; idx += 1024) {
        int i = idx >> 5, j = idx & 31;
        float acc = 0.0f;
#pragma unroll
        for (int k = 0; k < HID_F; ++k) acc += W1[i * HID_F + k] * sW2[k * OUT_F + j];
        W12[idx] = acc;
    }
    if (tid < OUT_F) {
        float acc = 0.0f;
#pragma unroll
        for (int k = 0; k < HID_F; ++k) acc += b1[k] * sW2[k * OUT_F + tid];
        c1[tid] = acc;
    }
}

// ---------------- fused CSR build over both graphs ----------------
__global__ void hist2_kernel(const int* __restrict__ ei0, const int* __restrict__ ei1,
                             int* __restrict__ counts, int E, int N)
{
    int e = blockIdx.x * blockDim.x + threadIdx.x;
    if (e >= 2 * E) return;
    int d = (e < E) ? ei0[E + e] : (ei1[E + (e - E)] + N);
    atomicAdd(&counts[d], 1);
}

// two-level exclusive scan (race-free)
__global__ __launch_bounds__(1024)
void scan1_kernel(const int* __restrict__ counts, int* __restrict__ lexcl,
                  int* __restrict__ partials, int N)
{
    __shared__ int wsum[16];
    const int tid  = threadIdx.x;
    const int lane = tid & 63;
    const int wv   = tid >> 6;
    const int i    = blockIdx.x * 1024 + tid;

    int v = (i < N) ? counts[i] : 0;
    int x = v;
#pragma unroll
    for (int off = 1; off < 64; off <<= 1) {
        int t = __shfl_up(x, off);
        if (lane >= off) x += t;
    }
    if (lane == 63) wsum[wv] = x;
    __syncthreads();
    int woff = 0;
    for (int w = 0; w < wv; ++w) woff += wsum[w];
    if (i < N) lexcl[i] = woff + x - v;
    if (tid == 1023) partials[blockIdx.x] = woff + x;
}

__global__ __launch_bounds__(1024)
void scan2_kernel(int* __restrict__ partials, int NB)
{
    __shared__ int wsum[16];
    const int tid  = threadIdx.x;
    const int lane = tid & 63;
    const int wv   = tid >> 6;
    int v = (tid < NB) ? partials[tid] : 0;
    int x = v;
#pragma unroll
    for (int off = 1; off < 64; off <<= 1) {
        int t = __shfl_up(x, off);
        if (lane >= off) x += t;
    }
    if (lane == 63) wsum[wv] = x;
    __syncthreads();
    int woff = 0;
    for (int w = 0; w < wv; ++w) woff += wsum[w];
    if (tid < NB) partials[tid] = woff + x - v;
}

// combine -> offsets/cursor, dinv = rsqrt(deg+1)
__global__ void scan3_kernel(const int* __restrict__ lexcl, const int* __restrict__ partials,
                             const int* __restrict__ counts,
                             int* __restrict__ offsets, int* __restrict__ cursor,
                             float* __restrict__ dinv, int n2, int e2tot)
{
    int i = blockIdx.x * blockDim.x + threadIdx.x;
    if (i >= n2) return;
    int o = lexcl[i] + partials[i >> 10];
    offsets[i] = o;
    cursor[i]  = o;
    dinv[i] = rsqrtf((float)counts[i] + 1.0f);
    if (i == 0) offsets[n2] = e2tot;
}

// scatter both graphs' edges into CSR (2 random writes/edge: cursor atomic + store)
__global__ void scatter2_kernel(const int* __restrict__ ei0, const int* __restrict__ ei1,
                                int* __restrict__ cursor, int* __restrict__ csr_src,
                                int E, int N)
{
    int e = blockIdx.x * blockDim.x + threadIdx.x;
    if (e >= 2 * E) return;
    int s, d;
    if (e < E) { s = ei0[e];           d = ei0[E + e]; }
    else       { s = ei1[e - E] + N;   d = ei1[E + (e - E)] + N; }
    int pos = atomicAdd(&cursor[d], 1);
    csr_src[pos] = s;
}

// ---------------- GEMM: Ys = (X @ W12) * dinv over 2N rows ----------------
__global__ __launch_bounds__(256)
void gemm_ys2_kernel(const float* __restrict__ x0, const float* __restrict__ x1,
                     const float* __restrict__ W12, const float* __restrict__ dinv,
                     float* __restrict__ Ys, int N, int n2)
{
    __shared__ float Ws[IN_F * OUT_F];
    __shared__ float xs[8 * IN_F];
    const int tid = threadIdx.x;

    for (int i = tid; i < IN_F * OUT_F; i += 256) Ws[i] = W12[i];
    const int row0 = blockIdx.x * 8;
    for (int i = tid; i < 8 * IN_F; i += 256) {
        int r = i >> 6;
        int rr = row0 + r;
        float v = 0.0f;
        if (rr < n2) {
            v = (rr < N) ? x0[(size_t)rr * IN_F + (i & 63)]
                         : x1[(size_t)(rr - N) * IN_F + (i & 63)];
        }
        xs[i] = v;
    }
    __syncthreads();

    const int r = tid >> 5;
    const int c = tid & 31;
    const int row = row0 + r;
    if (row >= n2) return;

    float acc = 0.0f;
#pragma unroll
    for (int k = 0; k < IN_F; ++k) acc += xs[r * IN_F + k] * Ws[k * OUT_F + c];

    Ys[(size_t)row * OUT_F + c] = acc * dinv[row];
}

// ---------------- CSR gather-aggregate, 32-wide, unroll 8 ----------------
// MODE 0: out_i = dinv_i^2 * (in_i + sum_j in_j); also sdsum_i = sum_j dinv_j (coalesced)
// MODE 1: out_i = dinv_i   * (in_i + sum_j in_j) + t_i*c1 + b2,  t_i = dinv_i*(dinv_i+sdsum_i)
template<int MODE>
__global__ __launch_bounds__(256)
void csr_agg32_kernel(const int* __restrict__ csr_src, const int* __restrict__ offsets,
                      const float* __restrict__ in, const float* __restrict__ dinv,
                      float* __restrict__ sdsum, const float* __restrict__ c1,
                      const float* __restrict__ b2,
                      float* __restrict__ out, int n)
{
    constexpr int F = OUT_F;              // 32
    const int lane = threadIdx.x & 63;
    const int wid  = (blockIdx.x * (blockDim.x >> 6)) + (threadIdx.x >> 6);
    const int sub  = lane >> 5;           // 2 nodes per wave
    const int f    = lane & 31;
    const int node = wid * 2 + sub;
    const int lbase = sub * F;

    const bool valid = (node < n);
    const int nc   = valid ? node : 0;
    const int off0 = offsets[nc];
    const int off1 = valid ? offsets[nc + 1] : off0;

    float acc0 = valid ? in[(size_t)nc * F + f] : 0.0f;   // self term
    float acc1 = 0.0f, acc2 = 0.0f, acc3 = 0.0f;
    float dsum = 0.0f;                                    // MODE 0 only
    for (int k = off0; k < off1; k += F) {
        int nk = off1 - k; if (nk > F) nk = F;
        int sj = (f < nk) ? csr_src[k + f] : 0;
        if (MODE == 0) {
            float dv = dinv[sj];
            dsum += (f < nk) ? dv : 0.0f;
        }
        int t = 0;
        for (; t + 8 <= nk; t += 8) {
            int s0 = __shfl(sj, lbase + t);
            int s1 = __shfl(sj, lbase + t + 1);
            int s2 = __shfl(sj, lbase + t + 2);
            int s3 = __shfl(sj, lbase + t + 3);
            int s4 = __shfl(sj, lbase + t + 4);
            int s5 = __shfl(sj, lbase + t + 5);
            int s6 = __shfl(sj, lbase + t + 6);
            int s7 = __shfl(sj, lbase + t + 7);
            float v0 = in[(size_t)s0 * F + f];
            float v1 = in[(size_t)s1 * F + f];
            float v2 = in[(size_t)s2 * F + f];
            float v3 = in[(size_t)s3 * F + f];
            float v4 = in[(size_t)s4 * F + f];
            float v5 = in[(size_t)s5 * F + f];
            float v6 = in[(size_t)s6 * F + f];
            float v7 = in[(size_t)s7 * F + f];
            acc0 += v0 + v4;
            acc1 += v1 + v5;
            acc2 += v2 + v6;
            acc3 += v3 + v7;
        }
        for (; t < nk; ++t) {
            int s = __shfl(sj, lbase + t);
            acc0 += in[(size_t)s * F + f];
        }
    }
    if (MODE == 0) {
        // reduce dsum over the 32-lane subgroup (xor offsets stay within half-wave)
#pragma unroll
        for (int off = 1; off < 32; off <<= 1) dsum += __shfl_xor(dsum, off);
    }
    if (valid) {
        float di = dinv[node];
        float s = (acc0 + acc1) + (acc2 + acc3);
        if (MODE == 0) {
            out[(size_t)node * F + f] = di * di * s;
            if (f == 0) sdsum[node] = dsum;
        } else {
            float t = di * (di + sdsum[node]);
            out[(size_t)node * F + f] = di * s + t * c1[f] + b2[f];
        }
    }
}

// ---------------- mean pool over both graphs (2N nodes -> 2B graphs) ----------------
__global__ void pool_sum2_kernel(const float* __restrict__ h,
                                 const int* __restrict__ bat0, const int* __restrict__ bat1,
                                 float* __restrict__ pooled, float* __restrict__ cnt,
                                 int N, int n2, int B)
{
    int t = blockIdx.x * blockDim.x + threadIdx.x;
    int i = t >> 5;          // node
    int f = t & 31;          // feature
    if (i >= n2) return;
    int g = (i < N) ? bat0[i] : (bat1[i - N] + B);
    atomicAdd(&pooled[(size_t)g * OUT_F + f], h[(size_t)i * OUT_F + f]);
    if (f == 0) atomicAdd(&cnt[g], 1.0f);
}

__global__ void pool_div_kernel(float* __restrict__ pooled, const float* __restrict__ cnt, int B2)
{
    int t = blockIdx.x * blockDim.x + threadIdx.x;
    if (t >= B2 * OUT_F) return;
    int g = t >> 5;
    pooled[t] /= fmaxf(cnt[g], 1.0f);
}

// ---------------- gate: softmax([p0|p1] @ Wc + bc) ----------------
__global__ void gate_kernel(const float* __restrict__ p0, const float* __restrict__ p1,
                            const float* __restrict__ Wc, const float* __restrict__ bc,
                            float* __restrict__ gate, int B)
{
    int g = blockIdx.x * blockDim.x + threadIdx.x;
    if (g >= B) return;
    float xv[2 * OUT_F];
#pragma unroll
    for (int k = 0; k < OUT_F; ++k) xv[k] = p0[(size_t)g * OUT_F + k];
#pragma unroll
    for (int k = 0; k < OUT_F; ++k) xv[OUT_F + k] = p1[(size_t)g * OUT_F + k];

    float lg[NEXP];
    float m = -1e30f;
#pragma unroll
    for (int e = 0; e < NEXP; ++e) {
        float acc = bc[e];
#pragma unroll
        for (int k = 0; k < 2 * OUT_F; ++k) acc += xv[k] * Wc[k * NEXP + e];
        lg[e] = acc;
        m = fmaxf(m, acc);
    }
    float se = 0.0f;
#pragma unroll
    for (int e = 0; e < NEXP; ++e) { lg[e] = expf(lg[e] - m); se += lg[e]; }
    float inv = 1.0f / se;
#pragma unroll
    for (int e = 0; e < NEXP; ++e) gate[(size_t)g * NEXP + e] = lg[e] * inv;
}

__global__ void zero_scalar_kernel(float* p) { *p = 0.0f; }

// ---------------- distortion: group edges by s (counting sort over B buckets) ----------------
__global__ void histD_kernel(const int* __restrict__ s_idx, int* __restrict__ cntD, int E2) {
    int e = blockIdx.x * blockDim.x + threadIdx.x;
    if (e >= E2) return;
    atomicAdd(&cntD[s_idx[e]], 1);
}

__global__ void combineD_kernel(const int* __restrict__ lexclD, const int* __restrict__ partialsD,
                                int* __restrict__ offD, int* __restrict__ curD, int B, int E2)
{
    int i = blockIdx.x * blockDim.x + threadIdx.x;
    if (i >= B) return;
    int o = lexclD[i] + partialsD[i >> 10];
    offD[i] = o;
    curD[i] = o;
    if (i == 0) offD[B] = E2;
}

__global__ void scatterD_kernel(const int* __restrict__ s_idx, const int* __restrict__ d_idx,
                                const float* __restrict__ dis,
                                int* __restrict__ curD, int* __restrict__ dD,
                                float* __restrict__ disD, int E2)
{
    int e = blockIdx.x * blockDim.x + threadIdx.x;
    if (e >= E2) return;
    int s = s_idx[e];
    int pos = atomicAdd(&curD[s], 1);
    dD[pos] = d_idx[e];
    disD[pos] = dis[e];
}

// 2 waves per s-group, interleaved over the group's edges (more TLP for the
// serial d-row latency chain); s-row + gate[s] held in registers.
__global__ __launch_bounds__(256)
void distortion2_kernel(const float* __restrict__ emb, const float* __restrict__ gate,
                        const int* __restrict__ offD, const int* __restrict__ dD,
                        const float* __restrict__ disD,
                        float* __restrict__ loss, int B, int E2)
{
    const int gw   = (blockIdx.x * (blockDim.x >> 6)) + (threadIdx.x >> 6);
    const int lane = threadIdx.x & 63;
    const int grp  = lane >> 4;          // 16-lane group = expert pair (grp, grp+4)
    const int s    = gw >> 1;
    const int half = gw & 1;
    if (s >= B) return;

    const float4* emb4  = (const float4*)emb;
    const float4* gate4 = (const float4*)gate;

    const float4* es = emb4 + (size_t)s * 128;
    float4 a0 = es[lane];
    float4 a1 = es[lane + 64];
    float4 gs0 = gate4[(size_t)s * 2];
    float4 gs1 = gate4[(size_t)s * 2 + 1];

    float lsum = 0.0f;
    const int j1 = offD[s + 1];
    for (int j = offD[s] + half; j < j1; j += 2) {
        int d = dD[j];
        float dv = disD[j];
        const float4* ed = emb4 + (size_t)d * 128;
        float4 b0 = ed[lane];
        float4 b1 = ed[lane + 64];
        float4 gd0 = gate4[(size_t)d * 2];
        float4 gd1 = gate4[(size_t)d * 2 + 1];

        float dx, pa, pb;
        dx = a0.x - b0.x; pa  = dx * dx;
        dx = a0.y - b0.y; pa += dx * dx;
        dx = a0.z - b0.z; pa += dx * dx;
        dx = a0.w - b0.w; pa += dx * dx;
        dx = a1.x - b1.x; pb  = dx * dx;
        dx = a1.y - b1.y; pb += dx * dx;
        dx = a1.z - b1.z; pb += dx * dx;
        dx = a1.w - b1.w; pb += dx * dx;

#pragma unroll
        for (int off = 1; off < 16; off <<= 1) {
            pa += __shfl_xor(pa, off);
            pb += __shfl_xor(pb, off);
        }

        float gp[NEXP] = { gs0.x * gd0.x, gs0.y * gd0.y, gs0.z * gd0.z, gs0.w * gd0.w,
                           gs1.x * gd1.x, gs1.y * gd1.y, gs1.z * gd1.z, gs1.w * gd1.w };
        float m = gp[0];
#pragma unroll
        for (int j2 = 1; j2 < NEXP; ++j2) m = fmaxf(m, gp[j2]);
        float se = 0.0f;
#pragma unroll
        for (int j2 = 0; j2 < NEXP; ++j2) { gp[j2] = expf(gp[j2] - m); se += gp[j2]; }

        float v = pa * gp[grp] + pb * gp[grp + 4];
        v += __shfl_xor(v, 16);
        v += __shfl_xor(v, 32);

        lsum += fabsf((v / se) / dv - 1.0f);
    }
    if (lane == 0) atomicAdd(loss, lsum / (float)E2);
}

// ---------------- launch ----------------
extern "C" void kernel_launch(void* const* d_in, const int* in_sizes, int n_in,
                              void* d_out, int out_size, void* d_ws, size_t ws_size,
                              hipStream_t stream)
{
    const float* x0   = (const float*)d_in[0];
    const float* x1   = (const float*)d_in[1];
    const float* W1   = (const float*)d_in[2];
    const float* b1   = (const float*)d_in[3];
    const float* W2   = (const float*)d_in[4];
    const float* b2   = (const float*)d_in[5];
    const float* Wc   = (const float*)d_in[6];
    const float* bc   = (const float*)d_in[7];
    const float* emb  = (const float*)d_in[8];
    const float* dis  = (const float*)d_in[9];
    const int*   ei0  = (const int*)d_in[10];
    const int*   ei1  = (const int*)d_in[11];
    const int*   bat0 = (const int*)d_in[12];
    const int*   bat1 = (const int*)d_in[13];
    const int*   ei2  = (const int*)d_in[14];

    const int N  = in_sizes[0] / IN_F;
    const int E  = in_sizes[10] / 2;
    const int B  = in_sizes[8] / (NEXP * EMB);
    const int E2 = in_sizes[14] / 2;
    const int n2 = 2 * N;

    float* gate_out = (float*)d_out;               // B*NEXP
    float* loss_out = gate_out + (size_t)B * NEXP; // 1

    // workspace layout (floats)
    float* ws      = (float*)d_ws;
    float* dinv    = ws;                           // 2N
    float* Ys      = dinv + n2;                    // 2N*32
    float* Zs      = Ys + (size_t)n2 * OUT_F;      // 2N*32
    float* sdsum   = Zs + (size_t)n2 * OUT_F;      // 2N
    float* pooled  = sdsum + n2;                   // 2B*32
    float* cnt     = pooled + (size_t)2 * B * OUT_F; // 2B
    float* W12     = cnt + 2 * B;                  // 64*32
    float* c1      = W12 + IN_F * OUT_F;           // 32
    float* disD    = c1 + OUT_F;                   // E2
    int*   iws     = (int*)(disD + E2);
    int*   counts  = iws;                          // 2N
    int*   offsets = counts + n2;                  // 2N+1
    int*   cursor  = offsets + n2 + 1;             // 2N
    int*   csr_src = cursor + n2;                  // 2E
    int*   lexcl   = csr_src + 2 * E;              // 2N
    int*   partials= lexcl + n2;                   // <=1024
    int*   cntD    = partials + 1024;              // B
    int*   lexclD  = cntD + B;                     // B
    int*   partialsD = lexclD + B;                 // <=16
    int*   offD    = partialsD + 16;               // B+1
    int*   curD    = offD + B + 1;                 // B
    int*   dD      = curD + B;                     // E2

    const int TB = 256;
    const int zgrid = 512;
    const int NB2 = (n2 + 1023) / 1024;            // scan blocks over 2N
    const int NBD = (B + 1023) / 1024;             // scan blocks over B

    // W12 = W1@W2, c1 = b1@W2 (once)
    w12_kernel<<<1, 1024, 0, stream>>>(W1, W2, b1, W12, c1);

    // ---- fused CSR build over both graphs ----
    zero_i32_kernel<<<zgrid, TB, 0, stream>>>(counts, n2);
    hist2_kernel<<<(2 * E + TB - 1) / TB, TB, 0, stream>>>(ei0, ei1, counts, E, N);
    scan1_kernel<<<NB2, 1024, 0, stream>>>(counts, lexcl, partials, n2);
    scan2_kernel<<<1, 1024, 0, stream>>>(partials, NB2);
    scan3_kernel<<<(n2 + TB - 1) / TB, TB, 0, stream>>>(lexcl, partials, counts,
                                                        offsets, cursor, dinv, n2, 2 * E);
    scatter2_kernel<<<(2 * E + TB - 1) / TB, TB, 0, stream>>>(ei0, ei1, cursor, csr_src, E, N);

    // ---- distortion edge sort by s (independent of encoder) ----
    zero_i32_kernel<<<zgrid, TB, 0, stream>>>(cntD, B);
    histD_kernel<<<(E2 + TB - 1) / TB, TB, 0, stream>>>(ei2, cntD, E2);
    scan1_kernel<<<NBD, 1024, 0, stream>>>(cntD, lexclD, partialsD, B);
    scan2_kernel<<<1, 1024, 0, stream>>>(partialsD, NBD);
    combineD_kernel<<<(B + TB - 1) / TB, TB, 0, stream>>>(lexclD, partialsD, offD, curD, B, E2);
    scatterD_kernel<<<(E2 + TB - 1) / TB, TB, 0, stream>>>(ei2, ei2 + E2, dis,
                                                           curD, dD, disD, E2);

    // ---- encoder: Ys = (X@W12)*dinv ; two aggregation passes ----
    gemm_ys2_kernel<<<(n2 + 7) / 8, 256, 0, stream>>>(x0, x1, W12, dinv, Ys, N, n2);
    csr_agg32_kernel<0><<<(n2 + 7) / 8, TB, 0, stream>>>(csr_src, offsets, Ys, dinv,
                                                         sdsum, nullptr, nullptr, Zs, n2);
    csr_agg32_kernel<1><<<(n2 + 7) / 8, TB, 0, stream>>>(csr_src, offsets, Zs, dinv,
                                                         sdsum, c1, b2, Ys, n2);

    // ---- mean pool (both graphs) ----
    zero_f32_kernel<<<zgrid, TB, 0, stream>>>(pooled, (long long)2 * B * OUT_F);
    zero_f32_kernel<<<zgrid, TB, 0, stream>>>(cnt, 2 * B);
    pool_sum2_kernel<<<((n2 * 32) + TB - 1) / TB, TB, 0, stream>>>(Ys, bat0, bat1,
                                                                   pooled, cnt, N, n2, B);
    pool_div_kernel<<<((2 * B * OUT_F) + TB - 1) / TB, TB, 0, stream>>>(pooled, cnt, 2 * B);

    // ---- gate ----
    gate_kernel<<<(B + TB - 1) / TB, TB, 0, stream>>>(pooled, pooled + (size_t)B * OUT_F,
                                                      Wc, bc, gate_out, B);

    // ---- distortion loss (grouped by s, 2 waves/group) ----
    zero_scalar_kernel<<<1, 1, 0, stream>>>(loss_out);
    distortion2_kernel<<<(2 * B + 3) / 4, TB, 0, stream>>>(emb, gate_out, offD, dD, disD,
                                                           loss_out, B, E2);
}

// Round 14
// 478.585 us; speedup vs baseline: 1.3092x; 1.0463x over previous
//
#include <hip/hip_runtime.h>
#include <math.h>

// ---------------- constants from the reference ----------------
constexpr int IN_F  = 64;
constexpr int HID_F = 64;
constexpr int OUT_F = 32;
constexpr int NEXP  = 8;
constexpr int EMB   = 64;   // emb_dim

// Encoder is linear: h2 = A^(A^(X W12)) + t*(b1 W2) + b2, W12 = W1@W2.
// Both subgraphs fused into one pipeline over 2N nodes / 2E edges.
// sdsum computed in MODE-0 agg pass (coalesced), not scatter-time atomics.
// Distortion: edges counting-sorted by s; ONE wave per s-group (4096 waves —
// measured TCC-queue knee; 8192 waves regressed 91->127 us, r13).

// ---------------- utility kernels ----------------
__global__ void zero_f32_kernel(float* __restrict__ p, long long n) {
    long long i = (long long)blockIdx.x * blockDim.x + threadIdx.x;
    long long stride = (long long)gridDim.x * blockDim.x;
    for (; i < n; i += stride) p[i] = 0.0f;
}

__global__ void zero_i32_kernel(int* __restrict__ p, long long n) {
    long long i = (long long)blockIdx.x * blockDim.x + threadIdx.x;
    long long stride = (long long)gridDim.x * blockDim.x;
    for (; i < n; i += stride) p[i] = 0;
}

// ---------------- W12 = W1@W2, c1 = b1@W2 (once) ----------------
__global__ __launch_bounds__(1024)
void w12_kernel(const float* __restrict__ W1, const float* __restrict__ W2,
                const float* __restrict__ b1,
                float* __restrict__ W12, float* __restrict__ c1)
{
    __shared__ float sW2[HID_F * OUT_F];
    const int tid = threadIdx.x;
    for (int i = tid; i < HID_F * OUT_F; i += 1024) sW2[i] = W2[i];
    __syncthreads();
    for (int idx = tid; idx < IN_F * OUT_F; idx += 1024) {
        int i = idx >> 5, j = idx & 31;
        float acc = 0.0f;
#pragma unroll
        for (int k = 0; k < HID_F; ++k) acc += W1[i * HID_F + k] * sW2[k * OUT_F + j];
        W12[idx] = acc;
    }
    if (tid < OUT_F) {
        float acc = 0.0f;
#pragma unroll
        for (int k = 0; k < HID_F; ++k) acc += b1[k] * sW2[k * OUT_F + tid];
        c1[tid] = acc;
    }
}

// ---------------- fused CSR build over both graphs ----------------
__global__ void hist2_kernel(const int* __restrict__ ei0, const int* __restrict__ ei1,
                             int* __restrict__ counts, int E, int N)
{
    int e = blockIdx.x * blockDim.x + threadIdx.x;
    if (e >= 2 * E) return;
    int d = (e < E) ? ei0[E + e] : (ei1[E + (e - E)] + N);
    atomicAdd(&counts[d], 1);
}

// two-level exclusive scan (race-free)
__global__ __launch_bounds__(1024)
void scan1_kernel(const int* __restrict__ counts, int* __restrict__ lexcl,
                  int* __restrict__ partials, int N)
{
    __shared__ int wsum[16];
    const int tid  = threadIdx.x;
    const int lane = tid & 63;
    const int wv   = tid >> 6;
    const int i    = blockIdx.x * 1024 + tid;

    int v = (i < N) ? counts[i] : 0;
    int x = v;
#pragma unroll
    for (int off = 1; off < 64; off <<= 1) {
        int t = __shfl_up(x, off);
        if (lane >= off) x += t;
    }
    if (lane == 63) wsum[wv] = x;
    __syncthreads();
    int woff = 0;
    for (int w = 0; w < wv; ++w) woff += wsum[w];
    if (i < N) lexcl[i] = woff + x - v;
    if (tid == 1023) partials[blockIdx.x] = woff + x;
}

__global__ __launch_bounds__(1024)
void scan2_kernel(int* __restrict__ partials, int NB)
{
    __shared__ int wsum[16];
    const int tid  = threadIdx.x;
    const int lane = tid & 63;
    const int wv   = tid >> 6;
    int v = (tid < NB) ? partials[tid] : 0;
    int x = v;
#pragma unroll
    for (int off = 1; off < 64; off <<= 1) {
        int t = __shfl_up(x, off);
        if (lane >= off) x += t;
    }
    if (lane == 63) wsum[wv] = x;
    __syncthreads();
    int woff = 0;
    for (int w = 0; w < wv; ++w) woff += wsum[w];
    if (tid < NB) partials[tid] = woff + x - v;
}

// combine -> offsets/cursor, dinv = rsqrt(deg+1)
__global__ void scan3_kernel(const int* __restrict__ lexcl, const int* __restrict__ partials,
                             const int* __restrict__ counts,
                             int* __restrict__ offsets, int* __restrict__ cursor,
                             float* __restrict__ dinv, int n2, int e2tot)
{
    int i = blockIdx.x * blockDim.x + threadIdx.x;
    if (i >= n2) return;
    int o = lexcl[i] + partials[i >> 10];
    offsets[i] = o;
    cursor[i]  = o;
    dinv[i] = rsqrtf((float)counts[i] + 1.0f);
    if (i == 0) offsets[n2] = e2tot;
}

// scatter both graphs' edges into CSR
__global__ void scatter2_kernel(const int* __restrict__ ei0, const int* __restrict__ ei1,
                                int* __restrict__ cursor, int* __restrict__ csr_src,
                                int E, int N)
{
    int e = blockIdx.x * blockDim.x + threadIdx.x;
    if (e >= 2 * E) return;
    int s, d;
    if (e < E) { s = ei0[e];           d = ei0[E + e]; }
    else       { s = ei1[e - E] + N;   d = ei1[E + (e - E)] + N; }
    int pos = atomicAdd(&cursor[d], 1);
    csr_src[pos] = s;
}

// ---------------- GEMM: Ys = (X @ W12) * dinv over 2N rows ----------------
__global__ __launch_bounds__(256)
void gemm_ys2_kernel(const float* __restrict__ x0, const float* __restrict__ x1,
                     const float* __restrict__ W12, const float* __restrict__ dinv,
                     float* __restrict__ Ys, int N, int n2)
{
    __shared__ float Ws[IN_F * OUT_F];
    __shared__ float xs[8 * IN_F];
    const int tid = threadIdx.x;

    for (int i = tid; i < IN_F * OUT_F; i += 256) Ws[i] = W12[i];
    const int row0 = blockIdx.x * 8;
    for (int i = tid; i < 8 * IN_F; i += 256) {
        int r = i >> 6;
        int rr = row0 + r;
        float v = 0.0f;
        if (rr < n2) {
            v = (rr < N) ? x0[(size_t)rr * IN_F + (i & 63)]
                         : x1[(size_t)(rr - N) * IN_F + (i & 63)];
        }
        xs[i] = v;
    }
    __syncthreads();

    const int r = tid >> 5;
    const int c = tid & 31;
    const int row = row0 + r;
    if (row >= n2) return;

    float acc = 0.0f;
#pragma unroll
    for (int k = 0; k < IN_F; ++k) acc += xs[r * IN_F + k] * Ws[k * OUT_F + c];

    Ys[(size_t)row * OUT_F + c] = acc * dinv[row];
}

// ---------------- CSR gather-aggregate, 32-wide, unroll 8 ----------------
// MODE 0: out_i = dinv_i^2 * (in_i + sum_j in_j); also sdsum_i = sum_j dinv_j (coalesced)
// MODE 1: out_i = dinv_i   * (in_i + sum_j in_j) + t_i*c1 + b2,  t_i = dinv_i*(dinv_i+sdsum_i)
template<int MODE>
__global__ __launch_bounds__(256)
void csr_agg32_kernel(const int* __restrict__ csr_src, const int* __restrict__ offsets,
                      const float* __restrict__ in, const float* __restrict__ dinv,
                      float* __restrict__ sdsum, const float* __restrict__ c1,
                      const float* __restrict__ b2,
                      float* __restrict__ out, int n)
{
    constexpr int F = OUT_F;              // 32
    const int lane = threadIdx.x & 63;
    const int wid  = (blockIdx.x * (blockDim.x >> 6)) + (threadIdx.x >> 6);
    const int sub  = lane >> 5;           // 2 nodes per wave
    const int f    = lane & 31;
    const int node = wid * 2 + sub;
    const int lbase = sub * F;

    const bool valid = (node < n);
    const int nc   = valid ? node : 0;
    const int off0 = offsets[nc];
    const int off1 = valid ? offsets[nc + 1] : off0;

    float acc0 = valid ? in[(size_t)nc * F + f] : 0.0f;   // self term
    float acc1 = 0.0f, acc2 = 0.0f, acc3 = 0.0f;
    float dsum = 0.0f;                                    // MODE 0 only
    for (int k = off0; k < off1; k += F) {
        int nk = off1 - k; if (nk > F) nk = F;
        int sj = (f < nk) ? csr_src[k + f] : 0;
        if (MODE == 0) {
            float dv = dinv[sj];
            dsum += (f < nk) ? dv : 0.0f;
        }
        int t = 0;
        for (; t + 8 <= nk; t += 8) {
            int s0 = __shfl(sj, lbase + t);
            int s1 = __shfl(sj, lbase + t + 1);
            int s2 = __shfl(sj, lbase + t + 2);
            int s3 = __shfl(sj, lbase + t + 3);
            int s4 = __shfl(sj, lbase + t + 4);
            int s5 = __shfl(sj, lbase + t + 5);
            int s6 = __shfl(sj, lbase + t + 6);
            int s7 = __shfl(sj, lbase + t + 7);
            float v0 = in[(size_t)s0 * F + f];
            float v1 = in[(size_t)s1 * F + f];
            float v2 = in[(size_t)s2 * F + f];
            float v3 = in[(size_t)s3 * F + f];
            float v4 = in[(size_t)s4 * F + f];
            float v5 = in[(size_t)s5 * F + f];
            float v6 = in[(size_t)s6 * F + f];
            float v7 = in[(size_t)s7 * F + f];
            acc0 += v0 + v4;
            acc1 += v1 + v5;
            acc2 += v2 + v6;
            acc3 += v3 + v7;
        }
        for (; t < nk; ++t) {
            int s = __shfl(sj, lbase + t);
            acc0 += in[(size_t)s * F + f];
        }
    }
    if (MODE == 0) {
#pragma unroll
        for (int off = 1; off < 32; off <<= 1) dsum += __shfl_xor(dsum, off);
    }
    if (valid) {
        float di = dinv[node];
        float s = (acc0 + acc1) + (acc2 + acc3);
        if (MODE == 0) {
            out[(size_t)node * F + f] = di * di * s;
            if (f == 0) sdsum[node] = dsum;
        } else {
            float t = di * (di + sdsum[node]);
            out[(size_t)node * F + f] = di * s + t * c1[f] + b2[f];
        }
    }
}

// ---------------- mean pool over both graphs (2N nodes -> 2B graphs) ----------------
__global__ void pool_sum2_kernel(const float* __restrict__ h,
                                 const int* __restrict__ bat0, const int* __restrict__ bat1,
                                 float* __restrict__ pooled, float* __restrict__ cnt,
                                 int N, int n2, int B)
{
    int t = blockIdx.x * blockDim.x + threadIdx.x;
    int i = t >> 5;          // node
    int f = t & 31;          // feature
    if (i >= n2) return;
    int g = (i < N) ? bat0[i] : (bat1[i - N] + B);
    atomicAdd(&pooled[(size_t)g * OUT_F + f], h[(size_t)i * OUT_F + f]);
    if (f == 0) atomicAdd(&cnt[g], 1.0f);
}

__global__ void pool_div_kernel(float* __restrict__ pooled, const float* __restrict__ cnt, int B2)
{
    int t = blockIdx.x * blockDim.x + threadIdx.x;
    if (t >= B2 * OUT_F) return;
    int g = t >> 5;
    pooled[t] /= fmaxf(cnt[g], 1.0f);
}

// ---------------- gate: softmax([p0|p1] @ Wc + bc) ----------------
__global__ void gate_kernel(const float* __restrict__ p0, const float* __restrict__ p1,
                            const float* __restrict__ Wc, const float* __restrict__ bc,
                            float* __restrict__ gate, int B)
{
    int g = blockIdx.x * blockDim.x + threadIdx.x;
    if (g >= B) return;
    float xv[2 * OUT_F];
#pragma unroll
    for (int k = 0; k < OUT_F; ++k) xv[k] = p0[(size_t)g * OUT_F + k];
#pragma unroll
    for (int k = 0; k < OUT_F; ++k) xv[OUT_F + k] = p1[(size_t)g * OUT_F + k];

    float lg[NEXP];
    float m = -1e30f;
#pragma unroll
    for (int e = 0; e < NEXP; ++e) {
        float acc = bc[e];
#pragma unroll
        for (int k = 0; k < 2 * OUT_F; ++k) acc += xv[k] * Wc[k * NEXP + e];
        lg[e] = acc;
        m = fmaxf(m, acc);
    }
    float se = 0.0f;
#pragma unroll
    for (int e = 0; e < NEXP; ++e) { lg[e] = expf(lg[e] - m); se += lg[e]; }
    float inv = 1.0f / se;
#pragma unroll
    for (int e = 0; e < NEXP; ++e) gate[(size_t)g * NEXP + e] = lg[e] * inv;
}

__global__ void zero_scalar_kernel(float* p) { *p = 0.0f; }

// ---------------- distortion: group edges by s (counting sort over B buckets) ----------------
__global__ void histD_kernel(const int* __restrict__ s_idx, int* __restrict__ cntD, int E2) {
    int e = blockIdx.x * blockDim.x + threadIdx.x;
    if (e >= E2) return;
    atomicAdd(&cntD[s_idx[e]], 1);
}

__global__ void combineD_kernel(const int* __restrict__ lexclD, const int* __restrict__ partialsD,
                                int* __restrict__ offD, int* __restrict__ curD, int B, int E2)
{
    int i = blockIdx.x * blockDim.x + threadIdx.x;
    if (i >= B) return;
    int o = lexclD[i] + partialsD[i >> 10];
    offD[i] = o;
    curD[i] = o;
    if (i == 0) offD[B] = E2;
}

__global__ void scatterD_kernel(const int* __restrict__ s_idx, const int* __restrict__ d_idx,
                                const float* __restrict__ dis,
                                int* __restrict__ curD, int* __restrict__ dD,
                                float* __restrict__ disD, int E2)
{
    int e = blockIdx.x * blockDim.x + threadIdx.x;
    if (e >= E2) return;
    int s = s_idx[e];
    int pos = atomicAdd(&curD[s], 1);
    dD[pos] = d_idx[e];
    disD[pos] = dis[e];
}

// ONE wave per s-group (4096 waves = measured TCC knee); s-row + gate[s]
// in registers across the group's ~32 edges; per edge only d-row + gate[d].
__global__ __launch_bounds__(256)
void distortion2_kernel(const float* __restrict__ emb, const float* __restrict__ gate,
                        const int* __restrict__ offD, const int* __restrict__ dD,
                        const float* __restrict__ disD,
                        float* __restrict__ loss, int B, int E2)
{
    const int s    = (blockIdx.x * (blockDim.x >> 6)) + (threadIdx.x >> 6);
    const int lane = threadIdx.x & 63;
    const int grp  = lane >> 4;          // 16-lane group = expert pair (grp, grp+4)
    if (s >= B) return;

    const float4* emb4  = (const float4*)emb;
    const float4* gate4 = (const float4*)gate;

    const float4* es = emb4 + (size_t)s * 128;
    float4 a0 = es[lane];
    float4 a1 = es[lane + 64];
    float4 gs0 = gate4[(size_t)s * 2];
    float4 gs1 = gate4[(size_t)s * 2 + 1];

    float lsum = 0.0f;
    const int j1 = offD[s + 1];
    for (int j = offD[s]; j < j1; ++j) {
        int d = dD[j];
        float dv = disD[j];
        const float4* ed = emb4 + (size_t)d * 128;
        float4 b0 = ed[lane];
        float4 b1 = ed[lane + 64];
        float4 gd0 = gate4[(size_t)d * 2];
        float4 gd1 = gate4[(size_t)d * 2 + 1];

        float dx, pa, pb;
        dx = a0.x - b0.x; pa  = dx * dx;
        dx = a0.y - b0.y; pa += dx * dx;
        dx = a0.z - b0.z; pa += dx * dx;
        dx = a0.w - b0.w; pa += dx * dx;
        dx = a1.x - b1.x; pb  = dx * dx;
        dx = a1.y - b1.y; pb += dx * dx;
        dx = a1.z - b1.z; pb += dx * dx;
        dx = a1.w - b1.w; pb += dx * dx;

#pragma unroll
        for (int off = 1; off < 16; off <<= 1) {
            pa += __shfl_xor(pa, off);
            pb += __shfl_xor(pb, off);
        }

        float gp[NEXP] = { gs0.x * gd0.x, gs0.y * gd0.y, gs0.z * gd0.z, gs0.w * gd0.w,
                           gs1.x * gd1.x, gs1.y * gd1.y, gs1.z * gd1.z, gs1.w * gd1.w };
        float m = gp[0];
#pragma unroll
        for (int j2 = 1; j2 < NEXP; ++j2) m = fmaxf(m, gp[j2]);
        float se = 0.0f;
#pragma unroll
        for (int j2 = 0; j2 < NEXP; ++j2) { gp[j2] = expf(gp[j2] - m); se += gp[j2]; }

        float v = pa * gp[grp] + pb * gp[grp + 4];
        v += __shfl_xor(v, 16);
        v += __shfl_xor(v, 32);

        lsum += fabsf((v / se) / dv - 1.0f);
    }
    if (lane == 0) atomicAdd(loss, lsum / (float)E2);
}

// ---------------- launch ----------------
extern "C" void kernel_launch(void* const* d_in, const int* in_sizes, int n_in,
                              void* d_out, int out_size, void* d_ws, size_t ws_size,
                              hipStream_t stream)
{
    const float* x0   = (const float*)d_in[0];
    const float* x1   = (const float*)d_in[1];
    const float* W1   = (const float*)d_in[2];
    const float* b1   = (const float*)d_in[3];
    const float* W2   = (const float*)d_in[4];
    const float* b2   = (const float*)d_in[5];
    const float* Wc   = (const float*)d_in[6];
    const float* bc   = (const float*)d_in[7];
    const float* emb  = (const float*)d_in[8];
    const float* dis  = (const float*)d_in[9];
    const int*   ei0  = (const int*)d_in[10];
    const int*   ei1  = (const int*)d_in[11];
    const int*   bat0 = (const int*)d_in[12];
    const int*   bat1 = (const int*)d_in[13];
    const int*   ei2  = (const int*)d_in[14];

    const int N  = in_sizes[0] / IN_F;
    const int E  = in_sizes[10] / 2;
    const int B  = in_sizes[8] / (NEXP * EMB);
    const int E2 = in_sizes[14] / 2;
    const int n2 = 2 * N;

    float* gate_out = (float*)d_out;               // B*NEXP
    float* loss_out = gate_out + (size_t)B * NEXP; // 1

    // workspace layout (floats)
    float* ws      = (float*)d_ws;
    float* dinv    = ws;                           // 2N
    float* Ys      = dinv + n2;                    // 2N*32
    float* Zs      = Ys + (size_t)n2 * OUT_F;      // 2N*32
    float* sdsum   = Zs + (size_t)n2 * OUT_F;      // 2N
    float* pooled  = sdsum + n2;                   // 2B*32
    float* cnt     = pooled + (size_t)2 * B * OUT_F; // 2B
    float* W12     = cnt + 2 * B;                  // 64*32
    float* c1      = W12 + IN_F * OUT_F;           // 32
    float* disD    = c1 + OUT_F;                   // E2
    int*   iws     = (int*)(disD + E2);
    int*   counts  = iws;                          // 2N
    int*   offsets = counts + n2;                  // 2N+1
    int*   cursor  = offsets + n2 + 1;             // 2N
    int*   csr_src = cursor + n2;                  // 2E
    int*   lexcl   = csr_src + 2 * E;              // 2N
    int*   partials= lexcl + n2;                   // <=1024
    int*   cntD    = partials + 1024;              // B
    int*   lexclD  = cntD + B;                     // B
    int*   partialsD = lexclD + B;                 // <=16
    int*   offD    = partialsD + 16;               // B+1
    int*   curD    = offD + B + 1;                 // B
    int*   dD      = curD + B;                     // E2

    const int TB = 256;
    const int zgrid = 512;
    const int NB2 = (n2 + 1023) / 1024;            // scan blocks over 2N
    const int NBD = (B + 1023) / 1024;             // scan blocks over B

    // W12 = W1@W2, c1 = b1@W2 (once)
    w12_kernel<<<1, 1024, 0, stream>>>(W1, W2, b1, W12, c1);

    // ---- fused CSR build over both graphs ----
    zero_i32_kernel<<<zgrid, TB, 0, stream>>>(counts, n2);
    hist2_kernel<<<(2 * E + TB - 1) / TB, TB, 0, stream>>>(ei0, ei1, counts, E, N);
    scan1_kernel<<<NB2, 1024, 0, stream>>>(counts, lexcl, partials, n2);
    scan2_kernel<<<1, 1024, 0, stream>>>(partials, NB2);
    scan3_kernel<<<(n2 + TB - 1) / TB, TB, 0, stream>>>(lexcl, partials, counts,
                                                        offsets, cursor, dinv, n2, 2 * E);
    scatter2_kernel<<<(2 * E + TB - 1) / TB, TB, 0, stream>>>(ei0, ei1, cursor, csr_src, E, N);

    // ---- distortion edge sort by s (independent of encoder) ----
    zero_i32_kernel<<<zgrid, TB, 0, stream>>>(cntD, B);
    histD_kernel<<<(E2 + TB - 1) / TB, TB, 0, stream>>>(ei2, cntD, E2);
    scan1_kernel<<<NBD, 1024, 0, stream>>>(cntD, lexclD, partialsD, B);
    scan2_kernel<<<1, 1024, 0, stream>>>(partialsD, NBD);
    combineD_kernel<<<(B + TB - 1) / TB, TB, 0, stream>>>(lexclD, partialsD, offD, curD, B, E2);
    scatterD_kernel<<<(E2 + TB - 1) / TB, TB, 0, stream>>>(ei2, ei2 + E2, dis,
                                                           curD, dD, disD, E2);

    // ---- encoder: Ys = (X@W12)*dinv ; two aggregation passes ----
    gemm_ys2_kernel<<<(n2 + 7) / 8, 256, 0, stream>>>(x0, x1, W12, dinv, Ys, N, n2);
    csr_agg32_kernel<0><<<(n2 + 7) / 8, TB, 0, stream>>>(csr_src, offsets, Ys, dinv,
                                                         sdsum, nullptr, nullptr, Zs, n2);
    csr_agg32_kernel<1><<<(n2 + 7) / 8, TB, 0, stream>>>(csr_src, offsets, Zs, dinv,
                                                         sdsum, c1, b2, Ys, n2);

    // ---- mean pool (both graphs) ----
    zero_f32_kernel<<<zgrid, TB, 0, stream>>>(pooled, (long long)2 * B * OUT_F);
    zero_f32_kernel<<<zgrid, TB, 0, stream>>>(cnt, 2 * B);
    pool_sum2_kernel<<<((n2 * 32) + TB - 1) / TB, TB, 0, stream>>>(Ys, bat0, bat1,
                                                                   pooled, cnt, N, n2, B);
    pool_div_kernel<<<((2 * B * OUT_F) + TB - 1) / TB, TB, 0, stream>>>(pooled, cnt, 2 * B);

    // ---- gate ----
    gate_kernel<<<(B + TB - 1) / TB, TB, 0, stream>>>(pooled, pooled + (size_t)B * OUT_F,
                                                      Wc, bc, gate_out, B);

    // ---- distortion loss (grouped by s, 1 wave/group) ----
    zero_scalar_kernel<<<1, 1, 0, stream>>>(loss_out);
    distortion2_kernel<<<(B + 3) / 4, TB, 0, stream>>>(emb, gate_out, offD, dD, disD,
                                                       loss_out, B, E2);
}

// Round 15
// 433.434 us; speedup vs baseline: 1.4456x; 1.1042x over previous
//
#include <hip/hip_runtime.h>
#include <math.h>

// ---------------- constants from the reference ----------------
constexpr int IN_F  = 64;
constexpr int HID_F = 64;
constexpr int OUT_F = 32;
constexpr int NEXP  = 8;
constexpr int EMB   = 64;   // emb_dim

// Encoder is linear: h2 = A^(A^(X W12)) + t*(b1 W2) + b2, W12 = W1@W2.
// Both subgraphs fused into one pipeline over 2N nodes / 2E edges.
// Scatter is dst-range-sharded x8 (blockIdx&7 ~ XCD): each shard's CSR slice
// (1.6MB) stays L2-resident so lines fill completely before eviction,
// attacking the measured 16x write amplification (107MB for 6.4MB payload).

// ---------------- utility kernels ----------------
__global__ void zero_f32_kernel(float* __restrict__ p, long long n) {
    long long i = (long long)blockIdx.x * blockDim.x + threadIdx.x;
    long long stride = (long long)gridDim.x * blockDim.x;
    for (; i < n; i += stride) p[i] = 0.0f;
}

__global__ void zero_i32_kernel(int* __restrict__ p, long long n) {
    long long i = (long long)blockIdx.x * blockDim.x + threadIdx.x;
    long long stride = (long long)gridDim.x * blockDim.x;
    for (; i < n; i += stride) p[i] = 0;
}

// ---------------- W12 = W1@W2, c1 = b1@W2 (once) ----------------
__global__ __launch_bounds__(1024)
void w12_kernel(const float* __restrict__ W1, const float* __restrict__ W2,
                const float* __restrict__ b1,
                float* __restrict__ W12, float* __restrict__ c1)
{
    __shared__ float sW2[HID_F * OUT_F];
    const int tid = threadIdx.x;
    for (int i = tid; i < HID_F * OUT_F; i += 1024) sW2[i] = W2[i];
    __syncthreads();
    for (int idx = tid; idx < IN_F * OUT_F; idx += 1024) {
        int i = idx >> 5, j = idx & 31;
        float acc = 0.0f;
#pragma unroll
        for (int k = 0; k < HID_F; ++k) acc += W1[i * HID_F + k] * sW2[k * OUT_F + j];
        W12[idx] = acc;
    }
    if (tid < OUT_F) {
        float acc = 0.0f;
#pragma unroll
        for (int k = 0; k < HID_F; ++k) acc += b1[k] * sW2[k * OUT_F + tid];
        c1[tid] = acc;
    }
}

// ---------------- fused CSR build over both graphs ----------------
__global__ void hist2_kernel(const int* __restrict__ ei0, const int* __restrict__ ei1,
                             int* __restrict__ counts, int E, int N)
{
    int e = blockIdx.x * blockDim.x + threadIdx.x;
    if (e >= 2 * E) return;
    int d = (e < E) ? ei0[E + e] : (ei1[E + (e - E)] + N);
    atomicAdd(&counts[d], 1);
}

// two-level exclusive scan (race-free)
__global__ __launch_bounds__(1024)
void scan1_kernel(const int* __restrict__ counts, int* __restrict__ lexcl,
                  int* __restrict__ partials, int N)
{
    __shared__ int wsum[16];
    const int tid  = threadIdx.x;
    const int lane = tid & 63;
    const int wv   = tid >> 6;
    const int i    = blockIdx.x * 1024 + tid;

    int v = (i < N) ? counts[i] : 0;
    int x = v;
#pragma unroll
    for (int off = 1; off < 64; off <<= 1) {
        int t = __shfl_up(x, off);
        if (lane >= off) x += t;
    }
    if (lane == 63) wsum[wv] = x;
    __syncthreads();
    int woff = 0;
    for (int w = 0; w < wv; ++w) woff += wsum[w];
    if (i < N) lexcl[i] = woff + x - v;
    if (tid == 1023) partials[blockIdx.x] = woff + x;
}

__global__ __launch_bounds__(1024)
void scan2_kernel(int* __restrict__ partials, int NB)
{
    __shared__ int wsum[16];
    const int tid  = threadIdx.x;
    const int lane = tid & 63;
    const int wv   = tid >> 6;
    int v = (tid < NB) ? partials[tid] : 0;
    int x = v;
#pragma unroll
    for (int off = 1; off < 64; off <<= 1) {
        int t = __shfl_up(x, off);
        if (lane >= off) x += t;
    }
    if (lane == 63) wsum[wv] = x;
    __syncthreads();
    int woff = 0;
    for (int w = 0; w < wv; ++w) woff += wsum[w];
    if (tid < NB) partials[tid] = woff + x - v;
}

// combine -> offsets/cursor, dinv = rsqrt(deg+1)
__global__ void scan3_kernel(const int* __restrict__ lexcl, const int* __restrict__ partials,
                             const int* __restrict__ counts,
                             int* __restrict__ offsets, int* __restrict__ cursor,
                             float* __restrict__ dinv, int n2, int e2tot)
{
    int i = blockIdx.x * blockDim.x + threadIdx.x;
    if (i >= n2) return;
    int o = lexcl[i] + partials[i >> 10];
    offsets[i] = o;
    cursor[i]  = o;
    dinv[i] = rsqrtf((float)counts[i] + 1.0f);
    if (i == 0) offsets[n2] = e2tot;
}

// dst-range-sharded scatter: shard = blockIdx&7 (~XCD). Each shard's blocks
// grid-stride ALL edges, committing only dst in [lo,hi). Shard CSR slice
// (~1.6MB) is L2-resident -> lines fill before eviction.
__global__ __launch_bounds__(256)
void scatter2_shard_kernel(const int* __restrict__ ei0, const int* __restrict__ ei1,
                           int* __restrict__ cursor, int* __restrict__ csr_src,
                           int E, int N, int n2)
{
    const int shard   = blockIdx.x & 7;
    const int bid     = blockIdx.x >> 3;
    const int nblocks = gridDim.x >> 3;
    const int lo = (int)(((long long)n2 * shard) >> 3);
    const int hi = (int)(((long long)n2 * (shard + 1)) >> 3);

    long long start  = (long long)bid * blockDim.x + threadIdx.x;
    long long stride = (long long)nblocks * blockDim.x;
    const long long e2 = 2LL * E;
    for (long long e = start; e < e2; e += stride) {
        int s, d;
        if (e < E) { s = ei0[e];                 d = ei0[E + e]; }
        else       { s = ei1[e - E] + N;         d = ei1[E + (e - E)] + N; }
        if (d >= lo && d < hi) {
            int pos = atomicAdd(&cursor[d], 1);
            csr_src[pos] = s;
        }
    }
}

// ---------------- GEMM: Ys = (X @ W12) * dinv over 2N rows ----------------
__global__ __launch_bounds__(256)
void gemm_ys2_kernel(const float* __restrict__ x0, const float* __restrict__ x1,
                     const float* __restrict__ W12, const float* __restrict__ dinv,
                     float* __restrict__ Ys, int N, int n2)
{
    __shared__ float Ws[IN_F * OUT_F];
    __shared__ float xs[8 * IN_F];
    const int tid = threadIdx.x;

    for (int i = tid; i < IN_F * OUT_F; i += 256) Ws[i] = W12[i];
    const int row0 = blockIdx.x * 8;
    for (int i = tid; i < 8 * IN_F; i += 256) {
        int r = i >> 6;
        int rr = row0 + r;
        float v = 0.0f;
        if (rr < n2) {
            v = (rr < N) ? x0[(size_t)rr * IN_F + (i & 63)]
                         : x1[(size_t)(rr - N) * IN_F + (i & 63)];
        }
        xs[i] = v;
    }
    __syncthreads();

    const int r = tid >> 5;
    const int c = tid & 31;
    const int row = row0 + r;
    if (row >= n2) return;

    float acc = 0.0f;
#pragma unroll
    for (int k = 0; k < IN_F; ++k) acc += xs[r * IN_F + k] * Ws[k * OUT_F + c];

    Ys[(size_t)row * OUT_F + c] = acc * dinv[row];
}

// ---------------- CSR gather-aggregate, 32-wide, unroll 8 ----------------
// MODE 0: out_i = dinv_i^2 * (in_i + sum_j in_j); also sdsum_i = sum_j dinv_j (coalesced)
// MODE 1: out_i = dinv_i   * (in_i + sum_j in_j) + t_i*c1 + b2,  t_i = dinv_i*(dinv_i+sdsum_i)
template<int MODE>
__global__ __launch_bounds__(256)
void csr_agg32_kernel(const int* __restrict__ csr_src, const int* __restrict__ offsets,
                      const float* __restrict__ in, const float* __restrict__ dinv,
                      float* __restrict__ sdsum, const float* __restrict__ c1,
                      const float* __restrict__ b2,
                      float* __restrict__ out, int n)
{
    constexpr int F = OUT_F;              // 32
    const int lane = threadIdx.x & 63;
    const int wid  = (blockIdx.x * (blockDim.x >> 6)) + (threadIdx.x >> 6);
    const int sub  = lane >> 5;           // 2 nodes per wave
    const int f    = lane & 31;
    const int node = wid * 2 + sub;
    const int lbase = sub * F;

    const bool valid = (node < n);
    const int nc   = valid ? node : 0;
    const int off0 = offsets[nc];
    const int off1 = valid ? offsets[nc + 1] : off0;

    float acc0 = valid ? in[(size_t)nc * F + f] : 0.0f;   // self term
    float acc1 = 0.0f, acc2 = 0.0f, acc3 = 0.0f;
    float dsum = 0.0f;                                    // MODE 0 only
    for (int k = off0; k < off1; k += F) {
        int nk = off1 - k; if (nk > F) nk = F;
        int sj = (f < nk) ? csr_src[k + f] : 0;
        if (MODE == 0) {
            float dv = dinv[sj];
            dsum += (f < nk) ? dv : 0.0f;
        }
        int t = 0;
        for (; t + 8 <= nk; t += 8) {
            int s0 = __shfl(sj, lbase + t);
            int s1 = __shfl(sj, lbase + t + 1);
            int s2 = __shfl(sj, lbase + t + 2);
            int s3 = __shfl(sj, lbase + t + 3);
            int s4 = __shfl(sj, lbase + t + 4);
            int s5 = __shfl(sj, lbase + t + 5);
            int s6 = __shfl(sj, lbase + t + 6);
            int s7 = __shfl(sj, lbase + t + 7);
            float v0 = in[(size_t)s0 * F + f];
            float v1 = in[(size_t)s1 * F + f];
            float v2 = in[(size_t)s2 * F + f];
            float v3 = in[(size_t)s3 * F + f];
            float v4 = in[(size_t)s4 * F + f];
            float v5 = in[(size_t)s5 * F + f];
            float v6 = in[(size_t)s6 * F + f];
            float v7 = in[(size_t)s7 * F + f];
            acc0 += v0 + v4;
            acc1 += v1 + v5;
            acc2 += v2 + v6;
            acc3 += v3 + v7;
        }
        for (; t < nk; ++t) {
            int s = __shfl(sj, lbase + t);
            acc0 += in[(size_t)s * F + f];
        }
    }
    if (MODE == 0) {
#pragma unroll
        for (int off = 1; off < 32; off <<= 1) dsum += __shfl_xor(dsum, off);
    }
    if (valid) {
        float di = dinv[node];
        float s = (acc0 + acc1) + (acc2 + acc3);
        if (MODE == 0) {
            out[(size_t)node * F + f] = di * di * s;
            if (f == 0) sdsum[node] = dsum;
        } else {
            float t = di * (di + sdsum[node]);
            out[(size_t)node * F + f] = di * s + t * c1[f] + b2[f];
        }
    }
}

// ---------------- mean pool over both graphs (2N nodes -> 2B graphs) ----------------
__global__ void pool_sum2_kernel(const float* __restrict__ h,
                                 const int* __restrict__ bat0, const int* __restrict__ bat1,
                                 float* __restrict__ pooled, float* __restrict__ cnt,
                                 int N, int n2, int B)
{
    int t = blockIdx.x * blockDim.x + threadIdx.x;
    int i = t >> 5;          // node
    int f = t & 31;          // feature
    if (i >= n2) return;
    int g = (i < N) ? bat0[i] : (bat1[i - N] + B);
    atomicAdd(&pooled[(size_t)g * OUT_F + f], h[(size_t)i * OUT_F + f]);
    if (f == 0) atomicAdd(&cnt[g], 1.0f);
}

__global__ void pool_div_kernel(float* __restrict__ pooled, const float* __restrict__ cnt, int B2)
{
    int t = blockIdx.x * blockDim.x + threadIdx.x;
    if (t >= B2 * OUT_F) return;
    int g = t >> 5;
    pooled[t] /= fmaxf(cnt[g], 1.0f);
}

// ---------------- gate: softmax([p0|p1] @ Wc + bc) ----------------
__global__ void gate_kernel(const float* __restrict__ p0, const float* __restrict__ p1,
                            const float* __restrict__ Wc, const float* __restrict__ bc,
                            float* __restrict__ gate, int B)
{
    int g = blockIdx.x * blockDim.x + threadIdx.x;
    if (g >= B) return;
    float xv[2 * OUT_F];
#pragma unroll
    for (int k = 0; k < OUT_F; ++k) xv[k] = p0[(size_t)g * OUT_F + k];
#pragma unroll
    for (int k = 0; k < OUT_F; ++k) xv[OUT_F + k] = p1[(size_t)g * OUT_F + k];

    float lg[NEXP];
    float m = -1e30f;
#pragma unroll
    for (int e = 0; e < NEXP; ++e) {
        float acc = bc[e];
#pragma unroll
        for (int k = 0; k < 2 * OUT_F; ++k) acc += xv[k] * Wc[k * NEXP + e];
        lg[e] = acc;
        m = fmaxf(m, acc);
    }
    float se = 0.0f;
#pragma unroll
    for (int e = 0; e < NEXP; ++e) { lg[e] = expf(lg[e] - m); se += lg[e]; }
    float inv = 1.0f / se;
#pragma unroll
    for (int e = 0; e < NEXP; ++e) gate[(size_t)g * NEXP + e] = lg[e] * inv;
}

__global__ void zero_scalar_kernel(float* p) { *p = 0.0f; }

// ---------------- distortion: group edges by s (counting sort over B buckets) ----------------
__global__ void histD_kernel(const int* __restrict__ s_idx, int* __restrict__ cntD, int E2) {
    int e = blockIdx.x * blockDim.x + threadIdx.x;
    if (e >= E2) return;
    atomicAdd(&cntD[s_idx[e]], 1);
}

__global__ void combineD_kernel(const int* __restrict__ lexclD, const int* __restrict__ partialsD,
                                int* __restrict__ offD, int* __restrict__ curD, int B, int E2)
{
    int i = blockIdx.x * blockDim.x + threadIdx.x;
    if (i >= B) return;
    int o = lexclD[i] + partialsD[i >> 10];
    offD[i] = o;
    curD[i] = o;
    if (i == 0) offD[B] = E2;
}

__global__ void scatterD_kernel(const int* __restrict__ s_idx, const int* __restrict__ d_idx,
                                const float* __restrict__ dis,
                                int* __restrict__ curD, int* __restrict__ dD,
                                float* __restrict__ disD, int E2)
{
    int e = blockIdx.x * blockDim.x + threadIdx.x;
    if (e >= E2) return;
    int s = s_idx[e];
    int pos = atomicAdd(&curD[s], 1);
    dD[pos] = d_idx[e];
    disD[pos] = dis[e];
}

// ONE wave per s-group (4096 waves = measured TCC knee); s-row + gate[s]
// in registers across the group's ~32 edges; per edge only d-row + gate[d].
__global__ __launch_bounds__(256)
void distortion2_kernel(const float* __restrict__ emb, const float* __restrict__ gate,
                        const int* __restrict__ offD, const int* __restrict__ dD,
                        const float* __restrict__ disD,
                        float* __restrict__ loss, int B, int E2)
{
    const int s    = (blockIdx.x * (blockDim.x >> 6)) + (threadIdx.x >> 6);
    const int lane = threadIdx.x & 63;
    const int grp  = lane >> 4;          // 16-lane group = expert pair (grp, grp+4)
    if (s >= B) return;

    const float4* emb4  = (const float4*)emb;
    const float4* gate4 = (const float4*)gate;

    const float4* es = emb4 + (size_t)s * 128;
    float4 a0 = es[lane];
    float4 a1 = es[lane + 64];
    float4 gs0 = gate4[(size_t)s * 2];
    float4 gs1 = gate4[(size_t)s * 2 + 1];

    float lsum = 0.0f;
    const int j1 = offD[s + 1];
    for (int j = offD[s]; j < j1; ++j) {
        int d = dD[j];
        float dv = disD[j];
        const float4* ed = emb4 + (size_t)d * 128;
        float4 b0 = ed[lane];
        float4 b1 = ed[lane + 64];
        float4 gd0 = gate4[(size_t)d * 2];
        float4 gd1 = gate4[(size_t)d * 2 + 1];

        float dx, pa, pb;
        dx = a0.x - b0.x; pa  = dx * dx;
        dx = a0.y - b0.y; pa += dx * dx;
        dx = a0.z - b0.z; pa += dx * dx;
        dx = a0.w - b0.w; pa += dx * dx;
        dx = a1.x - b1.x; pb  = dx * dx;
        dx = a1.y - b1.y; pb += dx * dx;
        dx = a1.z - b1.z; pb += dx * dx;
        dx = a1.w - b1.w; pb += dx * dx;

#pragma unroll
        for (int off = 1; off < 16; off <<= 1) {
            pa += __shfl_xor(pa, off);
            pb += __shfl_xor(pb, off);
        }

        float gp[NEXP] = { gs0.x * gd0.x, gs0.y * gd0.y, gs0.z * gd0.z, gs0.w * gd0.w,
                           gs1.x * gd1.x, gs1.y * gd1.y, gs1.z * gd1.z, gs1.w * gd1.w };
        float m = gp[0];
#pragma unroll
        for (int j2 = 1; j2 < NEXP; ++j2) m = fmaxf(m, gp[j2]);
        float se = 0.0f;
#pragma unroll
        for (int j2 = 0; j2 < NEXP; ++j2) { gp[j2] = expf(gp[j2] - m); se += gp[j2]; }

        float v = pa * gp[grp] + pb * gp[grp + 4];
        v += __shfl_xor(v, 16);
        v += __shfl_xor(v, 32);

        lsum += fabsf((v / se) / dv - 1.0f);
    }
    if (lane == 0) atomicAdd(loss, lsum / (float)E2);
}

// ---------------- launch ----------------
extern "C" void kernel_launch(void* const* d_in, const int* in_sizes, int n_in,
                              void* d_out, int out_size, void* d_ws, size_t ws_size,
                              hipStream_t stream)
{
    const float* x0   = (const float*)d_in[0];
    const float* x1   = (const float*)d_in[1];
    const float* W1   = (const float*)d_in[2];
    const float* b1   = (const float*)d_in[3];
    const float* W2   = (const float*)d_in[4];
    const float* b2   = (const float*)d_in[5];
    const float* Wc   = (const float*)d_in[6];
    const float* bc   = (const float*)d_in[7];
    const float* emb  = (const float*)d_in[8];
    const float* dis  = (const float*)d_in[9];
    const int*   ei0  = (const int*)d_in[10];
    const int*   ei1  = (const int*)d_in[11];
    const int*   bat0 = (const int*)d_in[12];
    const int*   bat1 = (const int*)d_in[13];
    const int*   ei2  = (const int*)d_in[14];

    const int N  = in_sizes[0] / IN_F;
    const int E  = in_sizes[10] / 2;
    const int B  = in_sizes[8] / (NEXP * EMB);
    const int E2 = in_sizes[14] / 2;
    const int n2 = 2 * N;

    float* gate_out = (float*)d_out;               // B*NEXP
    float* loss_out = gate_out + (size_t)B * NEXP; // 1

    // workspace layout (floats)
    float* ws      = (float*)d_ws;
    float* dinv    = ws;                           // 2N
    float* Ys      = dinv + n2;                    // 2N*32
    float* Zs      = Ys + (size_t)n2 * OUT_F;      // 2N*32
    float* sdsum   = Zs + (size_t)n2 * OUT_F;      // 2N
    float* pooled  = sdsum + n2;                   // 2B*32
    float* cnt     = pooled + (size_t)2 * B * OUT_F; // 2B
    float* W12     = cnt + 2 * B;                  // 64*32
    float* c1      = W12 + IN_F * OUT_F;           // 32
    float* disD    = c1 + OUT_F;                   // E2
    int*   iws     = (int*)(disD + E2);
    int*   counts  = iws;                          // 2N
    int*   offsets = counts + n2;                  // 2N+1
    int*   cursor  = offsets + n2 + 1;             // 2N
    int*   csr_src = cursor + n2;                  // 2E
    int*   lexcl   = csr_src + 2 * E;              // 2N
    int*   partials= lexcl + n2;                   // <=1024
    int*   cntD    = partials + 1024;              // B
    int*   lexclD  = cntD + B;                     // B
    int*   partialsD = lexclD + B;                 // <=16
    int*   offD    = partialsD + 16;               // B+1
    int*   curD    = offD + B + 1;                 // B
    int*   dD      = curD + B;                     // E2

    const int TB = 256;
    const int zgrid = 512;
    const int NB2 = (n2 + 1023) / 1024;            // scan blocks over 2N
    const int NBD = (B + 1023) / 1024;             // scan blocks over B

    // W12 = W1@W2, c1 = b1@W2 (once)
    w12_kernel<<<1, 1024, 0, stream>>>(W1, W2, b1, W12, c1);

    // ---- fused CSR build over both graphs ----
    zero_i32_kernel<<<zgrid, TB, 0, stream>>>(counts, n2);
    hist2_kernel<<<(2 * E + TB - 1) / TB, TB, 0, stream>>>(ei0, ei1, counts, E, N);
    scan1_kernel<<<NB2, 1024, 0, stream>>>(counts, lexcl, partials, n2);
    scan2_kernel<<<1, 1024, 0, stream>>>(partials, NB2);
    scan3_kernel<<<(n2 + TB - 1) / TB, TB, 0, stream>>>(lexcl, partials, counts,
                                                        offsets, cursor, dinv, n2, 2 * E);
    scatter2_shard_kernel<<<1024, TB, 0, stream>>>(ei0, ei1, cursor, csr_src, E, N, n2);

    // ---- distortion edge sort by s (independent of encoder) ----
    zero_i32_kernel<<<zgrid, TB, 0, stream>>>(cntD, B);
    histD_kernel<<<(E2 + TB - 1) / TB, TB, 0, stream>>>(ei2, cntD, E2);
    scan1_kernel<<<NBD, 1024, 0, stream>>>(cntD, lexclD, partialsD, B);
    scan2_kernel<<<1, 1024, 0, stream>>>(partialsD, NBD);
    combineD_kernel<<<(B + TB - 1) / TB, TB, 0, stream>>>(lexclD, partialsD, offD, curD, B, E2);
    scatterD_kernel<<<(E2 + TB - 1) / TB, TB, 0, stream>>>(ei2, ei2 + E2, dis,
                                                           curD, dD, disD, E2);

    // ---- encoder: Ys = (X@W12)*dinv ; two aggregation passes ----
    gemm_ys2_kernel<<<(n2 + 7) / 8, 256, 0, stream>>>(x0, x1, W12, dinv, Ys, N, n2);
    csr_agg32_kernel<0><<<(n2 + 7) / 8, TB, 0, stream>>>(csr_src, offsets, Ys, dinv,
                                                         sdsum, nullptr, nullptr, Zs, n2);
    csr_agg32_kernel<1><<<(n2 + 7) / 8, TB, 0, stream>>>(csr_src, offsets, Zs, dinv,
                                                         sdsum, c1, b2, Ys, n2);

    // ---- mean pool (both graphs) ----
    zero_f32_kernel<<<zgrid, TB, 0, stream>>>(pooled, (long long)2 * B * OUT_F);
    zero_f32_kernel<<<zgrid, TB, 0, stream>>>(cnt, 2 * B);
    pool_sum2_kernel<<<((n2 * 32) + TB - 1) / TB, TB, 0, stream>>>(Ys, bat0, bat1,
                                                                   pooled, cnt, N, n2, B);
    pool_div_kernel<<<((2 * B * OUT_F) + TB - 1) / TB, TB, 0, stream>>>(pooled, cnt, 2 * B);

    // ---- gate ----
    gate_kernel<<<(B + TB - 1) / TB, TB, 0, stream>>>(pooled, pooled + (size_t)B * OUT_F,
                                                      Wc, bc, gate_out, B);

    // ---- distortion loss (grouped by s, 1 wave/group) ----
    zero_scalar_kernel<<<1, 1, 0, stream>>>(loss_out);
    distortion2_kernel<<<(B + 3) / 4, TB, 0, stream>>>(emb, gate_out, offD, dD, disD,
                                                       loss_out, B, E2);
}

// Round 16
// 419.809 us; speedup vs baseline: 1.4925x; 1.0325x over previous
//
#include <hip/hip_runtime.h>
#include <math.h>

// ---------------- constants from the reference ----------------
constexpr int IN_F  = 64;
constexpr int HID_F = 64;
constexpr int OUT_F = 32;
constexpr int NEXP  = 8;
constexpr int EMB   = 64;   // emb_dim

// Encoder is linear: h2 = A^(A^(X W12)) + t*(b1 W2) + b2, W12 = W1@W2.
// Both subgraphs fused into one pipeline over 2N nodes / 2E edges.
// Scatter is dst-range-sharded x8 (L2-resident CSR slices).
// Distortion: edges sorted by s; one wave per s-group, HALF-WAVE PER EDGE
// (2 edges in flight inside the same vector instructions -> 2x MLP without
// register pipelining, which the compiler defeats — r7/r8 evidence).

// ---------------- utility kernels ----------------
__global__ void zero_f32_kernel(float* __restrict__ p, long long n) {
    long long i = (long long)blockIdx.x * blockDim.x + threadIdx.x;
    long long stride = (long long)gridDim.x * blockDim.x;
    for (; i < n; i += stride) p[i] = 0.0f;
}

__global__ void zero_i32_kernel(int* __restrict__ p, long long n) {
    long long i = (long long)blockIdx.x * blockDim.x + threadIdx.x;
    long long stride = (long long)gridDim.x * blockDim.x;
    for (; i < n; i += stride) p[i] = 0;
}

// ---------------- W12 = W1@W2, c1 = b1@W2 (once) ----------------
__global__ __launch_bounds__(1024)
void w12_kernel(const float* __restrict__ W1, const float* __restrict__ W2,
                const float* __restrict__ b1,
                float* __restrict__ W12, float* __restrict__ c1)
{
    __shared__ float sW2[HID_F * OUT_F];
    const int tid = threadIdx.x;
    for (int i = tid; i < HID_F * OUT_F; i += 1024) sW2[i] = W2[i];
    __syncthreads();
    for (int idx = tid; idx < IN_F * OUT_F; idx += 1024) {
        int i = idx >> 5, j = idx & 31;
        float acc = 0.0f;
#pragma unroll
        for (int k = 0; k < HID_F; ++k) acc += W1[i * HID_F + k] * sW2[k * OUT_F + j];
        W12[idx] = acc;
    }
    if (tid < OUT_F) {
        float acc = 0.0f;
#pragma unroll
        for (int k = 0; k < HID_F; ++k) acc += b1[k] * sW2[k * OUT_F + tid];
        c1[tid] = acc;
    }
}

// ---------------- fused CSR build over both graphs ----------------
__global__ void hist2_kernel(const int* __restrict__ ei0, const int* __restrict__ ei1,
                             int* __restrict__ counts, int E, int N)
{
    int e = blockIdx.x * blockDim.x + threadIdx.x;
    if (e >= 2 * E) return;
    int d = (e < E) ? ei0[E + e] : (ei1[E + (e - E)] + N);
    atomicAdd(&counts[d], 1);
}

// two-level exclusive scan (race-free)
__global__ __launch_bounds__(1024)
void scan1_kernel(const int* __restrict__ counts, int* __restrict__ lexcl,
                  int* __restrict__ partials, int N)
{
    __shared__ int wsum[16];
    const int tid  = threadIdx.x;
    const int lane = tid & 63;
    const int wv   = tid >> 6;
    const int i    = blockIdx.x * 1024 + tid;

    int v = (i < N) ? counts[i] : 0;
    int x = v;
#pragma unroll
    for (int off = 1; off < 64; off <<= 1) {
        int t = __shfl_up(x, off);
        if (lane >= off) x += t;
    }
    if (lane == 63) wsum[wv] = x;
    __syncthreads();
    int woff = 0;
    for (int w = 0; w < wv; ++w) woff += wsum[w];
    if (i < N) lexcl[i] = woff + x - v;
    if (tid == 1023) partials[blockIdx.x] = woff + x;
}

__global__ __launch_bounds__(1024)
void scan2_kernel(int* __restrict__ partials, int NB)
{
    __shared__ int wsum[16];
    const int tid  = threadIdx.x;
    const int lane = tid & 63;
    const int wv   = tid >> 6;
    int v = (tid < NB) ? partials[tid] : 0;
    int x = v;
#pragma unroll
    for (int off = 1; off < 64; off <<= 1) {
        int t = __shfl_up(x, off);
        if (lane >= off) x += t;
    }
    if (lane == 63) wsum[wv] = x;
    __syncthreads();
    int woff = 0;
    for (int w = 0; w < wv; ++w) woff += wsum[w];
    if (tid < NB) partials[tid] = woff + x - v;
}

// combine -> offsets/cursor, dinv = rsqrt(deg+1)
__global__ void scan3_kernel(const int* __restrict__ lexcl, const int* __restrict__ partials,
                             const int* __restrict__ counts,
                             int* __restrict__ offsets, int* __restrict__ cursor,
                             float* __restrict__ dinv, int n2, int e2tot)
{
    int i = blockIdx.x * blockDim.x + threadIdx.x;
    if (i >= n2) return;
    int o = lexcl[i] + partials[i >> 10];
    offsets[i] = o;
    cursor[i]  = o;
    dinv[i] = rsqrtf((float)counts[i] + 1.0f);
    if (i == 0) offsets[n2] = e2tot;
}

// dst-range-sharded scatter (r15-verified: breaks 16x write amplification)
__global__ __launch_bounds__(256)
void scatter2_shard_kernel(const int* __restrict__ ei0, const int* __restrict__ ei1,
                           int* __restrict__ cursor, int* __restrict__ csr_src,
                           int E, int N, int n2)
{
    const int shard   = blockIdx.x & 7;
    const int bid     = blockIdx.x >> 3;
    const int nblocks = gridDim.x >> 3;
    const int lo = (int)(((long long)n2 * shard) >> 3);
    const int hi = (int)(((long long)n2 * (shard + 1)) >> 3);

    long long start  = (long long)bid * blockDim.x + threadIdx.x;
    long long stride = (long long)nblocks * blockDim.x;
    const long long e2 = 2LL * E;
    for (long long e = start; e < e2; e += stride) {
        int s, d;
        if (e < E) { s = ei0[e];                 d = ei0[E + e]; }
        else       { s = ei1[e - E] + N;         d = ei1[E + (e - E)] + N; }
        if (d >= lo && d < hi) {
            int pos = atomicAdd(&cursor[d], 1);
            csr_src[pos] = s;
        }
    }
}

// ---------------- GEMM: Ys = (X @ W12) * dinv over 2N rows ----------------
__global__ __launch_bounds__(256)
void gemm_ys2_kernel(const float* __restrict__ x0, const float* __restrict__ x1,
                     const float* __restrict__ W12, const float* __restrict__ dinv,
                     float* __restrict__ Ys, int N, int n2)
{
    __shared__ float Ws[IN_F * OUT_F];
    __shared__ float xs[8 * IN_F];
    const int tid = threadIdx.x;

    for (int i = tid; i < IN_F * OUT_F; i += 256) Ws[i] = W12[i];
    const int row0 = blockIdx.x * 8;
    for (int i = tid; i < 8 * IN_F; i += 256) {
        int r = i >> 6;
        int rr = row0 + r;
        float v = 0.0f;
        if (rr < n2) {
            v = (rr < N) ? x0[(size_t)rr * IN_F + (i & 63)]
                         : x1[(size_t)(rr - N) * IN_F + (i & 63)];
        }
        xs[i] = v;
    }
    __syncthreads();

    const int r = tid >> 5;
    const int c = tid & 31;
    const int row = row0 + r;
    if (row >= n2) return;

    float acc = 0.0f;
#pragma unroll
    for (int k = 0; k < IN_F; ++k) acc += xs[r * IN_F + k] * Ws[k * OUT_F + c];

    Ys[(size_t)row * OUT_F + c] = acc * dinv[row];
}

// ---------------- CSR gather-aggregate, 32-wide, unroll 8 ----------------
// MODE 0: out_i = dinv_i^2 * (in_i + sum_j in_j); also sdsum_i = sum_j dinv_j (coalesced)
// MODE 1: out_i = dinv_i   * (in_i + sum_j in_j) + t_i*c1 + b2,  t_i = dinv_i*(dinv_i+sdsum_i)
template<int MODE>
__global__ __launch_bounds__(256)
void csr_agg32_kernel(const int* __restrict__ csr_src, const int* __restrict__ offsets,
                      const float* __restrict__ in, const float* __restrict__ dinv,
                      float* __restrict__ sdsum, const float* __restrict__ c1,
                      const float* __restrict__ b2,
                      float* __restrict__ out, int n)
{
    constexpr int F = OUT_F;              // 32
    const int lane = threadIdx.x & 63;
    const int wid  = (blockIdx.x * (blockDim.x >> 6)) + (threadIdx.x >> 6);
    const int sub  = lane >> 5;           // 2 nodes per wave
    const int f    = lane & 31;
    const int node = wid * 2 + sub;
    const int lbase = sub * F;

    const bool valid = (node < n);
    const int nc   = valid ? node : 0;
    const int off0 = offsets[nc];
    const int off1 = valid ? offsets[nc + 1] : off0;

    float acc0 = valid ? in[(size_t)nc * F + f] : 0.0f;   // self term
    float acc1 = 0.0f, acc2 = 0.0f, acc3 = 0.0f;
    float dsum = 0.0f;                                    // MODE 0 only
    for (int k = off0; k < off1; k += F) {
        int nk = off1 - k; if (nk > F) nk = F;
        int sj = (f < nk) ? csr_src[k + f] : 0;
        if (MODE == 0) {
            float dv = dinv[sj];
            dsum += (f < nk) ? dv : 0.0f;
        }
        int t = 0;
        for (; t + 8 <= nk; t += 8) {
            int s0 = __shfl(sj, lbase + t);
            int s1 = __shfl(sj, lbase + t + 1);
            int s2 = __shfl(sj, lbase + t + 2);
            int s3 = __shfl(sj, lbase + t + 3);
            int s4 = __shfl(sj, lbase + t + 4);
            int s5 = __shfl(sj, lbase + t + 5);
            int s6 = __shfl(sj, lbase + t + 6);
            int s7 = __shfl(sj, lbase + t + 7);
            float v0 = in[(size_t)s0 * F + f];
            float v1 = in[(size_t)s1 * F + f];
            float v2 = in[(size_t)s2 * F + f];
            float v3 = in[(size_t)s3 * F + f];
            float v4 = in[(size_t)s4 * F + f];
            float v5 = in[(size_t)s5 * F + f];
            float v6 = in[(size_t)s6 * F + f];
            float v7 = in[(size_t)s7 * F + f];
            acc0 += v0 + v4;
            acc1 += v1 + v5;
            acc2 += v2 + v6;
            acc3 += v3 + v7;
        }
        for (; t < nk; ++t) {
            int s = __shfl(sj, lbase + t);
            acc0 += in[(size_t)s * F + f];
        }
    }
    if (MODE == 0) {
#pragma unroll
        for (int off = 1; off < 32; off <<= 1) dsum += __shfl_xor(dsum, off);
    }
    if (valid) {
        float di = dinv[node];
        float s = (acc0 + acc1) + (acc2 + acc3);
        if (MODE == 0) {
            out[(size_t)node * F + f] = di * di * s;
            if (f == 0) sdsum[node] = dsum;
        } else {
            float t = di * (di + sdsum[node]);
            out[(size_t)node * F + f] = di * s + t * c1[f] + b2[f];
        }
    }
}

// ---------------- mean pool over both graphs (2N nodes -> 2B graphs) ----------------
__global__ void pool_sum2_kernel(const float* __restrict__ h,
                                 const int* __restrict__ bat0, const int* __restrict__ bat1,
                                 float* __restrict__ pooled, float* __restrict__ cnt,
                                 int N, int n2, int B)
{
    int t = blockIdx.x * blockDim.x + threadIdx.x;
    int i = t >> 5;          // node
    int f = t & 31;          // feature
    if (i >= n2) return;
    int g = (i < N) ? bat0[i] : (bat1[i - N] + B);
    atomicAdd(&pooled[(size_t)g * OUT_F + f], h[(size_t)i * OUT_F + f]);
    if (f == 0) atomicAdd(&cnt[g], 1.0f);
}

__global__ void pool_div_kernel(float* __restrict__ pooled, const float* __restrict__ cnt, int B2)
{
    int t = blockIdx.x * blockDim.x + threadIdx.x;
    if (t >= B2 * OUT_F) return;
    int g = t >> 5;
    pooled[t] /= fmaxf(cnt[g], 1.0f);
}

// ---------------- gate: softmax([p0|p1] @ Wc + bc) ----------------
__global__ void gate_kernel(const float* __restrict__ p0, const float* __restrict__ p1,
                            const float* __restrict__ Wc, const float* __restrict__ bc,
                            float* __restrict__ gate, int B)
{
    int g = blockIdx.x * blockDim.x + threadIdx.x;
    if (g >= B) return;
    float xv[2 * OUT_F];
#pragma unroll
    for (int k = 0; k < OUT_F; ++k) xv[k] = p0[(size_t)g * OUT_F + k];
#pragma unroll
    for (int k = 0; k < OUT_F; ++k) xv[OUT_F + k] = p1[(size_t)g * OUT_F + k];

    float lg[NEXP];
    float m = -1e30f;
#pragma unroll
    for (int e = 0; e < NEXP; ++e) {
        float acc = bc[e];
#pragma unroll
        for (int k = 0; k < 2 * OUT_F; ++k) acc += xv[k] * Wc[k * NEXP + e];
        lg[e] = acc;
        m = fmaxf(m, acc);
    }
    float se = 0.0f;
#pragma unroll
    for (int e = 0; e < NEXP; ++e) { lg[e] = expf(lg[e] - m); se += lg[e]; }
    float inv = 1.0f / se;
#pragma unroll
    for (int e = 0; e < NEXP; ++e) gate[(size_t)g * NEXP + e] = lg[e] * inv;
}

__global__ void zero_scalar_kernel(float* p) { *p = 0.0f; }

// ---------------- distortion: group edges by s (counting sort over B buckets) ----------------
__global__ void histD_kernel(const int* __restrict__ s_idx, int* __restrict__ cntD, int E2) {
    int e = blockIdx.x * blockDim.x + threadIdx.x;
    if (e >= E2) return;
    atomicAdd(&cntD[s_idx[e]], 1);
}

__global__ void combineD_kernel(const int* __restrict__ lexclD, const int* __restrict__ partialsD,
                                int* __restrict__ offD, int* __restrict__ curD, int B, int E2)
{
    int i = blockIdx.x * blockDim.x + threadIdx.x;
    if (i >= B) return;
    int o = lexclD[i] + partialsD[i >> 10];
    offD[i] = o;
    curD[i] = o;
    if (i == 0) offD[B] = E2;
}

__global__ void scatterD_kernel(const int* __restrict__ s_idx, const int* __restrict__ d_idx,
                                const float* __restrict__ dis,
                                int* __restrict__ curD, int* __restrict__ dD,
                                float* __restrict__ disD, int E2)
{
    int e = blockIdx.x * blockDim.x + threadIdx.x;
    if (e >= E2) return;
    int s = s_idx[e];
    int pos = atomicAdd(&curD[s], 1);
    dD[pos] = d_idx[e];
    disD[pos] = dis[e];
}

// One wave per s-group; HALF-WAVE (32 lanes) per edge -> 2 edges in flight
// per vector instruction. Lane hl holds d-row float4s {hl, hl+32, hl+64, hl+96}
// -> after 16-lane butterfly, lane-group g holds expert sums {g,g+2,g+4,g+6};
// off=16 shuffle completes the 8-expert weighted sum (halves never mix).
__global__ __launch_bounds__(256)
void distortion3_kernel(const float* __restrict__ emb, const float* __restrict__ gate,
                        const int* __restrict__ offD, const int* __restrict__ dD,
                        const float* __restrict__ disD,
                        float* __restrict__ loss, int B, int E2)
{
    const int s    = (blockIdx.x * (blockDim.x >> 6)) + (threadIdx.x >> 6);
    const int lane = threadIdx.x & 63;
    const int half = lane >> 5;          // which edge of the pair
    const int hl   = lane & 31;          // lane within half
    const int g    = hl >> 4;            // expert base (0 or 1)
    if (s >= B) return;

    const float4* emb4  = (const float4*)emb;
    const float4* gate4 = (const float4*)gate;

    // s-row resident: 4 float4/lane (both halves identical)
    const float4* es = emb4 + (size_t)s * 128;
    float4 a0 = es[hl];
    float4 a1 = es[hl + 32];
    float4 a2 = es[hl + 64];
    float4 a3 = es[hl + 96];
    float4 gs0 = gate4[(size_t)s * 2];
    float4 gs1 = gate4[(size_t)s * 2 + 1];

    float lsum = 0.0f;
    const int j0 = offD[s];
    const int j1 = offD[s + 1];
    for (int j = j0 + half; j < j1; j += 2) {
        int d = dD[j];
        float dv = disD[j];
        const float4* ed = emb4 + (size_t)d * 128;
        float4 b0 = ed[hl];
        float4 b1 = ed[hl + 32];
        float4 b2 = ed[hl + 64];
        float4 b3 = ed[hl + 96];
        float4 gd0 = gate4[(size_t)d * 2];
        float4 gd1 = gate4[(size_t)d * 2 + 1];

        float dx;
        float pa, pb, pc, pd;
        dx = a0.x - b0.x; pa  = dx * dx;
        dx = a0.y - b0.y; pa += dx * dx;
        dx = a0.z - b0.z; pa += dx * dx;
        dx = a0.w - b0.w; pa += dx * dx;
        dx = a1.x - b1.x; pb  = dx * dx;
        dx = a1.y - b1.y; pb += dx * dx;
        dx = a1.z - b1.z; pb += dx * dx;
        dx = a1.w - b1.w; pb += dx * dx;
        dx = a2.x - b2.x; pc  = dx * dx;
        dx = a2.y - b2.y; pc += dx * dx;
        dx = a2.z - b2.z; pc += dx * dx;
        dx = a2.w - b2.w; pc += dx * dx;
        dx = a3.x - b3.x; pd  = dx * dx;
        dx = a3.y - b3.y; pd += dx * dx;
        dx = a3.z - b3.z; pd += dx * dx;
        dx = a3.w - b3.w; pd += dx * dx;

        // 16-lane butterfly (bits 0-3: stays within the 16-group of this half)
#pragma unroll
        for (int off = 1; off < 16; off <<= 1) {
            pa += __shfl_xor(pa, off);
            pb += __shfl_xor(pb, off);
            pc += __shfl_xor(pc, off);
            pd += __shfl_xor(pd, off);
        }
        // lane-group g now holds: pa=expert g, pb=g+2, pc=g+4, pd=g+6

        float gp[NEXP] = { gs0.x * gd0.x, gs0.y * gd0.y, gs0.z * gd0.z, gs0.w * gd0.w,
                           gs1.x * gd1.x, gs1.y * gd1.y, gs1.z * gd1.z, gs1.w * gd1.w };
        float m = gp[0];
#pragma unroll
        for (int j2 = 1; j2 < NEXP; ++j2) m = fmaxf(m, gp[j2]);
        float se = 0.0f;
#pragma unroll
        for (int j2 = 0; j2 < NEXP; ++j2) { gp[j2] = expf(gp[j2] - m); se += gp[j2]; }

        float v = pa * gp[g] + pb * gp[g + 2] + pc * gp[g + 4] + pd * gp[g + 6];
        v += __shfl_xor(v, 16);      // combine expert groups within the half

        lsum += fabsf((v / se) / dv - 1.0f);
    }
    // lsum identical across each half; combine halves then one atomic
    float other = __shfl_xor(lsum, 32);
    if (lane == 0) atomicAdd(loss, (lsum + other) / (float)E2);
}

// ---------------- launch ----------------
extern "C" void kernel_launch(void* const* d_in, const int* in_sizes, int n_in,
                              void* d_out, int out_size, void* d_ws, size_t ws_size,
                              hipStream_t stream)
{
    const float* x0   = (const float*)d_in[0];
    const float* x1   = (const float*)d_in[1];
    const float* W1   = (const float*)d_in[2];
    const float* b1   = (const float*)d_in[3];
    const float* W2   = (const float*)d_in[4];
    const float* b2   = (const float*)d_in[5];
    const float* Wc   = (const float*)d_in[6];
    const float* bc   = (const float*)d_in[7];
    const float* emb  = (const float*)d_in[8];
    const float* dis  = (const float*)d_in[9];
    const int*   ei0  = (const int*)d_in[10];
    const int*   ei1  = (const int*)d_in[11];
    const int*   bat0 = (const int*)d_in[12];
    const int*   bat1 = (const int*)d_in[13];
    const int*   ei2  = (const int*)d_in[14];

    const int N  = in_sizes[0] / IN_F;
    const int E  = in_sizes[10] / 2;
    const int B  = in_sizes[8] / (NEXP * EMB);
    const int E2 = in_sizes[14] / 2;
    const int n2 = 2 * N;

    float* gate_out = (float*)d_out;               // B*NEXP
    float* loss_out = gate_out + (size_t)B * NEXP; // 1

    // workspace layout (floats)
    float* ws      = (float*)d_ws;
    float* dinv    = ws;                           // 2N
    float* Ys      = dinv + n2;                    // 2N*32
    float* Zs      = Ys + (size_t)n2 * OUT_F;      // 2N*32
    float* sdsum   = Zs + (size_t)n2 * OUT_F;      // 2N
    float* pooled  = sdsum + n2;                   // 2B*32
    float* cnt     = pooled + (size_t)2 * B * OUT_F; // 2B
    float* W12     = cnt + 2 * B;                  // 64*32
    float* c1      = W12 + IN_F * OUT_F;           // 32
    float* disD    = c1 + OUT_F;                   // E2
    int*   iws     = (int*)(disD + E2);
    int*   counts  = iws;                          // 2N
    int*   offsets = counts + n2;                  // 2N+1
    int*   cursor  = offsets + n2 + 1;             // 2N
    int*   csr_src = cursor + n2;                  // 2E
    int*   lexcl   = csr_src + 2 * E;              // 2N
    int*   partials= lexcl + n2;                   // <=1024
    int*   cntD    = partials + 1024;              // B
    int*   lexclD  = cntD + B;                     // B
    int*   partialsD = lexclD + B;                 // <=16
    int*   offD    = partialsD + 16;               // B+1
    int*   curD    = offD + B + 1;                 // B
    int*   dD      = curD + B;                     // E2

    const int TB = 256;
    const int zgrid = 512;
    const int NB2 = (n2 + 1023) / 1024;            // scan blocks over 2N
    const int NBD = (B + 1023) / 1024;             // scan blocks over B

    // W12 = W1@W2, c1 = b1@W2 (once)
    w12_kernel<<<1, 1024, 0, stream>>>(W1, W2, b1, W12, c1);

    // ---- fused CSR build over both graphs ----
    zero_i32_kernel<<<zgrid, TB, 0, stream>>>(counts, n2);
    hist2_kernel<<<(2 * E + TB - 1) / TB, TB, 0, stream>>>(ei0, ei1, counts, E, N);
    scan1_kernel<<<NB2, 1024, 0, stream>>>(counts, lexcl, partials, n2);
    scan2_kernel<<<1, 1024, 0, stream>>>(partials, NB2);
    scan3_kernel<<<(n2 + TB - 1) / TB, TB, 0, stream>>>(lexcl, partials, counts,
                                                        offsets, cursor, dinv, n2, 2 * E);
    scatter2_shard_kernel<<<1024, TB, 0, stream>>>(ei0, ei1, cursor, csr_src, E, N, n2);

    // ---- distortion edge sort by s (independent of encoder) ----
    zero_i32_kernel<<<zgrid, TB, 0, stream>>>(cntD, B);
    histD_kernel<<<(E2 + TB - 1) / TB, TB, 0, stream>>>(ei2, cntD, E2);
    scan1_kernel<<<NBD, 1024, 0, stream>>>(cntD, lexclD, partialsD, B);
    scan2_kernel<<<1, 1024, 0, stream>>>(partialsD, NBD);
    combineD_kernel<<<(B + TB - 1) / TB, TB, 0, stream>>>(lexclD, partialsD, offD, curD, B, E2);
    scatterD_kernel<<<(E2 + TB - 1) / TB, TB, 0, stream>>>(ei2, ei2 + E2, dis,
                                                           curD, dD, disD, E2);

    // ---- encoder: Ys = (X@W12)*dinv ; two aggregation passes ----
    gemm_ys2_kernel<<<(n2 + 7) / 8, 256, 0, stream>>>(x0, x1, W12, dinv, Ys, N, n2);
    csr_agg32_kernel<0><<<(n2 + 7) / 8, TB, 0, stream>>>(csr_src, offsets, Ys, dinv,
                                                         sdsum, nullptr, nullptr, Zs, n2);
    csr_agg32_kernel<1><<<(n2 + 7) / 8, TB, 0, stream>>>(csr_src, offsets, Zs, dinv,
                                                         sdsum, c1, b2, Ys, n2);

    // ---- mean pool (both graphs) ----
    zero_f32_kernel<<<zgrid, TB, 0, stream>>>(pooled, (long long)2 * B * OUT_F);
    zero_f32_kernel<<<zgrid, TB, 0, stream>>>(cnt, 2 * B);
    pool_sum2_kernel<<<((n2 * 32) + TB - 1) / TB, TB, 0, stream>>>(Ys, bat0, bat1,
                                                                   pooled, cnt, N, n2, B);
    pool_div_kernel<<<((2 * B * OUT_F) + TB - 1) / TB, TB, 0, stream>>>(pooled, cnt, 2 * B);

    // ---- gate ----
    gate_kernel<<<(B + TB - 1) / TB, TB, 0, stream>>>(pooled, pooled + (size_t)B * OUT_F,
                                                      Wc, bc, gate_out, B);

    // ---- distortion loss (grouped by s, half-wave per edge) ----
    zero_scalar_kernel<<<1, 1, 0, stream>>>(loss_out);
    distortion3_kernel<<<(B + 3) / 4, TB, 0, stream>>>(emb, gate_out, offD, dD, disD,
                                                       loss_out, B, E2);
}

// Round 17
// 413.836 us; speedup vs baseline: 1.5141x; 1.0144x over previous
//
#include <hip/hip_runtime.h>
#include <math.h>

// ---------------- constants from the reference ----------------
constexpr int IN_F  = 64;
constexpr int HID_F = 64;
constexpr int OUT_F = 32;
constexpr int NEXP  = 8;
constexpr int EMB   = 64;   // emb_dim

// Encoder is linear: h2 = A^(A^(X W12)) + t*(b1 W2) + b2, W12 = W1@W2.
// Distortion: edges sorted by key (d-quarter, s); shard = (qd, s-half) pinned
// to XCD via blockIdx&7. d-rows then hit a 2MB L2-resident slice; s-rows are
// band-streamed (512 consecutive s per shard step). Half-wave per edge.

// ---------------- utility kernels ----------------
__global__ void zero_f32_kernel(float* __restrict__ p, long long n) {
    long long i = (long long)blockIdx.x * blockDim.x + threadIdx.x;
    long long stride = (long long)gridDim.x * blockDim.x;
    for (; i < n; i += stride) p[i] = 0.0f;
}

__global__ void zero_i32_kernel(int* __restrict__ p, long long n) {
    long long i = (long long)blockIdx.x * blockDim.x + threadIdx.x;
    long long stride = (long long)gridDim.x * blockDim.x;
    for (; i < n; i += stride) p[i] = 0;
}

// ---------------- W12 = W1@W2, c1 = b1@W2 (once) ----------------
__global__ __launch_bounds__(1024)
void w12_kernel(const float* __restrict__ W1, const float* __restrict__ W2,
                const float* __restrict__ b1,
                float* __restrict__ W12, float* __restrict__ c1)
{
    __shared__ float sW2[HID_F * OUT_F];
    const int tid = threadIdx.x;
    for (int i = tid; i < HID_F * OUT_F; i += 1024) sW2[i] = W2[i];
    __syncthreads();
    for (int idx = tid; idx < IN_F * OUT_F; idx += 1024) {
        int i = idx >> 5, j = idx & 31;
        float acc = 0.0f;
#pragma unroll
        for (int k = 0; k < HID_F; ++k) acc += W1[i * HID_F + k] * sW2[k * OUT_F + j];
        W12[idx] = acc;
    }
    if (tid < OUT_F) {
        float acc = 0.0f;
#pragma unroll
        for (int k = 0; k < HID_F; ++k) acc += b1[k] * sW2[k * OUT_F + tid];
        c1[tid] = acc;
    }
}

// ---------------- fused CSR build over both graphs ----------------
__global__ void hist2_kernel(const int* __restrict__ ei0, const int* __restrict__ ei1,
                             int* __restrict__ counts, int E, int N)
{
    int e = blockIdx.x * blockDim.x + threadIdx.x;
    if (e >= 2 * E) return;
    int d = (e < E) ? ei0[E + e] : (ei1[E + (e - E)] + N);
    atomicAdd(&counts[d], 1);
}

// two-level exclusive scan (race-free)
__global__ __launch_bounds__(1024)
void scan1_kernel(const int* __restrict__ counts, int* __restrict__ lexcl,
                  int* __restrict__ partials, int N)
{
    __shared__ int wsum[16];
    const int tid  = threadIdx.x;
    const int lane = tid & 63;
    const int wv   = tid >> 6;
    const int i    = blockIdx.x * 1024 + tid;

    int v = (i < N) ? counts[i] : 0;
    int x = v;
#pragma unroll
    for (int off = 1; off < 64; off <<= 1) {
        int t = __shfl_up(x, off);
        if (lane >= off) x += t;
    }
    if (lane == 63) wsum[wv] = x;
    __syncthreads();
    int woff = 0;
    for (int w = 0; w < wv; ++w) woff += wsum[w];
    if (i < N) lexcl[i] = woff + x - v;
    if (tid == 1023) partials[blockIdx.x] = woff + x;
}

__global__ __launch_bounds__(1024)
void scan2_kernel(int* __restrict__ partials, int NB)
{
    __shared__ int wsum[16];
    const int tid  = threadIdx.x;
    const int lane = tid & 63;
    const int wv   = tid >> 6;
    int v = (tid < NB) ? partials[tid] : 0;
    int x = v;
#pragma unroll
    for (int off = 1; off < 64; off <<= 1) {
        int t = __shfl_up(x, off);
        if (lane >= off) x += t;
    }
    if (lane == 63) wsum[wv] = x;
    __syncthreads();
    int woff = 0;
    for (int w = 0; w < wv; ++w) woff += wsum[w];
    if (tid < NB) partials[tid] = woff + x - v;
}

// combine -> offsets/cursor, dinv = rsqrt(deg+1)
__global__ void scan3_kernel(const int* __restrict__ lexcl, const int* __restrict__ partials,
                             const int* __restrict__ counts,
                             int* __restrict__ offsets, int* __restrict__ cursor,
                             float* __restrict__ dinv, int n2, int e2tot)
{
    int i = blockIdx.x * blockDim.x + threadIdx.x;
    if (i >= n2) return;
    int o = lexcl[i] + partials[i >> 10];
    offsets[i] = o;
    cursor[i]  = o;
    dinv[i] = rsqrtf((float)counts[i] + 1.0f);
    if (i == 0) offsets[n2] = e2tot;
}

// dst-range-sharded scatter (r15-verified: breaks 16x write amplification)
__global__ __launch_bounds__(256)
void scatter2_shard_kernel(const int* __restrict__ ei0, const int* __restrict__ ei1,
                           int* __restrict__ cursor, int* __restrict__ csr_src,
                           int E, int N, int n2)
{
    const int shard   = blockIdx.x & 7;
    const int bid     = blockIdx.x >> 3;
    const int nblocks = gridDim.x >> 3;
    const int lo = (int)(((long long)n2 * shard) >> 3);
    const int hi = (int)(((long long)n2 * (shard + 1)) >> 3);

    long long start  = (long long)bid * blockDim.x + threadIdx.x;
    long long stride = (long long)nblocks * blockDim.x;
    const long long e2 = 2LL * E;
    for (long long e = start; e < e2; e += stride) {
        int s, d;
        if (e < E) { s = ei0[e];                 d = ei0[E + e]; }
        else       { s = ei1[e - E] + N;         d = ei1[E + (e - E)] + N; }
        if (d >= lo && d < hi) {
            int pos = atomicAdd(&cursor[d], 1);
            csr_src[pos] = s;
        }
    }
}

// ---------------- GEMM: Ys = (X @ W12) * dinv over 2N rows ----------------
__global__ __launch_bounds__(256)
void gemm_ys2_kernel(const float* __restrict__ x0, const float* __restrict__ x1,
                     const float* __restrict__ W12, const float* __restrict__ dinv,
                     float* __restrict__ Ys, int N, int n2)
{
    __shared__ float Ws[IN_F * OUT_F];
    __shared__ float xs[8 * IN_F];
    const int tid = threadIdx.x;

    for (int i = tid; i < IN_F * OUT_F; i += 256) Ws[i] = W12[i];
    const int row0 = blockIdx.x * 8;
    for (int i = tid; i < 8 * IN_F; i += 256) {
        int r = i >> 6;
        int rr = row0 + r;
        float v = 0.0f;
        if (rr < n2) {
            v = (rr < N) ? x0[(size_t)rr * IN_F + (i & 63)]
                         : x1[(size_t)(rr - N) * IN_F + (i & 63)];
        }
        xs[i] = v;
    }
    __syncthreads();

    const int r = tid >> 5;
    const int c = tid & 31;
    const int row = row0 + r;
    if (row >= n2) return;

    float acc = 0.0f;
#pragma unroll
    for (int k = 0; k < IN_F; ++k) acc += xs[r * IN_F + k] * Ws[k * OUT_F + c];

    Ys[(size_t)row * OUT_F + c] = acc * dinv[row];
}

// ---------------- CSR gather-aggregate, 32-wide, unroll 8 ----------------
template<int MODE>
__global__ __launch_bounds__(256)
void csr_agg32_kernel(const int* __restrict__ csr_src, const int* __restrict__ offsets,
                      const float* __restrict__ in, const float* __restrict__ dinv,
                      float* __restrict__ sdsum, const float* __restrict__ c1,
                      const float* __restrict__ b2,
                      float* __restrict__ out, int n)
{
    constexpr int F = OUT_F;              // 32
    const int lane = threadIdx.x & 63;
    const int wid  = (blockIdx.x * (blockDim.x >> 6)) + (threadIdx.x >> 6);
    const int sub  = lane >> 5;           // 2 nodes per wave
    const int f    = lane & 31;
    const int node = wid * 2 + sub;
    const int lbase = sub * F;

    const bool valid = (node < n);
    const int nc   = valid ? node : 0;
    const int off0 = offsets[nc];
    const int off1 = valid ? offsets[nc + 1] : off0;

    float acc0 = valid ? in[(size_t)nc * F + f] : 0.0f;   // self term
    float acc1 = 0.0f, acc2 = 0.0f, acc3 = 0.0f;
    float dsum = 0.0f;                                    // MODE 0 only
    for (int k = off0; k < off1; k += F) {
        int nk = off1 - k; if (nk > F) nk = F;
        int sj = (f < nk) ? csr_src[k + f] : 0;
        if (MODE == 0) {
            float dv = dinv[sj];
            dsum += (f < nk) ? dv : 0.0f;
        }
        int t = 0;
        for (; t + 8 <= nk; t += 8) {
            int s0 = __shfl(sj, lbase + t);
            int s1 = __shfl(sj, lbase + t + 1);
            int s2 = __shfl(sj, lbase + t + 2);
            int s3 = __shfl(sj, lbase + t + 3);
            int s4 = __shfl(sj, lbase + t + 4);
            int s5 = __shfl(sj, lbase + t + 5);
            int s6 = __shfl(sj, lbase + t + 6);
            int s7 = __shfl(sj, lbase + t + 7);
            float v0 = in[(size_t)s0 * F + f];
            float v1 = in[(size_t)s1 * F + f];
            float v2 = in[(size_t)s2 * F + f];
            float v3 = in[(size_t)s3 * F + f];
            float v4 = in[(size_t)s4 * F + f];
            float v5 = in[(size_t)s5 * F + f];
            float v6 = in[(size_t)s6 * F + f];
            float v7 = in[(size_t)s7 * F + f];
            acc0 += v0 + v4;
            acc1 += v1 + v5;
            acc2 += v2 + v6;
            acc3 += v3 + v7;
        }
        for (; t < nk; ++t) {
            int s = __shfl(sj, lbase + t);
            acc0 += in[(size_t)s * F + f];
        }
    }
    if (MODE == 0) {
#pragma unroll
        for (int off = 1; off < 32; off <<= 1) dsum += __shfl_xor(dsum, off);
    }
    if (valid) {
        float di = dinv[node];
        float s = (acc0 + acc1) + (acc2 + acc3);
        if (MODE == 0) {
            out[(size_t)node * F + f] = di * di * s;
            if (f == 0) sdsum[node] = dsum;
        } else {
            float t = di * (di + sdsum[node]);
            out[(size_t)node * F + f] = di * s + t * c1[f] + b2[f];
        }
    }
}

// ---------------- mean pool over both graphs (2N nodes -> 2B graphs) ----------------
__global__ void pool_sum2_kernel(const float* __restrict__ h,
                                 const int* __restrict__ bat0, const int* __restrict__ bat1,
                                 float* __restrict__ pooled, float* __restrict__ cnt,
                                 int N, int n2, int B)
{
    int t = blockIdx.x * blockDim.x + threadIdx.x;
    int i = t >> 5;          // node
    int f = t & 31;          // feature
    if (i >= n2) return;
    int g = (i < N) ? bat0[i] : (bat1[i - N] + B);
    atomicAdd(&pooled[(size_t)g * OUT_F + f], h[(size_t)i * OUT_F + f]);
    if (f == 0) atomicAdd(&cnt[g], 1.0f);
}

__global__ void pool_div_kernel(float* __restrict__ pooled, const float* __restrict__ cnt, int B2)
{
    int t = blockIdx.x * blockDim.x + threadIdx.x;
    if (t >= B2 * OUT_F) return;
    int g = t >> 5;
    pooled[t] /= fmaxf(cnt[g], 1.0f);
}

// ---------------- gate: softmax([p0|p1] @ Wc + bc) ----------------
__global__ void gate_kernel(const float* __restrict__ p0, const float* __restrict__ p1,
                            const float* __restrict__ Wc, const float* __restrict__ bc,
                            float* __restrict__ gate, int B)
{
    int g = blockIdx.x * blockDim.x + threadIdx.x;
    if (g >= B) return;
    float xv[2 * OUT_F];
#pragma unroll
    for (int k = 0; k < OUT_F; ++k) xv[k] = p0[(size_t)g * OUT_F + k];
#pragma unroll
    for (int k = 0; k < OUT_F; ++k) xv[OUT_F + k] = p1[(size_t)g * OUT_F + k];

    float lg[NEXP];
    float m = -1e30f;
#pragma unroll
    for (int e = 0; e < NEXP; ++e) {
        float acc = bc[e];
#pragma unroll
        for (int k = 0; k < 2 * OUT_F; ++k) acc += xv[k] * Wc[k * NEXP + e];
        lg[e] = acc;
        m = fmaxf(m, acc);
    }
    float se = 0.0f;
#pragma unroll
    for (int e = 0; e < NEXP; ++e) { lg[e] = expf(lg[e] - m); se += lg[e]; }
    float inv = 1.0f / se;
#pragma unroll
    for (int e = 0; e < NEXP; ++e) gate[(size_t)g * NEXP + e] = lg[e] * inv;
}

__global__ void zero_scalar_kernel(float* p) { *p = 0.0f; }

// ---------------- distortion: sort edges by key = qd*B + s ----------------
__global__ void histK_kernel(const int* __restrict__ s_idx, const int* __restrict__ d_idx,
                             int* __restrict__ histK, int E2, int B, int quarter)
{
    int e = blockIdx.x * blockDim.x + threadIdx.x;
    if (e >= E2) return;
    int qd = d_idx[e] / quarter; if (qd > 3) qd = 3;
    atomicAdd(&histK[qd * B + s_idx[e]], 1);
}

__global__ void combineK_kernel(const int* __restrict__ lexclK, const int* __restrict__ partialsK,
                                int* __restrict__ offK, int* __restrict__ curK, int nk, int E2)
{
    int i = blockIdx.x * blockDim.x + threadIdx.x;
    if (i >= nk) return;
    int o = lexclK[i] + partialsK[i >> 10];
    offK[i] = o;
    curK[i] = o;
    if (i == 0) offK[nk] = E2;
}

__global__ void scatterK_kernel(const int* __restrict__ s_idx, const int* __restrict__ d_idx,
                                const float* __restrict__ dis,
                                int* __restrict__ curK, int* __restrict__ dD,
                                float* __restrict__ disD, int E2, int B, int quarter)
{
    int e = blockIdx.x * blockDim.x + threadIdx.x;
    if (e >= E2) return;
    int d = d_idx[e];
    int qd = d / quarter; if (qd > 3) qd = 3;
    int pos = atomicAdd(&curK[qd * B + s_idx[e]], 1);
    dD[pos] = d;
    disD[pos] = dis[e];
}

// Shard = (qd, s-half) pinned to XCD (blockIdx&7). Each shard: 512 waves
// stride the shard's 2048 keys; per key, s-row -> registers, then half-wave
// per edge over the key's ~8 edges. d-rows stay in the XCD's 2MB L2 slice;
// s-rows stream in 512-consecutive bands. Grid MUST be 1024 blocks.
__global__ __launch_bounds__(256)
void distortion5_kernel(const float* __restrict__ emb, const float* __restrict__ gate,
                        const int* __restrict__ offK, const int* __restrict__ dD,
                        const float* __restrict__ disD,
                        float* __restrict__ loss, int B, int E2)
{
    const int lane = threadIdx.x & 63;
    const int half = lane >> 5;          // which edge of the pair
    const int hl   = lane & 31;          // lane within half
    const int g    = hl >> 4;            // expert base (0 or 1)
    const int xcd  = blockIdx.x & 7;
    const int bid  = blockIdx.x >> 3;    // 0..127
    const int wv   = threadIdx.x >> 6;   // 0..3
    const int wIdx = bid * 4 + wv;       // 0..511 within shard

    const int qd   = xcd >> 1;
    const int sh   = xcd & 1;
    const int halfB = B >> 1;
    const int k0 = qd * B + sh * halfB;
    const int k1 = qd * B + (sh ? B : halfB);

    const float4* emb4  = (const float4*)emb;
    const float4* gate4 = (const float4*)gate;

    float lsum = 0.0f;
    for (int k = k0 + wIdx; k < k1; k += 512) {
        const int j0 = offK[k];
        const int j1 = offK[k + 1];
        if (j0 == j1) continue;
        const int s = k - qd * B;

        const float4* es = emb4 + (size_t)s * 128;
        float4 a0 = es[hl];
        float4 a1 = es[hl + 32];
        float4 a2 = es[hl + 64];
        float4 a3 = es[hl + 96];
        float4 gs0 = gate4[(size_t)s * 2];
        float4 gs1 = gate4[(size_t)s * 2 + 1];

        for (int j = j0 + half; j < j1; j += 2) {
            int d = dD[j];
            float dv = disD[j];
            const float4* ed = emb4 + (size_t)d * 128;
            float4 b0 = ed[hl];
            float4 b1 = ed[hl + 32];
            float4 b2 = ed[hl + 64];
            float4 b3 = ed[hl + 96];
            float4 gd0 = gate4[(size_t)d * 2];
            float4 gd1 = gate4[(size_t)d * 2 + 1];

            float dx;
            float pa, pb, pc, pd;
            dx = a0.x - b0.x; pa  = dx * dx;
            dx = a0.y - b0.y; pa += dx * dx;
            dx = a0.z - b0.z; pa += dx * dx;
            dx = a0.w - b0.w; pa += dx * dx;
            dx = a1.x - b1.x; pb  = dx * dx;
            dx = a1.y - b1.y; pb += dx * dx;
            dx = a1.z - b1.z; pb += dx * dx;
            dx = a1.w - b1.w; pb += dx * dx;
            dx = a2.x - b2.x; pc  = dx * dx;
            dx = a2.y - b2.y; pc += dx * dx;
            dx = a2.z - b2.z; pc += dx * dx;
            dx = a2.w - b2.w; pc += dx * dx;
            dx = a3.x - b3.x; pd  = dx * dx;
            dx = a3.y - b3.y; pd += dx * dx;
            dx = a3.z - b3.z; pd += dx * dx;
            dx = a3.w - b3.w; pd += dx * dx;

#pragma unroll
            for (int off = 1; off < 16; off <<= 1) {
                pa += __shfl_xor(pa, off);
                pb += __shfl_xor(pb, off);
                pc += __shfl_xor(pc, off);
                pd += __shfl_xor(pd, off);
            }
            // lane-group g holds: pa=expert g, pb=g+2, pc=g+4, pd=g+6

            float gp[NEXP] = { gs0.x * gd0.x, gs0.y * gd0.y, gs0.z * gd0.z, gs0.w * gd0.w,
                               gs1.x * gd1.x, gs1.y * gd1.y, gs1.z * gd1.z, gs1.w * gd1.w };
            float m = gp[0];
#pragma unroll
            for (int j2 = 1; j2 < NEXP; ++j2) m = fmaxf(m, gp[j2]);
            float se = 0.0f;
#pragma unroll
            for (int j2 = 0; j2 < NEXP; ++j2) { gp[j2] = expf(gp[j2] - m); se += gp[j2]; }

            float v = pa * gp[g] + pb * gp[g + 2] + pc * gp[g + 4] + pd * gp[g + 6];
            v += __shfl_xor(v, 16);

            lsum += fabsf((v / se) / dv - 1.0f);
        }
    }
    float other = __shfl_xor(lsum, 32);
    if (lane == 0) atomicAdd(loss, (lsum + other) / (float)E2);
}

// ---------------- launch ----------------
extern "C" void kernel_launch(void* const* d_in, const int* in_sizes, int n_in,
                              void* d_out, int out_size, void* d_ws, size_t ws_size,
                              hipStream_t stream)
{
    const float* x0   = (const float*)d_in[0];
    const float* x1   = (const float*)d_in[1];
    const float* W1   = (const float*)d_in[2];
    const float* b1   = (const float*)d_in[3];
    const float* W2   = (const float*)d_in[4];
    const float* b2   = (const float*)d_in[5];
    const float* Wc   = (const float*)d_in[6];
    const float* bc   = (const float*)d_in[7];
    const float* emb  = (const float*)d_in[8];
    const float* dis  = (const float*)d_in[9];
    const int*   ei0  = (const int*)d_in[10];
    const int*   ei1  = (const int*)d_in[11];
    const int*   bat0 = (const int*)d_in[12];
    const int*   bat1 = (const int*)d_in[13];
    const int*   ei2  = (const int*)d_in[14];

    const int N  = in_sizes[0] / IN_F;
    const int E  = in_sizes[10] / 2;
    const int B  = in_sizes[8] / (NEXP * EMB);
    const int E2 = in_sizes[14] / 2;
    const int n2 = 2 * N;
    const int nk = 4 * B;                          // sort keys
    const int quarter = (B + 3) / 4;

    float* gate_out = (float*)d_out;               // B*NEXP
    float* loss_out = gate_out + (size_t)B * NEXP; // 1

    // workspace layout (floats)
    float* ws      = (float*)d_ws;
    float* dinv    = ws;                           // 2N
    float* Ys      = dinv + n2;                    // 2N*32
    float* Zs      = Ys + (size_t)n2 * OUT_F;      // 2N*32
    float* sdsum   = Zs + (size_t)n2 * OUT_F;      // 2N
    float* pooled  = sdsum + n2;                   // 2B*32
    float* cnt     = pooled + (size_t)2 * B * OUT_F; // 2B
    float* W12     = cnt + 2 * B;                  // 64*32
    float* c1      = W12 + IN_F * OUT_F;           // 32
    float* disD    = c1 + OUT_F;                   // E2
    int*   iws     = (int*)(disD + E2);
    int*   counts  = iws;                          // 2N
    int*   offsets = counts + n2;                  // 2N+1
    int*   cursor  = offsets + n2 + 1;             // 2N
    int*   csr_src = cursor + n2;                  // 2E
    int*   lexcl   = csr_src + 2 * E;              // 2N
    int*   partials= lexcl + n2;                   // <=1024
    int*   histK   = partials + 1024;              // 4B
    int*   lexclK  = histK + nk;                   // 4B
    int*   partialsK = lexclK + nk;                // <=1024 (16 used)
    int*   offK    = partialsK + 1024;             // 4B+1
    int*   curK    = offK + nk + 1;                // 4B
    int*   dD      = curK + nk;                    // E2

    const int TB = 256;
    const int zgrid = 512;
    const int NB2 = (n2 + 1023) / 1024;            // scan blocks over 2N
    const int NBK = (nk + 1023) / 1024;            // scan blocks over 4B keys

    // W12 = W1@W2, c1 = b1@W2 (once)
    w12_kernel<<<1, 1024, 0, stream>>>(W1, W2, b1, W12, c1);

    // ---- fused CSR build over both graphs ----
    zero_i32_kernel<<<zgrid, TB, 0, stream>>>(counts, n2);
    hist2_kernel<<<(2 * E + TB - 1) / TB, TB, 0, stream>>>(ei0, ei1, counts, E, N);
    scan1_kernel<<<NB2, 1024, 0, stream>>>(counts, lexcl, partials, n2);
    scan2_kernel<<<1, 1024, 0, stream>>>(partials, NB2);
    scan3_kernel<<<(n2 + TB - 1) / TB, TB, 0, stream>>>(lexcl, partials, counts,
                                                        offsets, cursor, dinv, n2, 2 * E);
    scatter2_shard_kernel<<<1024, TB, 0, stream>>>(ei0, ei1, cursor, csr_src, E, N, n2);

    // ---- distortion edge sort by key (qd, s) ----
    zero_i32_kernel<<<zgrid, TB, 0, stream>>>(histK, nk);
    histK_kernel<<<(E2 + TB - 1) / TB, TB, 0, stream>>>(ei2, ei2 + E2, histK, E2, B, quarter);
    scan1_kernel<<<NBK, 1024, 0, stream>>>(histK, lexclK, partialsK, nk);
    scan2_kernel<<<1, 1024, 0, stream>>>(partialsK, NBK);
    combineK_kernel<<<(nk + TB - 1) / TB, TB, 0, stream>>>(lexclK, partialsK, offK, curK, nk, E2);
    scatterK_kernel<<<(E2 + TB - 1) / TB, TB, 0, stream>>>(ei2, ei2 + E2, dis,
                                                           curK, dD, disD, E2, B, quarter);

    // ---- encoder: Ys = (X@W12)*dinv ; two aggregation passes ----
    gemm_ys2_kernel<<<(n2 + 7) / 8, 256, 0, stream>>>(x0, x1, W12, dinv, Ys, N, n2);
    csr_agg32_kernel<0><<<(n2 + 7) / 8, TB, 0, stream>>>(csr_src, offsets, Ys, dinv,
                                                         sdsum, nullptr, nullptr, Zs, n2);
    csr_agg32_kernel<1><<<(n2 + 7) / 8, TB, 0, stream>>>(csr_src, offsets, Zs, dinv,
                                                         sdsum, c1, b2, Ys, n2);

    // ---- mean pool (both graphs) ----
    zero_f32_kernel<<<zgrid, TB, 0, stream>>>(pooled, (long long)2 * B * OUT_F);
    zero_f32_kernel<<<zgrid, TB, 0, stream>>>(cnt, 2 * B);
    pool_sum2_kernel<<<((n2 * 32) + TB - 1) / TB, TB, 0, stream>>>(Ys, bat0, bat1,
                                                                   pooled, cnt, N, n2, B);
    pool_div_kernel<<<((2 * B * OUT_F) + TB - 1) / TB, TB, 0, stream>>>(pooled, cnt, 2 * B);

    // ---- gate ----
    gate_kernel<<<(B + TB - 1) / TB, TB, 0, stream>>>(pooled, pooled + (size_t)B * OUT_F,
                                                      Wc, bc, gate_out, B);

    // ---- distortion loss (XCD-sharded, L2-resident d-quarters) ----
    zero_scalar_kernel<<<1, 1, 0, stream>>>(loss_out);
    distortion5_kernel<<<1024, TB, 0, stream>>>(emb, gate_out, offK, dD, disD,
                                                loss_out, B, E2);
}